// Round 1
// baseline (3874.450 us; speedup 1.0000x reference)
//
#include <hip/hip_runtime.h>
#include <math.h>

#define TTOK   25216      // 128*197
#define SEQL   197
#define NBATCH 128
#define DMODEL 256
#define NHEADS 8
#define FFD    1024
#define NEXP   4
#define NCLS   38
#define CONVK  768
#define NPATCH 196

#define BM 128
#define BN 64
#define BK 32
#define CHUNK 8192

__device__ __forceinline__ float warp_sum(float v) {
  #pragma unroll
  for (int o = 32; o; o >>= 1) v += __shfl_xor(v, o);
  return v;
}
__device__ __forceinline__ float warp_max(float v) {
  #pragma unroll
  for (int o = 32; o; o >>= 1) v = fmaxf(v, __shfl_xor(v, o));
  return v;
}

// 16-FMA*? micro kernel: As[BK][BM+4] (transposed A tile), Bs[BK][BN]
#define GEMM_MICRO()                                                          \
  {                                                                           \
    _Pragma("unroll")                                                         \
    for (int kk = 0; kk < BK; ++kk) {                                         \
      float ar[8], br[4];                                                     \
      *(float4*)&ar[0] = *(const float4*)&As[kk][ty*8];                       \
      *(float4*)&ar[4] = *(const float4*)&As[kk][ty*8+4];                     \
      *(float4*)&br[0] = *(const float4*)&Bs[kk][tx*4];                       \
      _Pragma("unroll")                                                       \
      for (int i2 = 0; i2 < 8; ++i2)                                          \
        _Pragma("unroll")                                                     \
        for (int j2 = 0; j2 < 4; ++j2)                                        \
          acc[i2][j2] = fmaf(ar[i2], br[j2], acc[i2][j2]);                    \
    }                                                                         \
  }

// ---------------- transpose: in[R][C] -> out[C][R] ----------------
__global__ __launch_bounds__(256) void k_transpose(const float* __restrict__ in,
                                                   float* __restrict__ out,
                                                   int R, int C) {
  __shared__ float tile[32][33];
  int c0 = blockIdx.x * 32, r0 = blockIdx.y * 32;
  int x = threadIdx.x & 31, y = threadIdx.x >> 5;
  for (int i = y; i < 32; i += 8) {
    int r = r0 + i, c = c0 + x;
    if (r < R && c < C) tile[i][x] = in[(size_t)r * C + c];
  }
  __syncthreads();
  for (int i = y; i < 32; i += 8) {
    int c = c0 + i, r = r0 + x;
    if (r < R && c < C) out[(size_t)c * R + r] = tile[x][i];
  }
}

// ---------------- patch-embed conv as im2col GEMM ----------------
// wT: [768][256] (K-major), out rows -> tok[b*197 + 1 + p]
__global__ __launch_bounds__(256) void k_conv(const float* __restrict__ x,
                                              const float* __restrict__ wT,
                                              const float* __restrict__ cb,
                                              float* __restrict__ tok) {
  __shared__ __align__(16) float As[BK][BM + 4];
  __shared__ __align__(16) float Bs[BK][BN];
  const int tid = threadIdx.x;
  const int m0 = blockIdx.x * BM;
  const int n0 = blockIdx.y * BN;
  const int tx = tid & 15, ty = tid >> 4;
  float acc[8][4] = {};
  for (int kc = 0; kc < CONVK; kc += BK) {
    #pragma unroll
    for (int i = 0; i < (BM * BK) / 256; ++i) {
      int e = i * 256 + tid;
      int mm = e >> 5, kk = e & 31;
      int m = m0 + mm;
      int b = m / NPATCH, p = m - b * NPATCH;
      int py = p / 14, px = p - py * 14;
      int k = kc + kk;
      int c = k >> 8, r = k & 255;
      As[kk][mm] = x[((size_t)(b * 3 + c) * 224 + py * 16 + (r >> 4)) * 224 +
                     px * 16 + (r & 15)];
    }
    #pragma unroll
    for (int i = 0; i < (BK * BN) / 256; ++i) {
      int e = i * 256 + tid;
      int kk = e >> 6, nn = e & 63;
      Bs[kk][nn] = wT[(size_t)(kc + kk) * DMODEL + n0 + nn];
    }
    __syncthreads();
    GEMM_MICRO();
    __syncthreads();
  }
  #pragma unroll
  for (int i = 0; i < 8; ++i) {
    int m = m0 + ty * 8 + i;
    int b = m / NPATCH, p = m - b * NPATCH;
    float* dst = tok + ((size_t)b * SEQL + 1 + p) * DMODEL + n0 + tx * 4;
    #pragma unroll
    for (int j = 0; j < 4; ++j) dst[j] = acc[i][j] + cb[n0 + tx * 4 + j];
  }
}

// ---------------- generic GEMM: C[m][n] (=|+=) sum_k A[m][k]*WT[k][n] + bias[n]
__global__ __launch_bounds__(256) void k_gemm(const float* __restrict__ A, int lda,
                                              const float* __restrict__ WT, int ldn,
                                              const float* __restrict__ bias,
                                              float* __restrict__ C, int ldc,
                                              int K, int addC) {
  __shared__ __align__(16) float As[BK][BM + 4];
  __shared__ __align__(16) float Bs[BK][BN];
  const int tid = threadIdx.x;
  const int m0 = blockIdx.x * BM;
  const int n0 = blockIdx.y * BN;
  const int tx = tid & 15, ty = tid >> 4;
  float acc[8][4] = {};
  for (int kc = 0; kc < K; kc += BK) {
    #pragma unroll
    for (int i = 0; i < (BM * BK) / 256; ++i) {
      int e = i * 256 + tid;
      int mm = e >> 5, kk = e & 31;
      As[kk][mm] = A[(size_t)(m0 + mm) * lda + kc + kk];
    }
    #pragma unroll
    for (int i = 0; i < (BK * BN) / 256; ++i) {
      int e = i * 256 + tid;
      int kk = e >> 6, nn = e & 63;
      Bs[kk][nn] = WT[(size_t)(kc + kk) * ldn + n0 + nn];
    }
    __syncthreads();
    GEMM_MICRO();
    __syncthreads();
  }
  #pragma unroll
  for (int i = 0; i < 8; ++i) {
    int m = m0 + ty * 8 + i;
    float* dst = C + (size_t)m * ldc + n0 + tx * 4;
    #pragma unroll
    for (int j = 0; j < 4; ++j) {
      float v = acc[i][j] + bias[n0 + tx * 4 + j];
      if (addC) v += dst[j];
      dst[j] = v;
    }
  }
}

// ---------------- MoE expert GEMM1: hid = gelu(x2[gathered] @ w1 + b1) -------
__global__ __launch_bounds__(256) void k_moe1(const float* __restrict__ x2,
                                              const float* __restrict__ w1,
                                              const float* __restrict__ b1,
                                              const int* __restrict__ cnt,
                                              const int* __restrict__ list,
                                              float* __restrict__ hid, int chunk0) {
  int rows = *cnt - chunk0;
  rows = rows > CHUNK ? CHUNK : rows;
  const int m0 = blockIdx.x * BM;
  if (m0 >= rows) return;
  __shared__ __align__(16) float As[BK][BM + 4];
  __shared__ __align__(16) float Bs[BK][BN];
  const int tid = threadIdx.x;
  const int n0 = blockIdx.y * BN;
  const int tx = tid & 15, ty = tid >> 4;
  float acc[8][4] = {};
  for (int kc = 0; kc < DMODEL; kc += BK) {
    #pragma unroll
    for (int i = 0; i < (BM * BK) / 256; ++i) {
      int e = i * 256 + tid;
      int mm = e >> 5, kk = e & 31;
      int row = m0 + mm;
      float v = 0.f;
      if (row < rows) v = x2[(size_t)list[chunk0 + row] * DMODEL + kc + kk];
      As[kk][mm] = v;
    }
    #pragma unroll
    for (int i = 0; i < (BK * BN) / 256; ++i) {
      int e = i * 256 + tid;
      int kk = e >> 6, nn = e & 63;
      Bs[kk][nn] = w1[(size_t)(kc + kk) * FFD + n0 + nn];
    }
    __syncthreads();
    GEMM_MICRO();
    __syncthreads();
  }
  #pragma unroll
  for (int i = 0; i < 8; ++i) {
    int row = m0 + ty * 8 + i;
    if (row < rows) {
      float* dst = hid + (size_t)row * FFD + n0 + tx * 4;
      #pragma unroll
      for (int j = 0; j < 4; ++j) {
        float v = acc[i][j] + b1[n0 + tx * 4 + j];
        dst[j] = 0.5f * v * (1.0f + erff(v * 0.70710678118654752f));
      }
    }
  }
}

// ---------------- MoE expert GEMM2: tok[list[g]] += hid @ w2 + b2 ------------
__global__ __launch_bounds__(256) void k_moe2(const float* __restrict__ hid,
                                              const float* __restrict__ w2,
                                              const float* __restrict__ b2,
                                              const int* __restrict__ cnt,
                                              const int* __restrict__ list,
                                              float* __restrict__ tok, int chunk0) {
  int rows = *cnt - chunk0;
  rows = rows > CHUNK ? CHUNK : rows;
  const int m0 = blockIdx.x * BM;
  if (m0 >= rows) return;
  __shared__ __align__(16) float As[BK][BM + 4];
  __shared__ __align__(16) float Bs[BK][BN];
  const int tid = threadIdx.x;
  const int n0 = blockIdx.y * BN;
  const int tx = tid & 15, ty = tid >> 4;
  float acc[8][4] = {};
  for (int kc = 0; kc < FFD; kc += BK) {
    #pragma unroll
    for (int i = 0; i < (BM * BK) / 256; ++i) {
      int e = i * 256 + tid;
      int mm = e >> 5, kk = e & 31;
      int row = m0 + mm;
      As[kk][mm] = (row < rows) ? hid[(size_t)row * FFD + kc + kk] : 0.f;
    }
    #pragma unroll
    for (int i = 0; i < (BK * BN) / 256; ++i) {
      int e = i * 256 + tid;
      int kk = e >> 6, nn = e & 63;
      Bs[kk][nn] = w2[(size_t)(kc + kk) * DMODEL + n0 + nn];
    }
    __syncthreads();
    GEMM_MICRO();
    __syncthreads();
  }
  #pragma unroll
  for (int i = 0; i < 8; ++i) {
    int row = m0 + ty * 8 + i;
    if (row < rows) {
      int t = list[chunk0 + row];
      float* dst = tok + (size_t)t * DMODEL + n0 + tx * 4;
      #pragma unroll
      for (int j = 0; j < 4; ++j) dst[j] += acc[i][j] + b2[n0 + tx * 4 + j];
    }
  }
}

// ---------------- LayerNorm over D=256, one block per row --------------------
__global__ __launch_bounds__(256) void k_ln(const float* __restrict__ in,
                                            float* __restrict__ out,
                                            const float* __restrict__ g,
                                            const float* __restrict__ bb) {
  const int row = blockIdx.x;
  const int tid = threadIdx.x;
  float v = in[(size_t)row * DMODEL + tid];
  float s1 = warp_sum(v), s2 = warp_sum(v * v);
  __shared__ float a1[4], a2[4];
  int w = tid >> 6, lane = tid & 63;
  if (lane == 0) { a1[w] = s1; a2[w] = s2; }
  __syncthreads();
  s1 = a1[0] + a1[1] + a1[2] + a1[3];
  s2 = a2[0] + a2[1] + a2[2] + a2[3];
  float mu = s1 * (1.f / DMODEL);
  float var = s2 * (1.f / DMODEL) - mu * mu;
  float rs = rsqrtf(var + 1e-5f);
  out[(size_t)row * DMODEL + tid] = (v - mu) * rs * g[tid] + bb[tid];
}

// ---------------- fused attention: one block per (b,h) -----------------------
__global__ __launch_bounds__(256) void k_attn(const float* __restrict__ qkv,
                                              float* __restrict__ ao) {
  const int bh = blockIdx.x;
  const int b = bh >> 3, h = bh & 7;
  __shared__ float Ks[SEQL][33];
  __shared__ float Vs[SEQL][33];
  __shared__ float Ss[4][SEQL + 3];
  const float* base = qkv + (size_t)b * SEQL * 768;
  for (int e = threadIdx.x; e < SEQL * 32; e += 256) {
    int s = e >> 5, d = e & 31;
    Ks[s][d] = base[(size_t)s * 768 + 256 + h * 32 + d];
    Vs[s][d] = base[(size_t)s * 768 + 512 + h * 32 + d];
  }
  __syncthreads();
  const int w = threadIdx.x >> 6, lane = threadIdx.x & 63;
  for (int q = w; q < SEQL; q += 4) {
    const float* qrow = base + (size_t)q * 768 + h * 32;
    float qr[32];
    #pragma unroll
    for (int d = 0; d < 32; ++d) qr[d] = qrow[d];
    float sc[4];
    float mx = -1e30f;
    #pragma unroll
    for (int r = 0; r < 4; ++r) {
      int k = lane + 64 * r;
      float s = -1e30f;
      if (k < SEQL) {
        s = 0.f;
        #pragma unroll
        for (int d = 0; d < 32; ++d) s = fmaf(qr[d], Ks[k][d], s);
        s *= 0.17677669529663687f;  // 1/sqrt(32)
      }
      sc[r] = s;
      mx = fmaxf(mx, s);
    }
    mx = warp_max(mx);
    float sum = 0.f;
    #pragma unroll
    for (int r = 0; r < 4; ++r) {
      int k = lane + 64 * r;
      float e2 = (k < SEQL) ? expf(sc[r] - mx) : 0.f;
      sc[r] = e2;
      sum += e2;
    }
    sum = warp_sum(sum);
    float inv = 1.f / sum;
    #pragma unroll
    for (int r = 0; r < 4; ++r) {
      int k = lane + 64 * r;
      if (k < SEQL) Ss[w][k] = sc[r] * inv;
    }
    // wave-local LDS scratch: producer and consumer are the same wave
    int d = lane & 31, half = lane >> 5;
    float acc = 0.f;
    for (int i = 0; i < 99; ++i) {
      int k = half * 99 + i;
      if (k < SEQL) acc = fmaf(Ss[w][k], Vs[k][d], acc);
    }
    acc += __shfl_xor(acc, 32);
    if (lane < 32) ao[((size_t)b * SEQL + q) * DMODEL + h * 32 + d] = acc;
  }
}

// ---------------- router: logits -> top-2 mask -> compacted lists ------------
__global__ __launch_bounds__(256) void k_router(const float* __restrict__ x2,
                                                const float* __restrict__ rw,
                                                const float* __restrict__ rb,
                                                int* __restrict__ cnt,
                                                int* __restrict__ list) {
  int gw = (blockIdx.x * 256 + threadIdx.x) >> 6;
  int lane = threadIdx.x & 63;
  if (gw >= TTOK) return;
  const float* row = x2 + (size_t)gw * DMODEL;
  float p[NEXP];
  #pragma unroll
  for (int e2 = 0; e2 < NEXP; ++e2) {
    float s = 0.f;
    for (int d = lane; d < DMODEL; d += 64) s = fmaf(row[d], rw[e2 * DMODEL + d], s);
    p[e2] = warp_sum(s) + rb[e2];
  }
  if (lane < NEXP) {
    int e2 = lane;
    int rank = 0;
    #pragma unroll
    for (int j = 0; j < NEXP; ++j)
      if (j != e2 && (p[j] > p[e2] || (p[j] == p[e2] && j < e2))) ++rank;
    if (rank < 2) {
      int idx = atomicAdd(&cnt[e2], 1);
      list[e2 * TTOK + idx] = gw;
    }
  }
}

// ---------------- cls token fill ---------------------------------------------
__global__ void k_cls(const float* __restrict__ cls, float* __restrict__ tok) {
  tok[(size_t)blockIdx.x * SEQL * DMODEL + threadIdx.x] = cls[threadIdx.x];
}

// ---------------- classifier head --------------------------------------------
__global__ __launch_bounds__(256) void k_head(const float* __restrict__ tok,
                                              const float* __restrict__ hw,
                                              const float* __restrict__ hb,
                                              float* __restrict__ out) {
  int b = blockIdx.x;
  int w = threadIdx.x >> 6, lane = threadIdx.x & 63;
  const float* row = tok + (size_t)b * SEQL * DMODEL;  // token 0
  for (int c = w; c < NCLS; c += 4) {
    float s = 0.f;
    for (int d = lane; d < DMODEL; d += 64) s = fmaf(row[d], hw[c * DMODEL + d], s);
    s = warp_sum(s);
    if (lane == 0) out[b * NCLS + c] = s + hb[c];
  }
}

extern "C" void kernel_launch(void* const* d_in, const int* in_sizes, int n_in,
                              void* d_out, int out_size, void* d_ws, size_t ws_size,
                              hipStream_t stream) {
  const float* x      = (const float*)d_in[0];
  const float* conv_w = (const float*)d_in[1];
  const float* conv_b = (const float*)d_in[2];
  const float* cls    = (const float*)d_in[3];
  const float* ln1g   = (const float*)d_in[4];
  const float* ln1b   = (const float*)d_in[5];
  const float* qkv_w  = (const float*)d_in[6];
  const float* qkv_b  = (const float*)d_in[7];
  const float* out_w  = (const float*)d_in[8];
  const float* out_b  = (const float*)d_in[9];
  const float* ln2g   = (const float*)d_in[10];
  const float* ln2b   = (const float*)d_in[11];
  const float* rw     = (const float*)d_in[12];
  const float* rb     = (const float*)d_in[13];
  const float* e_w1   = (const float*)d_in[14];
  const float* e_b1   = (const float*)d_in[15];
  const float* e_w2   = (const float*)d_in[16];
  const float* e_b2   = (const float*)d_in[17];
  const float* head_w = (const float*)d_in[18];
  const float* head_b = (const float*)d_in[19];
  float* out = (float*)d_out;

  char* ws = (char*)d_ws;
  size_t off = 0;
  auto alloc = [&](size_t bytes) {
    void* p = ws + off;
    off += (bytes + 255) & ~(size_t)255;
    return p;
  };
  float* tok  = (float*)alloc((size_t)TTOK * DMODEL * 4);
  float* x2   = (float*)alloc((size_t)TTOK * DMODEL * 4);   // ln out / attn out
  float* qkvb = (float*)alloc((size_t)TTOK * 768 * 4);
  float* cwT  = (float*)alloc((size_t)CONVK * DMODEL * 4);
  float* qwT  = (float*)alloc((size_t)DMODEL * 768 * 4);
  float* owT  = (float*)alloc((size_t)DMODEL * DMODEL * 4);
  int*   cnt  = (int*)alloc(256);
  int*   list = (int*)alloc((size_t)NEXP * TTOK * 4);
  float* hid  = qkvb;  // reuse: qkv dead after attention

  hipMemsetAsync(cnt, 0, NEXP * sizeof(int), stream);

  // weight transposes to K-major
  k_transpose<<<dim3(CONVK / 32, DMODEL / 32), 256, 0, stream>>>(conv_w, cwT, DMODEL, CONVK);
  k_transpose<<<dim3(DMODEL / 32, 768 / 32), 256, 0, stream>>>(qkv_w, qwT, 768, DMODEL);
  k_transpose<<<dim3(DMODEL / 32, DMODEL / 32), 256, 0, stream>>>(out_w, owT, DMODEL, DMODEL);

  // patch embed + cls
  k_conv<<<dim3(25088 / BM, DMODEL / BN), 256, 0, stream>>>(x, cwT, conv_b, tok);
  k_cls<<<NBATCH, DMODEL, 0, stream>>>(cls, tok);

  // attention block
  k_ln<<<TTOK, DMODEL, 0, stream>>>(tok, x2, ln1g, ln1b);
  k_gemm<<<dim3(TTOK / BM, 768 / BN), 256, 0, stream>>>(x2, DMODEL, qwT, 768, qkv_b,
                                                        qkvb, 768, DMODEL, 0);
  k_attn<<<NBATCH * NHEADS, 256, 0, stream>>>(qkvb, x2);
  k_gemm<<<dim3(TTOK / BM, DMODEL / BN), 256, 0, stream>>>(x2, DMODEL, owT, DMODEL, out_b,
                                                           tok, DMODEL, DMODEL, 1);

  // MoE block
  k_ln<<<TTOK, DMODEL, 0, stream>>>(tok, x2, ln2g, ln2b);
  k_router<<<TTOK / 4, 256, 0, stream>>>(x2, rw, rb, cnt, list);
  for (int e = 0; e < NEXP; ++e) {
    for (int c = 0; c < 4; ++c) {
      k_moe1<<<dim3(CHUNK / BM, FFD / BN), 256, 0, stream>>>(
          x2, e_w1 + (size_t)e * DMODEL * FFD, e_b1 + (size_t)e * FFD,
          cnt + e, list + (size_t)e * TTOK, hid, c * CHUNK);
      k_moe2<<<dim3(CHUNK / BM, DMODEL / BN), 256, 0, stream>>>(
          hid, e_w2 + (size_t)e * FFD * DMODEL, e_b2 + (size_t)e * DMODEL,
          cnt + e, list + (size_t)e * TTOK, tok, c * CHUNK);
    }
  }

  // head
  k_head<<<NBATCH, 256, 0, stream>>>(tok, head_w, head_b, out);
}

// Round 3
// 1273.370 us; speedup vs baseline: 3.0427x; 3.0427x over previous
//
#include <hip/hip_runtime.h>
#include <hip/hip_bf16.h>
#include <math.h>

#define TTOK   25216      // 128*197
#define SEQL   197
#define NBATCH 128
#define DMODEL 256
#define NHEADS 8
#define FFD    1024
#define NEXP   4
#define NCLS   38
#define CONVK  768
#define NPATCH 196
#define CM     25088      // conv GEMM rows = 128*196

typedef unsigned short u16;
using s16x8 = __attribute__((ext_vector_type(8))) short;
using f32x4 = __attribute__((ext_vector_type(4))) float;

__device__ __forceinline__ float b2f(u16 v) {
  union { unsigned u; float f; } x; x.u = (unsigned)v << 16; return x.f;
}
__device__ __forceinline__ u16 f2b(float f) {
  __hip_bfloat16 h = __float2bfloat16(f);
  return *reinterpret_cast<u16*>(&h);
}
__device__ __forceinline__ void gload16(const void* g, void* l) {
  __builtin_amdgcn_global_load_lds(
      (const __attribute__((address_space(1))) void*)g,
      (__attribute__((address_space(3))) void*)l, 16, 0, 0);
}
__device__ __forceinline__ float warp_sum(float v) {
  #pragma unroll
  for (int o = 32; o; o >>= 1) v += __shfl_xor(v, o);
  return v;
}
__device__ __forceinline__ float warp_max(float v) {
  #pragma unroll
  for (int o = 32; o; o >>= 1) v = fmaxf(v, __shfl_xor(v, o));
  return v;
}

// ---------------- fp32 -> bf16 hi/lo split cast (n % 1024 == 0) --------------
__global__ __launch_bounds__(256) void k_cast2(const float* __restrict__ in,
                                               u16* __restrict__ hi,
                                               u16* __restrict__ lo) {
  int i = (blockIdx.x * 256 + threadIdx.x) * 4;
  float4 v = *(const float4*)&in[i];
  float vv[4] = {v.x, v.y, v.z, v.w};
  u16 h[4], l[4];
  #pragma unroll
  for (int j = 0; j < 4; ++j) {
    h[j] = f2b(vv[j]);
    l[j] = f2b(vv[j] - b2f(h[j]));
  }
  *(uint2*)&hi[i] = *(const uint2*)h;
  *(uint2*)&lo[i] = *(const uint2*)l;
}

// ---------------- transpose+cast: in[R][C] fp32 -> out[C][R] bf16 (single) ---
__global__ __launch_bounds__(256) void k_castT(const float* __restrict__ in,
                                               u16* __restrict__ out, int R, int C) {
  in  += (size_t)blockIdx.z * R * C;
  out += (size_t)blockIdx.z * R * C;
  __shared__ float t[32][33];
  int c0 = blockIdx.x * 32, r0 = blockIdx.y * 32;
  int xx = threadIdx.x & 31, yy = threadIdx.x >> 5;
  for (int i = yy; i < 32; i += 8)
    t[i][xx] = in[(size_t)(r0 + i) * C + c0 + xx];
  __syncthreads();
  for (int i = yy; i < 32; i += 8)
    out[(size_t)(c0 + i) * R + r0 + xx] = f2b(t[xx][i]);
}

// ---------------- im2col + split cast: x fp32 -> Acv hi/lo [25088][768] ------
__global__ __launch_bounds__(256) void k_im2col(const float* __restrict__ x,
                                                u16* __restrict__ Ah,
                                                u16* __restrict__ Al) {
  long idx = ((long)blockIdx.x * 256 + threadIdx.x) * 8;
  int m = (int)(idx / CONVK), k = (int)(idx % CONVK);
  int b = m / NPATCH, p = m - b * NPATCH;
  int py = p / 14, px = p - py * 14;
  int c = k >> 8, r = k & 255;
  int ry = r >> 4, rx = r & 15;                       // rx in {0, 8}
  const float* src = &x[(((long)(b * 3 + c) * 224) + py * 16 + ry) * 224 +
                        px * 16 + rx];
  u16 h[8], l[8];
  #pragma unroll
  for (int j = 0; j < 8; ++j) {
    float v = src[j];
    h[j] = f2b(v);
    l[j] = f2b(v - b2f(h[j]));
  }
  *(uint4*)&Ah[idx] = *(const uint4*)h;
  *(uint4*)&Al[idx] = *(const uint4*)l;
}

// ---------------- bf16(x2) MFMA GEMM -----------------------------------------
// C[m][n] = op( sum_k A[m][k]*W[n][k] + bias[n] )
// SPLIT: A=Ah+Al, W=Wh+Wl, acc = AhWh + AhWl + AlWh  (fp32-class accuracy)
// 128x128 tile, BK=64, 4 waves, 4x4 frags of 16x16x32, global_load_lds + XOR swizzle
template<int SPLIT, int GELU, int OUTBF, int ADDC, int GATHER, int SCATTER, int CMAP, int DYNM>
__global__ __launch_bounds__(256) void k_mm(
    const u16* __restrict__ Ah, const u16* __restrict__ Al,
    const u16* __restrict__ Wh, const u16* __restrict__ Wl,
    const float* __restrict__ bias,
    float* __restrict__ Cf, u16* __restrict__ Cb, u16* __restrict__ Cb2, int ldc,
    int M, int K, const int* __restrict__ cntp, const int* __restrict__ list) {
  const int rows = DYNM ? *cntp : M;
  const int m0 = blockIdx.x * 128;
  if (m0 >= rows) return;
  const int n0 = blockIdx.y * 128;
  __shared__ u16 As[(SPLIT ? 2 : 1) * 128 * 64];
  __shared__ u16 Bs[(SPLIT ? 2 : 1) * 128 * 64];
  const int tid = threadIdx.x;
  const int lane = tid & 63;
  const int wv = tid >> 6;
  const int wr = wv >> 1, wc = wv & 1;
  f32x4 acc[4][4] = {};

  // staging address precompute: round i covers LDS bytes [i*4096 + tid*16, +16)
  long aoff[4], woff[4]; int rofs[4];
  #pragma unroll
  for (int i = 0; i < 4; ++i) {
    int off = i * 4096 + tid * 16;
    int row = off >> 7;               // tile row
    int c16 = (off >> 4) & 7;         // 16B chunk within 128B row
    int kk = (c16 ^ (row & 7)) << 3;  // pre-swizzled source k (elements)
    int ar = m0 + row;
    if (DYNM) ar = ar < rows ? ar : rows - 1;
    aoff[i] = GATHER ? (long)list[ar] * K + kk : (long)ar * K + kk;
    woff[i] = (long)(n0 + row) * K + kk;
    rofs[i] = off;
  }
  for (int kc = 0; kc < K; kc += 64) {
    #pragma unroll
    for (int i = 0; i < 4; ++i) {
      gload16(Ah + aoff[i] + kc, (char*)As + rofs[i]);
      gload16(Wh + woff[i] + kc, (char*)Bs + rofs[i]);
      if (SPLIT) {
        gload16(Al + aoff[i] + kc, (char*)As + 16384 + rofs[i]);
        gload16(Wl + woff[i] + kc, (char*)Bs + 16384 + rofs[i]);
      }
    }
    __syncthreads();
    #pragma unroll
    for (int kf = 0; kf < 2; ++kf) {
      s16x8 ah[4], bh[4], al[4], bl[4];
      #pragma unroll
      for (int i = 0; i < 4; ++i) {
        int rowa = wr * 64 + i * 16 + (lane & 15);
        int kb = (kf * 64 + ((lane >> 4) << 4)) ^ ((rowa & 7) << 4);
        ah[i] = *(const s16x8*)((const char*)As + rowa * 128 + kb);
        if (SPLIT) al[i] = *(const s16x8*)((const char*)As + 16384 + rowa * 128 + kb);
        int rowb = wc * 64 + i * 16 + (lane & 15);
        int kbn = (kf * 64 + ((lane >> 4) << 4)) ^ ((rowb & 7) << 4);
        bh[i] = *(const s16x8*)((const char*)Bs + rowb * 128 + kbn);
        if (SPLIT) bl[i] = *(const s16x8*)((const char*)Bs + 16384 + rowb * 128 + kbn);
      }
      #pragma unroll
      for (int i = 0; i < 4; ++i)
        #pragma unroll
        for (int j = 0; j < 4; ++j)
          acc[i][j] = __builtin_amdgcn_mfma_f32_16x16x32_bf16(ah[i], bh[j],
                                                              acc[i][j], 0, 0, 0);
      if (SPLIT) {
        #pragma unroll
        for (int i = 0; i < 4; ++i)
          #pragma unroll
          for (int j = 0; j < 4; ++j)
            acc[i][j] = __builtin_amdgcn_mfma_f32_16x16x32_bf16(ah[i], bl[j],
                                                                acc[i][j], 0, 0, 0);
        #pragma unroll
        for (int i = 0; i < 4; ++i)
          #pragma unroll
          for (int j = 0; j < 4; ++j)
            acc[i][j] = __builtin_amdgcn_mfma_f32_16x16x32_bf16(al[i], bh[j],
                                                                acc[i][j], 0, 0, 0);
      }
    }
    __syncthreads();
  }
  // epilogue: C/D layout col=lane&15, row=(lane>>4)*4+j  [m89-verified]
  const int mb = m0 + wr * 64 + ((lane >> 4) << 2);
  const int nb = n0 + wc * 64 + (lane & 15);
  #pragma unroll
  for (int i = 0; i < 4; ++i) {
    #pragma unroll
    for (int jf = 0; jf < 4; ++jf) {
      #pragma unroll
      for (int j = 0; j < 4; ++j) {
        int m = mb + i * 16 + j;
        int n = nb + jf * 16;
        if (DYNM && m >= rows) continue;
        float v = acc[i][jf][j] + bias[n];
        if (GELU) v = 0.5f * v * (1.0f + erff(v * 0.70710678118654752f));
        long cr;
        if (SCATTER)     cr = list[m];
        else if (CMAP) { int bq = m / NPATCH; cr = (long)bq * SEQL + (m - bq * NPATCH) + 1; }
        else             cr = m;
        if (OUTBF) {
          u16 h = f2b(v);
          Cb[cr * ldc + n] = h;
          if (Cb2) Cb2[cr * ldc + n] = f2b(v - b2f(h));
        } else if (ADDC) {
          Cf[cr * ldc + n] += v;
        } else {
          Cf[cr * ldc + n] = v;
        }
      }
    }
  }
}

// ---------------- LayerNorm over D=256: bf16 hi (+optional lo) out -----------
__global__ __launch_bounds__(256) void k_ln(const float* __restrict__ in,
                                            u16* __restrict__ outh,
                                            u16* __restrict__ outl,
                                            const float* __restrict__ g,
                                            const float* __restrict__ bb) {
  const int row = blockIdx.x;
  const int tid = threadIdx.x;
  float v = in[(size_t)row * DMODEL + tid];
  float s1 = warp_sum(v), s2 = warp_sum(v * v);
  __shared__ float a1[4], a2[4];
  int w = tid >> 6, lane = tid & 63;
  if (lane == 0) { a1[w] = s1; a2[w] = s2; }
  __syncthreads();
  s1 = a1[0] + a1[1] + a1[2] + a1[3];
  s2 = a2[0] + a2[1] + a2[2] + a2[3];
  float mu = s1 * (1.f / DMODEL);
  float var = s2 * (1.f / DMODEL) - mu * mu;
  float rs = rsqrtf(var + 1e-5f);
  float r = (v - mu) * rs * g[tid] + bb[tid];
  u16 h = f2b(r);
  outh[(size_t)row * DMODEL + tid] = h;
  if (outl) outl[(size_t)row * DMODEL + tid] = f2b(r - b2f(h));
}

// ---------------- fused attention (fp32 math, bf16x2 in/out), 8 waves --------
__global__ __launch_bounds__(512) void k_attn(const u16* __restrict__ qh,
                                              const u16* __restrict__ ql,
                                              u16* __restrict__ aoh,
                                              u16* __restrict__ aol) {
  const int bh = blockIdx.x;
  const int b = bh >> 3, h = bh & 7;
  __shared__ float Ks[SEQL][33];
  __shared__ float Vs[SEQL][33];
  __shared__ float Ss[8][SEQL + 3];
  const u16* baseh = qh + (size_t)b * SEQL * 768;
  const u16* basel = ql + (size_t)b * SEQL * 768;
  for (int e = threadIdx.x; e < SEQL * 32; e += 512) {
    int s = e >> 5, d = e & 31;
    size_t ko = (size_t)s * 768 + 256 + h * 32 + d;
    size_t vo = (size_t)s * 768 + 512 + h * 32 + d;
    Ks[s][d] = b2f(baseh[ko]) + b2f(basel[ko]);
    Vs[s][d] = b2f(baseh[vo]) + b2f(basel[vo]);
  }
  __syncthreads();
  const int w = threadIdx.x >> 6, lane = threadIdx.x & 63;
  for (int q = w; q < SEQL; q += 8) {
    const u16* qrh = baseh + (size_t)q * 768 + h * 32;
    const u16* qrl = basel + (size_t)q * 768 + h * 32;
    float qr[32];
    #pragma unroll
    for (int i = 0; i < 4; ++i) {
      s16x8 vh = *(const s16x8*)(qrh + i * 8);
      s16x8 vl = *(const s16x8*)(qrl + i * 8);
      #pragma unroll
      for (int j = 0; j < 8; ++j)
        qr[i * 8 + j] = b2f((u16)vh[j]) + b2f((u16)vl[j]);
    }
    float sc[4];
    float mx = -1e30f;
    #pragma unroll
    for (int r = 0; r < 4; ++r) {
      int k = lane + 64 * r;
      float s = -1e30f;
      if (k < SEQL) {
        s = 0.f;
        #pragma unroll
        for (int d = 0; d < 32; ++d) s = fmaf(qr[d], Ks[k][d], s);
        s *= 0.17677669529663687f;  // 1/sqrt(32)
      }
      sc[r] = s;
      mx = fmaxf(mx, s);
    }
    mx = warp_max(mx);
    float sum = 0.f;
    #pragma unroll
    for (int r = 0; r < 4; ++r) {
      int k = lane + 64 * r;
      float e2 = (k < SEQL) ? expf(sc[r] - mx) : 0.f;
      sc[r] = e2;
      sum += e2;
    }
    sum = warp_sum(sum);
    float inv = 1.f / sum;
    #pragma unroll
    for (int r = 0; r < 4; ++r) {
      int k = lane + 64 * r;
      if (k < SEQL) Ss[w][k] = sc[r] * inv;
    }
    int d = lane & 31, half = lane >> 5;
    float acc = 0.f;
    for (int i = 0; i < 99; ++i) {
      int k = half * 99 + i;
      if (k < SEQL) acc = fmaf(Ss[w][k], Vs[k][d], acc);
    }
    acc += __shfl_xor(acc, 32);
    if (lane < 32) {
      size_t o = ((size_t)b * SEQL + q) * DMODEL + h * 32 + d;
      u16 hh = f2b(acc);
      aoh[o] = hh;
      aol[o] = f2b(acc - b2f(hh));
    }
  }
}

// ---------------- router: inline LN2 on fp32 tok -> exact-ish top-2 ----------
__global__ __launch_bounds__(256) void k_router(const float* __restrict__ tok,
                                                const float* __restrict__ g,
                                                const float* __restrict__ bb,
                                                const float* __restrict__ rw,
                                                const float* __restrict__ rb,
                                                int* __restrict__ cnt,
                                                int* __restrict__ list) {
  int gw = (blockIdx.x * 256 + threadIdx.x) >> 6;
  int lane = threadIdx.x & 63;
  if (gw >= TTOK) return;
  const float* row = tok + (size_t)gw * DMODEL;
  float vv[4];
  *(float4*)vv = *(const float4*)&row[lane * 4];
  float s1 = vv[0] + vv[1] + vv[2] + vv[3];
  float s2 = vv[0]*vv[0] + vv[1]*vv[1] + vv[2]*vv[2] + vv[3]*vv[3];
  s1 = warp_sum(s1);
  s2 = warp_sum(s2);
  float mu = s1 * (1.f / DMODEL);
  float var = s2 * (1.f / DMODEL) - mu * mu;
  float rs = rsqrtf(var + 1e-5f);
  float xd[4];
  #pragma unroll
  for (int j = 0; j < 4; ++j)
    xd[j] = (vv[j] - mu) * rs * g[lane * 4 + j] + bb[lane * 4 + j];
  float p[NEXP];
  #pragma unroll
  for (int e2 = 0; e2 < NEXP; ++e2) {
    float s = 0.f;
    #pragma unroll
    for (int j = 0; j < 4; ++j) s = fmaf(xd[j], rw[e2 * DMODEL + lane * 4 + j], s);
    p[e2] = warp_sum(s) + rb[e2];
  }
  if (lane < NEXP) {
    int e2 = lane;
    int rank = 0;
    #pragma unroll
    for (int j = 0; j < NEXP; ++j)
      if (j != e2 && (p[j] > p[e2] || (p[j] == p[e2] && j < e2))) ++rank;
    if (rank < 2) {
      int idx = atomicAdd(&cnt[e2], 1);
      list[e2 * TTOK + idx] = gw;
    }
  }
}

__global__ void k_cls(const float* __restrict__ cls, float* __restrict__ tok) {
  tok[(size_t)blockIdx.x * SEQL * DMODEL + threadIdx.x] = cls[threadIdx.x];
}

__global__ __launch_bounds__(256) void k_head(const float* __restrict__ tok,
                                              const float* __restrict__ hw,
                                              const float* __restrict__ hb,
                                              float* __restrict__ out) {
  int b = blockIdx.x;
  int w = threadIdx.x >> 6, lane = threadIdx.x & 63;
  const float* row = tok + (size_t)b * SEQL * DMODEL;  // token 0
  for (int c = w; c < NCLS; c += 4) {
    float s = 0.f;
    for (int d = lane; d < DMODEL; d += 64) s = fmaf(row[d], hw[c * DMODEL + d], s);
    s = warp_sum(s);
    if (lane == 0) out[b * NCLS + c] = s + hb[c];
  }
}

extern "C" void kernel_launch(void* const* d_in, const int* in_sizes, int n_in,
                              void* d_out, int out_size, void* d_ws, size_t ws_size,
                              hipStream_t stream) {
  const float* x      = (const float*)d_in[0];
  const float* conv_w = (const float*)d_in[1];
  const float* conv_b = (const float*)d_in[2];
  const float* cls    = (const float*)d_in[3];
  const float* ln1g   = (const float*)d_in[4];
  const float* ln1b   = (const float*)d_in[5];
  const float* qkv_w  = (const float*)d_in[6];
  const float* qkv_b  = (const float*)d_in[7];
  const float* out_w  = (const float*)d_in[8];
  const float* out_b  = (const float*)d_in[9];
  const float* ln2g   = (const float*)d_in[10];
  const float* ln2b   = (const float*)d_in[11];
  const float* rw     = (const float*)d_in[12];
  const float* rb     = (const float*)d_in[13];
  const float* e_w1   = (const float*)d_in[14];
  const float* e_b1   = (const float*)d_in[15];
  const float* e_w2   = (const float*)d_in[16];
  const float* e_b2   = (const float*)d_in[17];
  const float* head_w = (const float*)d_in[18];
  const float* head_b = (const float*)d_in[19];
  float* out = (float*)d_out;

  char* ws = (char*)d_ws;
  size_t off = 0;
  auto alloc = [&](size_t bytes) {
    void* p = ws + off;
    off += (bytes + 255) & ~(size_t)255;
    return p;
  };
  float* tok  = (float*)alloc((size_t)TTOK * DMODEL * 4);      // 25.8 MB
  u16*   x2h  = (u16*)alloc((size_t)TTOK * DMODEL * 2);        // 12.9
  u16*   x2l  = (u16*)alloc((size_t)TTOK * DMODEL * 2);        // 12.9
  u16*   qkvh = (u16*)alloc((size_t)TTOK * 768 * 2);           // 38.7
  u16*   qkvl = (u16*)alloc((size_t)TTOK * 768 * 2);           // 38.7
  u16*   aoh  = (u16*)alloc((size_t)TTOK * DMODEL * 2);        // 12.9
  u16*   aol  = (u16*)alloc((size_t)TTOK * DMODEL * 2);        // 12.9
  u16*   cwh  = (u16*)alloc((size_t)DMODEL * CONVK * 2);
  u16*   cwl  = (u16*)alloc((size_t)DMODEL * CONVK * 2);
  u16*   qwh  = (u16*)alloc((size_t)768 * DMODEL * 2);
  u16*   qwl  = (u16*)alloc((size_t)768 * DMODEL * 2);
  u16*   owh  = (u16*)alloc((size_t)DMODEL * DMODEL * 2);
  u16*   owl  = (u16*)alloc((size_t)DMODEL * DMODEL * 2);
  u16*   w1T  = (u16*)alloc((size_t)NEXP * FFD * DMODEL * 2);  // 2.1
  u16*   w2T  = (u16*)alloc((size_t)NEXP * DMODEL * FFD * 2);  // 2.1
  int*   cnt  = (int*)alloc(256);
  int*   list = (int*)alloc((size_t)NEXP * TTOK * 4);
  // aliases (lifetimes disjoint, stream-ordered):
  u16* Acvh = qkvh;                 // im2col hi: dead before qkv GEMM writes qkvh
  u16* Acvl = qkvl;
  u16* hid  = qkvh;                 // MoE hidden (51.6 MB <= 77.4): qkv dead after attn

  hipMemsetAsync(cnt, 0, NEXP * sizeof(int), stream);

  // weight splits / transposes
  k_cast2<<<192, 256, 0, stream>>>(conv_w, cwh, cwl);
  k_cast2<<<192, 256, 0, stream>>>(qkv_w, qwh, qwl);
  k_cast2<<<64, 256, 0, stream>>>(out_w, owh, owl);
  k_castT<<<dim3(FFD / 32, DMODEL / 32, NEXP), 256, 0, stream>>>(e_w1, w1T, DMODEL, FFD);
  k_castT<<<dim3(DMODEL / 32, FFD / 32, NEXP), 256, 0, stream>>>(e_w2, w2T, FFD, DMODEL);

  // patch embed (split GEMM, fp32 out into tok with CMAP)
  k_im2col<<<(CM * CONVK / 8) / 256, 256, 0, stream>>>(x, Acvh, Acvl);
  k_mm<1,0,0,0,0,0,1,0><<<dim3(CM / 128, 2), 256, 0, stream>>>(
      Acvh, Acvl, cwh, cwl, conv_b, tok, nullptr, nullptr, DMODEL,
      CM, CONVK, nullptr, nullptr);
  k_cls<<<NBATCH, DMODEL, 0, stream>>>(cls, tok);

  // attention block (split GEMMs)
  k_ln<<<TTOK, 256, 0, stream>>>(tok, x2h, x2l, ln1g, ln1b);
  k_mm<1,0,1,0,0,0,0,0><<<dim3(TTOK / 128, 6), 256, 0, stream>>>(
      x2h, x2l, qwh, qwl, qkv_b, nullptr, qkvh, qkvl, 768,
      TTOK, DMODEL, nullptr, nullptr);
  k_attn<<<NBATCH * NHEADS, 512, 0, stream>>>(qkvh, qkvl, aoh, aol);
  k_mm<1,0,0,1,0,0,0,0><<<dim3(TTOK / 128, 2), 256, 0, stream>>>(
      aoh, aol, owh, owl, out_b, tok, nullptr, nullptr, DMODEL,
      TTOK, DMODEL, nullptr, nullptr);

  // MoE block (plain bf16 GEMMs; router from fp32 tok, inline LN)
  k_router<<<TTOK / 4, 256, 0, stream>>>(tok, ln2g, ln2b, rw, rb, cnt, list);
  k_ln<<<TTOK, 256, 0, stream>>>(tok, x2h, nullptr, ln2g, ln2b);
  for (int e = 0; e < NEXP; ++e) {
    k_mm<0,1,1,0,1,0,0,1><<<dim3(TTOK / 128, FFD / 128), 256, 0, stream>>>(
        x2h, nullptr, w1T + (size_t)e * FFD * DMODEL, nullptr,
        e_b1 + (size_t)e * FFD, nullptr, hid, nullptr, FFD,
        0, DMODEL, cnt + e, list + (size_t)e * TTOK);
    k_mm<0,0,0,1,0,1,0,1><<<dim3(TTOK / 128, DMODEL / 128), 256, 0, stream>>>(
        hid, nullptr, w2T + (size_t)e * DMODEL * FFD, nullptr,
        e_b2 + (size_t)e * DMODEL, tok, nullptr, nullptr, DMODEL,
        0, FFD, cnt + e, list + (size_t)e * TTOK);
  }

  // head
  k_head<<<NBATCH, 256, 0, stream>>>(tok, head_w, head_b, out);
}

// Round 4
// 1043.256 us; speedup vs baseline: 3.7138x; 1.2206x over previous
//
#include <hip/hip_runtime.h>
#include <hip/hip_bf16.h>
#include <math.h>

#define TTOK   25216      // 128*197
#define SEQL   197
#define NBATCH 128
#define DMODEL 256
#define NHEADS 8
#define FFD    1024
#define NEXP   4
#define NCLS   38
#define CONVK  768
#define NPATCH 196
#define CM     25088      // conv GEMM rows = 128*196

typedef unsigned short u16;
using s16x8 = __attribute__((ext_vector_type(8))) short;
using f32x4 = __attribute__((ext_vector_type(4))) float;

__device__ __forceinline__ float b2f(u16 v) {
  union { unsigned u; float f; } x; x.u = (unsigned)v << 16; return x.f;
}
__device__ __forceinline__ u16 f2b(float f) {
  __hip_bfloat16 h = __float2bfloat16(f);
  return *reinterpret_cast<u16*>(&h);
}
__device__ __forceinline__ void gload16(const void* g, void* l) {
  __builtin_amdgcn_global_load_lds(
      (const __attribute__((address_space(1))) void*)g,
      (__attribute__((address_space(3))) void*)l, 16, 0, 0);
}
__device__ __forceinline__ float warp_sum(float v) {
  #pragma unroll
  for (int o = 32; o; o >>= 1) v += __shfl_xor(v, o);
  return v;
}

// ---------------- fp32 -> bf16 hi/lo split cast (n % 1024 == 0) --------------
__global__ __launch_bounds__(256) void k_cast2(const float* __restrict__ in,
                                               u16* __restrict__ hi,
                                               u16* __restrict__ lo) {
  int i = (blockIdx.x * 256 + threadIdx.x) * 4;
  float4 v = *(const float4*)&in[i];
  float vv[4] = {v.x, v.y, v.z, v.w};
  u16 h[4], l[4];
  #pragma unroll
  for (int j = 0; j < 4; ++j) {
    h[j] = f2b(vv[j]);
    l[j] = f2b(vv[j] - b2f(h[j]));
  }
  *(uint2*)&hi[i] = *(const uint2*)h;
  *(uint2*)&lo[i] = *(const uint2*)l;
}

// ---------------- transpose+cast: in[R][C] fp32 -> out[C][R] bf16 (single) ---
__global__ __launch_bounds__(256) void k_castT(const float* __restrict__ in,
                                               u16* __restrict__ out, int R, int C) {
  in  += (size_t)blockIdx.z * R * C;
  out += (size_t)blockIdx.z * R * C;
  __shared__ float t[32][33];
  int c0 = blockIdx.x * 32, r0 = blockIdx.y * 32;
  int xx = threadIdx.x & 31, yy = threadIdx.x >> 5;
  for (int i = yy; i < 32; i += 8)
    t[i][xx] = in[(size_t)(r0 + i) * C + c0 + xx];
  __syncthreads();
  for (int i = yy; i < 32; i += 8)
    out[(size_t)(c0 + i) * R + r0 + xx] = f2b(t[xx][i]);
}

// ---------------- im2col + split cast: x fp32 -> Acv hi/lo [25088][768] ------
__global__ __launch_bounds__(256) void k_im2col(const float* __restrict__ x,
                                                u16* __restrict__ Ah,
                                                u16* __restrict__ Al) {
  long idx = ((long)blockIdx.x * 256 + threadIdx.x) * 8;
  int m = (int)(idx / CONVK), k = (int)(idx % CONVK);
  int b = m / NPATCH, p = m - b * NPATCH;
  int py = p / 14, px = p - py * 14;
  int c = k >> 8, r = k & 255;
  int ry = r >> 4, rx = r & 15;                       // rx in {0, 8}
  const float* src = &x[(((long)(b * 3 + c) * 224) + py * 16 + ry) * 224 +
                        px * 16 + rx];
  u16 h[8], l[8];
  #pragma unroll
  for (int j = 0; j < 8; ++j) {
    float v = src[j];
    h[j] = f2b(v);
    l[j] = f2b(v - b2f(h[j]));
  }
  *(uint4*)&Ah[idx] = *(const uint4*)h;
  *(uint4*)&Al[idx] = *(const uint4*)l;
}

// ---------------- bf16(x2) MFMA GEMM -----------------------------------------
// C[m][n] = op( sum_k A[m][k]*W[n][k] + bias[n] )
// SPLIT: A=Ah+Al, W=Wh+Wl, acc = AhWh + AhWl + AlWh  (fp32-class accuracy)
template<int SPLIT, int GELU, int OUTBF, int ADDC, int GATHER, int SCATTER, int CMAP, int DYNM>
__global__ __launch_bounds__(256) void k_mm(
    const u16* __restrict__ Ah, const u16* __restrict__ Al,
    const u16* __restrict__ Wh, const u16* __restrict__ Wl,
    const float* __restrict__ bias,
    float* __restrict__ Cf, u16* __restrict__ Cb, u16* __restrict__ Cb2, int ldc,
    int M, int K, const int* __restrict__ cntp, const int* __restrict__ list) {
  const int rows = DYNM ? *cntp : M;
  const int m0 = blockIdx.x * 128;
  if (m0 >= rows) return;
  const int n0 = blockIdx.y * 128;
  __shared__ u16 As[(SPLIT ? 2 : 1) * 128 * 64];
  __shared__ u16 Bs[(SPLIT ? 2 : 1) * 128 * 64];
  const int tid = threadIdx.x;
  const int lane = tid & 63;
  const int wv = tid >> 6;
  const int wr = wv >> 1, wc = wv & 1;
  f32x4 acc[4][4] = {};

  long aoff[4], woff[4]; int rofs[4];
  #pragma unroll
  for (int i = 0; i < 4; ++i) {
    int off = i * 4096 + tid * 16;
    int row = off >> 7;
    int c16 = (off >> 4) & 7;
    int kk = (c16 ^ (row & 7)) << 3;
    int ar = m0 + row;
    if (DYNM) ar = ar < rows ? ar : rows - 1;
    aoff[i] = GATHER ? (long)list[ar] * K + kk : (long)ar * K + kk;
    woff[i] = (long)(n0 + row) * K + kk;
    rofs[i] = off;
  }
  for (int kc = 0; kc < K; kc += 64) {
    #pragma unroll
    for (int i = 0; i < 4; ++i) {
      gload16(Ah + aoff[i] + kc, (char*)As + rofs[i]);
      gload16(Wh + woff[i] + kc, (char*)Bs + rofs[i]);
      if (SPLIT) {
        gload16(Al + aoff[i] + kc, (char*)As + 16384 + rofs[i]);
        gload16(Wl + woff[i] + kc, (char*)Bs + 16384 + rofs[i]);
      }
    }
    __syncthreads();
    #pragma unroll
    for (int kf = 0; kf < 2; ++kf) {
      s16x8 ah[4], bh[4], al[4], bl[4];
      #pragma unroll
      for (int i = 0; i < 4; ++i) {
        int rowa = wr * 64 + i * 16 + (lane & 15);
        int kb = (kf * 64 + ((lane >> 4) << 4)) ^ ((rowa & 7) << 4);
        ah[i] = *(const s16x8*)((const char*)As + rowa * 128 + kb);
        if (SPLIT) al[i] = *(const s16x8*)((const char*)As + 16384 + rowa * 128 + kb);
        int rowb = wc * 64 + i * 16 + (lane & 15);
        int kbn = (kf * 64 + ((lane >> 4) << 4)) ^ ((rowb & 7) << 4);
        bh[i] = *(const s16x8*)((const char*)Bs + rowb * 128 + kbn);
        if (SPLIT) bl[i] = *(const s16x8*)((const char*)Bs + 16384 + rowb * 128 + kbn);
      }
      #pragma unroll
      for (int i = 0; i < 4; ++i)
        #pragma unroll
        for (int j = 0; j < 4; ++j)
          acc[i][j] = __builtin_amdgcn_mfma_f32_16x16x32_bf16(ah[i], bh[j],
                                                              acc[i][j], 0, 0, 0);
      if (SPLIT) {
        #pragma unroll
        for (int i = 0; i < 4; ++i)
          #pragma unroll
          for (int j = 0; j < 4; ++j)
            acc[i][j] = __builtin_amdgcn_mfma_f32_16x16x32_bf16(ah[i], bl[j],
                                                                acc[i][j], 0, 0, 0);
        #pragma unroll
        for (int i = 0; i < 4; ++i)
          #pragma unroll
          for (int j = 0; j < 4; ++j)
            acc[i][j] = __builtin_amdgcn_mfma_f32_16x16x32_bf16(al[i], bh[j],
                                                                acc[i][j], 0, 0, 0);
      }
    }
    __syncthreads();
  }
  const int mb = m0 + wr * 64 + ((lane >> 4) << 2);
  const int nb = n0 + wc * 64 + (lane & 15);
  #pragma unroll
  for (int i = 0; i < 4; ++i) {
    #pragma unroll
    for (int jf = 0; jf < 4; ++jf) {
      #pragma unroll
      for (int j = 0; j < 4; ++j) {
        int m = mb + i * 16 + j;
        int n = nb + jf * 16;
        if (DYNM && m >= rows) continue;
        float v = acc[i][jf][j] + bias[n];
        if (GELU) v = 0.5f * v * (1.0f + erff(v * 0.70710678118654752f));
        long cr;
        if (SCATTER)     cr = list[m];
        else if (CMAP) { int bq = m / NPATCH; cr = (long)bq * SEQL + (m - bq * NPATCH) + 1; }
        else             cr = m;
        if (OUTBF) {
          u16 h = f2b(v);
          Cb[cr * ldc + n] = h;
          if (Cb2) Cb2[cr * ldc + n] = f2b(v - b2f(h));
        } else if (ADDC) {
          Cf[cr * ldc + n] += v;
        } else {
          Cf[cr * ldc + n] = v;
        }
      }
    }
  }
}

// ---------------- LayerNorm over D=256: bf16 hi (+optional lo) out -----------
__global__ __launch_bounds__(256) void k_ln(const float* __restrict__ in,
                                            u16* __restrict__ outh,
                                            u16* __restrict__ outl,
                                            const float* __restrict__ g,
                                            const float* __restrict__ bb) {
  const int row = blockIdx.x;
  const int tid = threadIdx.x;
  float v = in[(size_t)row * DMODEL + tid];
  float s1 = warp_sum(v), s2 = warp_sum(v * v);
  __shared__ float a1[4], a2[4];
  int w = tid >> 6, lane = tid & 63;
  if (lane == 0) { a1[w] = s1; a2[w] = s2; }
  __syncthreads();
  s1 = a1[0] + a1[1] + a1[2] + a1[3];
  s2 = a2[0] + a2[1] + a2[2] + a2[3];
  float mu = s1 * (1.f / DMODEL);
  float var = s2 * (1.f / DMODEL) - mu * mu;
  float rs = rsqrtf(var + 1e-5f);
  float r = (v - mu) * rs * g[tid] + bb[tid];
  u16 h = f2b(r);
  outh[(size_t)row * DMODEL + tid] = h;
  if (outl) outl[(size_t)row * DMODEL + tid] = f2b(r - b2f(h));
}

// ---------------- MFMA fused attention, split precision ----------------------
// block = (b,h); 4 waves; 13 q-tiles of 16; K-frags from global; V transposed in LDS;
// P via per-wave LDS round-trip (hi then lo). All LDS zeroed so padding is exact 0.
#define LDP 232
__global__ __launch_bounds__(256) void k_attn(const u16* __restrict__ qh,
                                              const u16* __restrict__ ql,
                                              u16* __restrict__ aoh,
                                              u16* __restrict__ aol) {
  const int bh = blockIdx.x;
  const int b = bh >> 3, h = bh & 7;
  __shared__ __align__(16) u16 lds[2 * 32 * LDP + 4 * 16 * LDP];
  u16* Vt = lds;                               // [2][32][LDP] (hi, lo)
  const int tid = threadIdx.x, lane = tid & 63, w = tid >> 6;
  u16* P = lds + 2 * 32 * LDP + w * 16 * LDP;  // per-wave [16][LDP]

  for (int i = tid; i < (int)(sizeof(lds) / 4); i += 256) ((unsigned*)lds)[i] = 0;
  __syncthreads();

  const u16* bqh = qh + (size_t)b * SEQL * 768;
  const u16* bql = ql + (size_t)b * SEQL * 768;
  // stage V transposed: Vt[d][s] = V[s][d]
  #pragma unroll
  for (int it = 0; it < 4; ++it) {
    int s = (tid >> 2) + it * 64, c = tid & 3;
    if (s < SEQL) {
      s16x8 vh = *(const s16x8*)(bqh + (size_t)s * 768 + 512 + h * 32 + c * 8);
      s16x8 vl = *(const s16x8*)(bql + (size_t)s * 768 + 512 + h * 32 + c * 8);
      #pragma unroll
      for (int i = 0; i < 8; ++i) {
        Vt[(c * 8 + i) * LDP + s] = (u16)vh[i];
        Vt[(32 + c * 8 + i) * LDP + s] = (u16)vl[i];
      }
    }
  }
  __syncthreads();

  const int l15 = lane & 15, l4 = lane >> 4;
  for (int it = 0; it < 4; ++it) {
    const int qt = it * 4 + w;
    const bool act = qt < 13;
    f32x4 sc[13];
    float inv[4];
    if (act) {
      int qrow = qt * 16 + l15;
      int qcl = qrow < SEQL ? qrow : SEQL - 1;
      s16x8 qfh = *(const s16x8*)(bqh + (size_t)qcl * 768 + h * 32 + l4 * 8);
      s16x8 qfl = *(const s16x8*)(bql + (size_t)qcl * 768 + h * 32 + l4 * 8);
      #pragma unroll
      for (int j = 0; j < 13; ++j) {
        int key = j * 16 + l15;
        int kcl = key < SEQL ? key : SEQL - 1;
        s16x8 kfh = *(const s16x8*)(bqh + (size_t)kcl * 768 + 256 + h * 32 + l4 * 8);
        s16x8 kfl = *(const s16x8*)(bql + (size_t)kcl * 768 + 256 + h * 32 + l4 * 8);
        f32x4 c = {};
        c = __builtin_amdgcn_mfma_f32_16x16x32_bf16(qfh, kfh, c, 0, 0, 0);
        c = __builtin_amdgcn_mfma_f32_16x16x32_bf16(qfh, kfl, c, 0, 0, 0);
        c = __builtin_amdgcn_mfma_f32_16x16x32_bf16(qfl, kfh, c, 0, 0, 0);
        sc[j] = c;
      }
      // softmax over 208 keys (rows r = l4*4+jj, cols j*16+l15)
      float mr[4] = {-1e30f, -1e30f, -1e30f, -1e30f};
      #pragma unroll
      for (int j = 0; j < 13; ++j) {
        float msk = (j * 16 + l15) < SEQL ? 0.f : -1e30f;
        #pragma unroll
        for (int jj = 0; jj < 4; ++jj) {
          float s = sc[j][jj] * 0.17677669529663687f + msk;
          sc[j][jj] = s;
          mr[jj] = fmaxf(mr[jj], s);
        }
      }
      #pragma unroll
      for (int o = 1; o <= 8; o <<= 1)
        #pragma unroll
        for (int jj = 0; jj < 4; ++jj) mr[jj] = fmaxf(mr[jj], __shfl_xor(mr[jj], o));
      float sm[4] = {0.f, 0.f, 0.f, 0.f};
      #pragma unroll
      for (int j = 0; j < 13; ++j)
        #pragma unroll
        for (int jj = 0; jj < 4; ++jj) {
          float e = __expf(sc[j][jj] - mr[jj]);
          sc[j][jj] = e;
          sm[jj] += e;
        }
      #pragma unroll
      for (int o = 1; o <= 8; o <<= 1)
        #pragma unroll
        for (int jj = 0; jj < 4; ++jj) sm[jj] += __shfl_xor(sm[jj], o);
      #pragma unroll
      for (int jj = 0; jj < 4; ++jj) inv[jj] = 1.f / sm[jj];
      // write P hi
      #pragma unroll
      for (int j = 0; j < 13; ++j)
        #pragma unroll
        for (int jj = 0; jj < 4; ++jj)
          P[(l4 * 4 + jj) * LDP + j * 16 + l15] = f2b(sc[j][jj]);
    }
    __syncthreads();
    s16x8 pfh[7], pfl[7];
    if (act) {
      #pragma unroll
      for (int c = 0; c < 7; ++c)
        pfh[c] = *(const s16x8*)(P + l15 * LDP + c * 32 + l4 * 8);
    }
    __syncthreads();
    if (act) {
      // write P lo
      #pragma unroll
      for (int j = 0; j < 13; ++j)
        #pragma unroll
        for (int jj = 0; jj < 4; ++jj) {
          float v = sc[j][jj];
          P[(l4 * 4 + jj) * LDP + j * 16 + l15] = f2b(v - b2f(f2b(v)));
        }
    }
    __syncthreads();
    if (act) {
      #pragma unroll
      for (int c = 0; c < 7; ++c)
        pfl[c] = *(const s16x8*)(P + l15 * LDP + c * 32 + l4 * 8);
      f32x4 o0 = {}, o1 = {};
      #pragma unroll
      for (int c = 0; c < 7; ++c) {
        s16x8 v0h = *(const s16x8*)(Vt + l15 * LDP + c * 32 + l4 * 8);
        s16x8 v1h = *(const s16x8*)(Vt + (16 + l15) * LDP + c * 32 + l4 * 8);
        s16x8 v0l = *(const s16x8*)(Vt + (32 + l15) * LDP + c * 32 + l4 * 8);
        s16x8 v1l = *(const s16x8*)(Vt + (48 + l15) * LDP + c * 32 + l4 * 8);
        o0 = __builtin_amdgcn_mfma_f32_16x16x32_bf16(pfh[c], v0h, o0, 0, 0, 0);
        o0 = __builtin_amdgcn_mfma_f32_16x16x32_bf16(pfh[c], v0l, o0, 0, 0, 0);
        o0 = __builtin_amdgcn_mfma_f32_16x16x32_bf16(pfl[c], v0h, o0, 0, 0, 0);
        o1 = __builtin_amdgcn_mfma_f32_16x16x32_bf16(pfh[c], v1h, o1, 0, 0, 0);
        o1 = __builtin_amdgcn_mfma_f32_16x16x32_bf16(pfh[c], v1l, o1, 0, 0, 0);
        o1 = __builtin_amdgcn_mfma_f32_16x16x32_bf16(pfl[c], v1h, o1, 0, 0, 0);
      }
      #pragma unroll
      for (int jj = 0; jj < 4; ++jj) {
        int qrow2 = qt * 16 + l4 * 4 + jj;
        if (qrow2 < SEQL) {
          size_t o = ((size_t)b * SEQL + qrow2) * DMODEL + h * 32 + l15;
          float v0 = o0[jj] * inv[jj], v1 = o1[jj] * inv[jj];
          u16 h0 = f2b(v0), h1 = f2b(v1);
          aoh[o] = h0;
          aol[o] = f2b(v0 - b2f(h0));
          aoh[o + 16] = h1;
          aol[o + 16] = f2b(v1 - b2f(h1));
        }
      }
    }
  }
}

// ---------------- router: inline LN2 on fp32 tok -> exact-ish top-2 ----------
__global__ __launch_bounds__(256) void k_router(const float* __restrict__ tok,
                                                const float* __restrict__ g,
                                                const float* __restrict__ bb,
                                                const float* __restrict__ rw,
                                                const float* __restrict__ rb,
                                                int* __restrict__ cnt,
                                                int* __restrict__ list) {
  int gw = (blockIdx.x * 256 + threadIdx.x) >> 6;
  int lane = threadIdx.x & 63;
  if (gw >= TTOK) return;
  const float* row = tok + (size_t)gw * DMODEL;
  float vv[4];
  *(float4*)vv = *(const float4*)&row[lane * 4];
  float s1 = vv[0] + vv[1] + vv[2] + vv[3];
  float s2 = vv[0]*vv[0] + vv[1]*vv[1] + vv[2]*vv[2] + vv[3]*vv[3];
  s1 = warp_sum(s1);
  s2 = warp_sum(s2);
  float mu = s1 * (1.f / DMODEL);
  float var = s2 * (1.f / DMODEL) - mu * mu;
  float rs = rsqrtf(var + 1e-5f);
  float xd[4];
  #pragma unroll
  for (int j = 0; j < 4; ++j)
    xd[j] = (vv[j] - mu) * rs * g[lane * 4 + j] + bb[lane * 4 + j];
  float p[NEXP];
  #pragma unroll
  for (int e2 = 0; e2 < NEXP; ++e2) {
    float s = 0.f;
    #pragma unroll
    for (int j = 0; j < 4; ++j) s = fmaf(xd[j], rw[e2 * DMODEL + lane * 4 + j], s);
    p[e2] = warp_sum(s) + rb[e2];
  }
  if (lane < NEXP) {
    int e2 = lane;
    int rank = 0;
    #pragma unroll
    for (int j = 0; j < NEXP; ++j)
      if (j != e2 && (p[j] > p[e2] || (p[j] == p[e2] && j < e2))) ++rank;
    if (rank < 2) {
      int idx = atomicAdd(&cnt[e2], 1);
      list[e2 * TTOK + idx] = gw;
    }
  }
}

__global__ void k_cls(const float* __restrict__ cls, float* __restrict__ tok) {
  tok[(size_t)blockIdx.x * SEQL * DMODEL + threadIdx.x] = cls[threadIdx.x];
}

__global__ __launch_bounds__(256) void k_head(const float* __restrict__ tok,
                                              const float* __restrict__ hw,
                                              const float* __restrict__ hb,
                                              float* __restrict__ out) {
  int b = blockIdx.x;
  int w = threadIdx.x >> 6, lane = threadIdx.x & 63;
  const float* row = tok + (size_t)b * SEQL * DMODEL;  // token 0
  for (int c = w; c < NCLS; c += 4) {
    float s = 0.f;
    for (int d = lane; d < DMODEL; d += 64) s = fmaf(row[d], hw[c * DMODEL + d], s);
    s = warp_sum(s);
    if (lane == 0) out[b * NCLS + c] = s + hb[c];
  }
}

extern "C" void kernel_launch(void* const* d_in, const int* in_sizes, int n_in,
                              void* d_out, int out_size, void* d_ws, size_t ws_size,
                              hipStream_t stream) {
  const float* x      = (const float*)d_in[0];
  const float* conv_w = (const float*)d_in[1];
  const float* conv_b = (const float*)d_in[2];
  const float* cls    = (const float*)d_in[3];
  const float* ln1g   = (const float*)d_in[4];
  const float* ln1b   = (const float*)d_in[5];
  const float* qkv_w  = (const float*)d_in[6];
  const float* qkv_b  = (const float*)d_in[7];
  const float* out_w  = (const float*)d_in[8];
  const float* out_b  = (const float*)d_in[9];
  const float* ln2g   = (const float*)d_in[10];
  const float* ln2b   = (const float*)d_in[11];
  const float* rw     = (const float*)d_in[12];
  const float* rb     = (const float*)d_in[13];
  const float* e_w1   = (const float*)d_in[14];
  const float* e_b1   = (const float*)d_in[15];
  const float* e_w2   = (const float*)d_in[16];
  const float* e_b2   = (const float*)d_in[17];
  const float* head_w = (const float*)d_in[18];
  const float* head_b = (const float*)d_in[19];
  float* out = (float*)d_out;

  char* ws = (char*)d_ws;
  size_t off = 0;
  auto alloc = [&](size_t bytes) {
    void* p = ws + off;
    off += (bytes + 255) & ~(size_t)255;
    return p;
  };
  float* tok  = (float*)alloc((size_t)TTOK * DMODEL * 4);
  u16*   x2h  = (u16*)alloc((size_t)TTOK * DMODEL * 2);
  u16*   x2l  = (u16*)alloc((size_t)TTOK * DMODEL * 2);
  u16*   qkvh = (u16*)alloc((size_t)TTOK * 768 * 2);
  u16*   qkvl = (u16*)alloc((size_t)TTOK * 768 * 2);
  u16*   aoh  = (u16*)alloc((size_t)TTOK * DMODEL * 2);
  u16*   aol  = (u16*)alloc((size_t)TTOK * DMODEL * 2);
  u16*   cwh  = (u16*)alloc((size_t)DMODEL * CONVK * 2);
  u16*   cwl  = (u16*)alloc((size_t)DMODEL * CONVK * 2);
  u16*   qwh  = (u16*)alloc((size_t)768 * DMODEL * 2);
  u16*   qwl  = (u16*)alloc((size_t)768 * DMODEL * 2);
  u16*   owh  = (u16*)alloc((size_t)DMODEL * DMODEL * 2);
  u16*   owl  = (u16*)alloc((size_t)DMODEL * DMODEL * 2);
  u16*   w1T  = (u16*)alloc((size_t)NEXP * FFD * DMODEL * 2);
  u16*   w2T  = (u16*)alloc((size_t)NEXP * DMODEL * FFD * 2);
  int*   cnt  = (int*)alloc(256);
  int*   list = (int*)alloc((size_t)NEXP * TTOK * 4);
  // aliases (lifetimes disjoint, stream-ordered):
  u16* Acvh = qkvh;                 // im2col hi: dead before qkv GEMM writes qkvh
  u16* Acvl = qkvl;
  u16* hid  = qkvh;                 // MoE hidden: qkv dead after attn

  hipMemsetAsync(cnt, 0, NEXP * sizeof(int), stream);

  // weight splits / transposes
  k_cast2<<<192, 256, 0, stream>>>(conv_w, cwh, cwl);
  k_cast2<<<192, 256, 0, stream>>>(qkv_w, qwh, qwl);
  k_cast2<<<64, 256, 0, stream>>>(out_w, owh, owl);
  k_castT<<<dim3(FFD / 32, DMODEL / 32, NEXP), 256, 0, stream>>>(e_w1, w1T, DMODEL, FFD);
  k_castT<<<dim3(DMODEL / 32, FFD / 32, NEXP), 256, 0, stream>>>(e_w2, w2T, FFD, DMODEL);

  // patch embed (split GEMM, fp32 out into tok with CMAP)
  k_im2col<<<(CM * CONVK / 8) / 256, 256, 0, stream>>>(x, Acvh, Acvl);
  k_mm<1,0,0,0,0,0,1,0><<<dim3(CM / 128, 2), 256, 0, stream>>>(
      Acvh, Acvl, cwh, cwl, conv_b, tok, nullptr, nullptr, DMODEL,
      CM, CONVK, nullptr, nullptr);
  k_cls<<<NBATCH, DMODEL, 0, stream>>>(cls, tok);

  // attention block (split GEMMs + MFMA attention)
  k_ln<<<TTOK, 256, 0, stream>>>(tok, x2h, x2l, ln1g, ln1b);
  k_mm<1,0,1,0,0,0,0,0><<<dim3(TTOK / 128, 6), 256, 0, stream>>>(
      x2h, x2l, qwh, qwl, qkv_b, nullptr, qkvh, qkvl, 768,
      TTOK, DMODEL, nullptr, nullptr);
  k_attn<<<NBATCH * NHEADS, 256, 0, stream>>>(qkvh, qkvl, aoh, aol);
  k_mm<1,0,0,1,0,0,0,0><<<dim3(TTOK / 128, 2), 256, 0, stream>>>(
      aoh, aol, owh, owl, out_b, tok, nullptr, nullptr, DMODEL,
      TTOK, DMODEL, nullptr, nullptr);

  // MoE block (plain bf16 GEMMs; router from fp32 tok, inline LN)
  k_router<<<TTOK / 4, 256, 0, stream>>>(tok, ln2g, ln2b, rw, rb, cnt, list);
  k_ln<<<TTOK, 256, 0, stream>>>(tok, x2h, nullptr, ln2g, ln2b);
  for (int e = 0; e < NEXP; ++e) {
    k_mm<0,1,1,0,1,0,0,1><<<dim3(TTOK / 128, FFD / 128), 256, 0, stream>>>(
        x2h, nullptr, w1T + (size_t)e * FFD * DMODEL, nullptr,
        e_b1 + (size_t)e * FFD, nullptr, hid, nullptr, FFD,
        0, DMODEL, cnt + e, list + (size_t)e * TTOK);
    k_mm<0,0,0,1,0,1,0,1><<<dim3(TTOK / 128, DMODEL / 128), 256, 0, stream>>>(
        hid, nullptr, w2T + (size_t)e * DMODEL * FFD, nullptr,
        e_b2 + (size_t)e * DMODEL, tok, nullptr, nullptr, DMODEL,
        0, FFD, cnt + e, list + (size_t)e * TTOK);
  }

  // head
  k_head<<<NBATCH, 256, 0, stream>>>(tok, head_w, head_b, out);
}

// Round 5
// 756.633 us; speedup vs baseline: 5.1206x; 1.3788x over previous
//
#include <hip/hip_runtime.h>
#include <hip/hip_bf16.h>
#include <math.h>

#define TTOK   25216      // 128*197
#define SEQL   197
#define NBATCH 128
#define DMODEL 256
#define NHEADS 8
#define FFD    1024
#define NEXP   4
#define NCLS   38
#define CONVK  768
#define NPATCH 196
#define CM     25088      // conv GEMM rows = 128*196
#define NTB    64         // tokens per router block (394*64 = 25216 exactly)

typedef unsigned short u16;
using s16x8 = __attribute__((ext_vector_type(8))) short;
using f32x4 = __attribute__((ext_vector_type(4))) float;

__device__ __forceinline__ float b2f(u16 v) {
  union { unsigned u; float f; } x; x.u = (unsigned)v << 16; return x.f;
}
__device__ __forceinline__ u16 f2b(float f) {
  __hip_bfloat16 h = __float2bfloat16(f);
  return *reinterpret_cast<u16*>(&h);
}
__device__ __forceinline__ void gload16(const void* g, void* l) {
  __builtin_amdgcn_global_load_lds(
      (const __attribute__((address_space(1))) void*)g,
      (__attribute__((address_space(3))) void*)l, 16, 0, 0);
}
__device__ __forceinline__ float warp_sum(float v) {
  #pragma unroll
  for (int o = 32; o; o >>= 1) v += __shfl_xor(v, o);
  return v;
}

// ---------------- fp32 -> bf16 hi/lo split cast (n % 1024 == 0) --------------
__global__ __launch_bounds__(256) void k_cast2(const float* __restrict__ in,
                                               u16* __restrict__ hi,
                                               u16* __restrict__ lo) {
  int i = (blockIdx.x * 256 + threadIdx.x) * 4;
  float4 v = *(const float4*)&in[i];
  float vv[4] = {v.x, v.y, v.z, v.w};
  u16 h[4], l[4];
  #pragma unroll
  for (int j = 0; j < 4; ++j) {
    h[j] = f2b(vv[j]);
    l[j] = f2b(vv[j] - b2f(h[j]));
  }
  *(uint2*)&hi[i] = *(const uint2*)h;
  *(uint2*)&lo[i] = *(const uint2*)l;
}

// ---------------- transpose+cast: in[R][C] fp32 -> out[C][R] bf16 (single) ---
__global__ __launch_bounds__(256) void k_castT(const float* __restrict__ in,
                                               u16* __restrict__ out, int R, int C) {
  in  += (size_t)blockIdx.z * R * C;
  out += (size_t)blockIdx.z * R * C;
  __shared__ float t[32][33];
  int c0 = blockIdx.x * 32, r0 = blockIdx.y * 32;
  int xx = threadIdx.x & 31, yy = threadIdx.x >> 5;
  for (int i = yy; i < 32; i += 8)
    t[i][xx] = in[(size_t)(r0 + i) * C + c0 + xx];
  __syncthreads();
  for (int i = yy; i < 32; i += 8)
    out[(size_t)(c0 + i) * R + r0 + xx] = f2b(t[xx][i]);
}

// ---------------- im2col + split cast: x fp32 -> Acv hi/lo [25088][768] ------
__global__ __launch_bounds__(256) void k_im2col(const float* __restrict__ x,
                                                u16* __restrict__ Ah,
                                                u16* __restrict__ Al) {
  long idx = ((long)blockIdx.x * 256 + threadIdx.x) * 8;
  int m = (int)(idx / CONVK), k = (int)(idx % CONVK);
  int b = m / NPATCH, p = m - b * NPATCH;
  int py = p / 14, px = p - py * 14;
  int c = k >> 8, r = k & 255;
  int ry = r >> 4, rx = r & 15;                       // rx in {0, 8}
  const float* src = &x[(((long)(b * 3 + c) * 224) + py * 16 + ry) * 224 +
                        px * 16 + rx];
  u16 h[8], l[8];
  #pragma unroll
  for (int j = 0; j < 8; ++j) {
    float v = src[j];
    h[j] = f2b(v);
    l[j] = f2b(v - b2f(h[j]));
  }
  *(uint4*)&Ah[idx] = *(const uint4*)h;
  *(uint4*)&Al[idx] = *(const uint4*)l;
}

// ---------------- bf16(x2) MFMA GEMM -----------------------------------------
// C[m][n] = op( sum_k A[m][k]*W[n][k] + bias[n] )
// SPLIT: A=Ah+Al, W=Wh+Wl, acc = AhWh + AhWl + AlWh  (fp32-class accuracy)
template<int SPLIT, int GELU, int OUTBF, int ADDC, int GATHER, int SCATTER, int CMAP, int DYNM>
__global__ __launch_bounds__(256) void k_mm(
    const u16* __restrict__ Ah, const u16* __restrict__ Al,
    const u16* __restrict__ Wh, const u16* __restrict__ Wl,
    const float* __restrict__ bias,
    float* __restrict__ Cf, u16* __restrict__ Cb, u16* __restrict__ Cb2, int ldc,
    int M, int K, const int* __restrict__ cntp, const int* __restrict__ list) {
  const int rows = DYNM ? *cntp : M;
  const int m0 = blockIdx.x * 128;
  if (m0 >= rows) return;
  const int n0 = blockIdx.y * 128;
  __shared__ u16 As[(SPLIT ? 2 : 1) * 128 * 64];
  __shared__ u16 Bs[(SPLIT ? 2 : 1) * 128 * 64];
  const int tid = threadIdx.x;
  const int lane = tid & 63;
  const int wv = tid >> 6;
  const int wr = wv >> 1, wc = wv & 1;
  f32x4 acc[4][4] = {};

  long aoff[4], woff[4]; int rofs[4];
  #pragma unroll
  for (int i = 0; i < 4; ++i) {
    int off = i * 4096 + tid * 16;
    int row = off >> 7;
    int c16 = (off >> 4) & 7;
    int kk = (c16 ^ (row & 7)) << 3;
    int ar = m0 + row;
    if (DYNM) ar = ar < rows ? ar : rows - 1;
    aoff[i] = GATHER ? (long)list[ar] * K + kk : (long)ar * K + kk;
    woff[i] = (long)(n0 + row) * K + kk;
    rofs[i] = off;
  }
  for (int kc = 0; kc < K; kc += 64) {
    #pragma unroll
    for (int i = 0; i < 4; ++i) {
      gload16(Ah + aoff[i] + kc, (char*)As + rofs[i]);
      gload16(Wh + woff[i] + kc, (char*)Bs + rofs[i]);
      if (SPLIT) {
        gload16(Al + aoff[i] + kc, (char*)As + 16384 + rofs[i]);
        gload16(Wl + woff[i] + kc, (char*)Bs + 16384 + rofs[i]);
      }
    }
    __syncthreads();
    #pragma unroll
    for (int kf = 0; kf < 2; ++kf) {
      s16x8 ah[4], bh[4], al[4], bl[4];
      #pragma unroll
      for (int i = 0; i < 4; ++i) {
        int rowa = wr * 64 + i * 16 + (lane & 15);
        int kb = (kf * 64 + ((lane >> 4) << 4)) ^ ((rowa & 7) << 4);
        ah[i] = *(const s16x8*)((const char*)As + rowa * 128 + kb);
        if (SPLIT) al[i] = *(const s16x8*)((const char*)As + 16384 + rowa * 128 + kb);
        int rowb = wc * 64 + i * 16 + (lane & 15);
        int kbn = (kf * 64 + ((lane >> 4) << 4)) ^ ((rowb & 7) << 4);
        bh[i] = *(const s16x8*)((const char*)Bs + rowb * 128 + kbn);
        if (SPLIT) bl[i] = *(const s16x8*)((const char*)Bs + 16384 + rowb * 128 + kbn);
      }
      #pragma unroll
      for (int i = 0; i < 4; ++i)
        #pragma unroll
        for (int j = 0; j < 4; ++j)
          acc[i][j] = __builtin_amdgcn_mfma_f32_16x16x32_bf16(ah[i], bh[j],
                                                              acc[i][j], 0, 0, 0);
      if (SPLIT) {
        #pragma unroll
        for (int i = 0; i < 4; ++i)
          #pragma unroll
          for (int j = 0; j < 4; ++j)
            acc[i][j] = __builtin_amdgcn_mfma_f32_16x16x32_bf16(ah[i], bl[j],
                                                                acc[i][j], 0, 0, 0);
        #pragma unroll
        for (int i = 0; i < 4; ++i)
          #pragma unroll
          for (int j = 0; j < 4; ++j)
            acc[i][j] = __builtin_amdgcn_mfma_f32_16x16x32_bf16(al[i], bh[j],
                                                                acc[i][j], 0, 0, 0);
      }
    }
    __syncthreads();
  }
  const int mb = m0 + wr * 64 + ((lane >> 4) << 2);
  const int nb = n0 + wc * 64 + (lane & 15);
  #pragma unroll
  for (int i = 0; i < 4; ++i) {
    #pragma unroll
    for (int jf = 0; jf < 4; ++jf) {
      #pragma unroll
      for (int j = 0; j < 4; ++j) {
        int m = mb + i * 16 + j;
        int n = nb + jf * 16;
        if (DYNM && m >= rows) continue;
        float v = acc[i][jf][j] + bias[n];
        if (GELU) v = 0.5f * v * (1.0f + erff(v * 0.70710678118654752f));
        long cr;
        if (SCATTER)     cr = list[m];
        else if (CMAP) { int bq = m / NPATCH; cr = (long)bq * SEQL + (m - bq * NPATCH) + 1; }
        else             cr = m;
        if (OUTBF) {
          u16 h = f2b(v);
          Cb[cr * ldc + n] = h;
          if (Cb2) Cb2[cr * ldc + n] = f2b(v - b2f(h));
        } else if (ADDC) {
          Cf[cr * ldc + n] += v;
        } else {
          Cf[cr * ldc + n] = v;
        }
      }
    }
  }
}

// ---------------- LayerNorm over D=256: bf16 hi (+optional lo) out -----------
__global__ __launch_bounds__(256) void k_ln(const float* __restrict__ in,
                                            u16* __restrict__ outh,
                                            u16* __restrict__ outl,
                                            const float* __restrict__ g,
                                            const float* __restrict__ bb) {
  const int row = blockIdx.x;
  const int tid = threadIdx.x;
  float v = in[(size_t)row * DMODEL + tid];
  float s1 = warp_sum(v), s2 = warp_sum(v * v);
  __shared__ float a1[4], a2[4];
  int w = tid >> 6, lane = tid & 63;
  if (lane == 0) { a1[w] = s1; a2[w] = s2; }
  __syncthreads();
  s1 = a1[0] + a1[1] + a1[2] + a1[3];
  s2 = a2[0] + a2[1] + a2[2] + a2[3];
  float mu = s1 * (1.f / DMODEL);
  float var = s2 * (1.f / DMODEL) - mu * mu;
  float rs = rsqrtf(var + 1e-5f);
  float r = (v - mu) * rs * g[tid] + bb[tid];
  u16 h = f2b(r);
  outh[(size_t)row * DMODEL + tid] = h;
  if (outl) outl[(size_t)row * DMODEL + tid] = f2b(r - b2f(h));
}

// ---------------- MFMA fused attention, split precision ----------------------
#define LDP 232
__global__ __launch_bounds__(256) void k_attn(const u16* __restrict__ qh,
                                              const u16* __restrict__ ql,
                                              u16* __restrict__ aoh,
                                              u16* __restrict__ aol) {
  const int bh = blockIdx.x;
  const int b = bh >> 3, h = bh & 7;
  __shared__ __align__(16) u16 lds[2 * 32 * LDP + 4 * 16 * LDP];
  u16* Vt = lds;                               // [2][32][LDP] (hi, lo)
  const int tid = threadIdx.x, lane = tid & 63, w = tid >> 6;
  u16* P = lds + 2 * 32 * LDP + w * 16 * LDP;  // per-wave [16][LDP]

  for (int i = tid; i < (int)(sizeof(lds) / 4); i += 256) ((unsigned*)lds)[i] = 0;
  __syncthreads();

  const u16* bqh = qh + (size_t)b * SEQL * 768;
  const u16* bql = ql + (size_t)b * SEQL * 768;
  #pragma unroll
  for (int it = 0; it < 4; ++it) {
    int s = (tid >> 2) + it * 64, c = tid & 3;
    if (s < SEQL) {
      s16x8 vh = *(const s16x8*)(bqh + (size_t)s * 768 + 512 + h * 32 + c * 8);
      s16x8 vl = *(const s16x8*)(bql + (size_t)s * 768 + 512 + h * 32 + c * 8);
      #pragma unroll
      for (int i = 0; i < 8; ++i) {
        Vt[(c * 8 + i) * LDP + s] = (u16)vh[i];
        Vt[(32 + c * 8 + i) * LDP + s] = (u16)vl[i];
      }
    }
  }
  __syncthreads();

  const int l15 = lane & 15, l4 = lane >> 4;
  for (int it = 0; it < 4; ++it) {
    const int qt = it * 4 + w;
    const bool act = qt < 13;
    f32x4 sc[13];
    float inv[4];
    if (act) {
      int qrow = qt * 16 + l15;
      int qcl = qrow < SEQL ? qrow : SEQL - 1;
      s16x8 qfh = *(const s16x8*)(bqh + (size_t)qcl * 768 + h * 32 + l4 * 8);
      s16x8 qfl = *(const s16x8*)(bql + (size_t)qcl * 768 + h * 32 + l4 * 8);
      #pragma unroll
      for (int j = 0; j < 13; ++j) {
        int key = j * 16 + l15;
        int kcl = key < SEQL ? key : SEQL - 1;
        s16x8 kfh = *(const s16x8*)(bqh + (size_t)kcl * 768 + 256 + h * 32 + l4 * 8);
        s16x8 kfl = *(const s16x8*)(bql + (size_t)kcl * 768 + 256 + h * 32 + l4 * 8);
        f32x4 c = {};
        c = __builtin_amdgcn_mfma_f32_16x16x32_bf16(qfh, kfh, c, 0, 0, 0);
        c = __builtin_amdgcn_mfma_f32_16x16x32_bf16(qfh, kfl, c, 0, 0, 0);
        c = __builtin_amdgcn_mfma_f32_16x16x32_bf16(qfl, kfh, c, 0, 0, 0);
        sc[j] = c;
      }
      float mr[4] = {-1e30f, -1e30f, -1e30f, -1e30f};
      #pragma unroll
      for (int j = 0; j < 13; ++j) {
        float msk = (j * 16 + l15) < SEQL ? 0.f : -1e30f;
        #pragma unroll
        for (int jj = 0; jj < 4; ++jj) {
          float s = sc[j][jj] * 0.17677669529663687f + msk;
          sc[j][jj] = s;
          mr[jj] = fmaxf(mr[jj], s);
        }
      }
      #pragma unroll
      for (int o = 1; o <= 8; o <<= 1)
        #pragma unroll
        for (int jj = 0; jj < 4; ++jj) mr[jj] = fmaxf(mr[jj], __shfl_xor(mr[jj], o));
      float sm[4] = {0.f, 0.f, 0.f, 0.f};
      #pragma unroll
      for (int j = 0; j < 13; ++j)
        #pragma unroll
        for (int jj = 0; jj < 4; ++jj) {
          float e = __expf(sc[j][jj] - mr[jj]);
          sc[j][jj] = e;
          sm[jj] += e;
        }
      #pragma unroll
      for (int o = 1; o <= 8; o <<= 1)
        #pragma unroll
        for (int jj = 0; jj < 4; ++jj) sm[jj] += __shfl_xor(sm[jj], o);
      #pragma unroll
      for (int jj = 0; jj < 4; ++jj) inv[jj] = 1.f / sm[jj];
      #pragma unroll
      for (int j = 0; j < 13; ++j)
        #pragma unroll
        for (int jj = 0; jj < 4; ++jj)
          P[(l4 * 4 + jj) * LDP + j * 16 + l15] = f2b(sc[j][jj]);
    }
    __syncthreads();
    s16x8 pfh[7], pfl[7];
    if (act) {
      #pragma unroll
      for (int c = 0; c < 7; ++c)
        pfh[c] = *(const s16x8*)(P + l15 * LDP + c * 32 + l4 * 8);
    }
    __syncthreads();
    if (act) {
      #pragma unroll
      for (int j = 0; j < 13; ++j)
        #pragma unroll
        for (int jj = 0; jj < 4; ++jj) {
          float v = sc[j][jj];
          P[(l4 * 4 + jj) * LDP + j * 16 + l15] = f2b(v - b2f(f2b(v)));
        }
    }
    __syncthreads();
    if (act) {
      #pragma unroll
      for (int c = 0; c < 7; ++c)
        pfl[c] = *(const s16x8*)(P + l15 * LDP + c * 32 + l4 * 8);
      f32x4 o0 = {}, o1 = {};
      #pragma unroll
      for (int c = 0; c < 7; ++c) {
        s16x8 v0h = *(const s16x8*)(Vt + l15 * LDP + c * 32 + l4 * 8);
        s16x8 v1h = *(const s16x8*)(Vt + (16 + l15) * LDP + c * 32 + l4 * 8);
        s16x8 v0l = *(const s16x8*)(Vt + (32 + l15) * LDP + c * 32 + l4 * 8);
        s16x8 v1l = *(const s16x8*)(Vt + (48 + l15) * LDP + c * 32 + l4 * 8);
        o0 = __builtin_amdgcn_mfma_f32_16x16x32_bf16(pfh[c], v0h, o0, 0, 0, 0);
        o0 = __builtin_amdgcn_mfma_f32_16x16x32_bf16(pfh[c], v0l, o0, 0, 0, 0);
        o0 = __builtin_amdgcn_mfma_f32_16x16x32_bf16(pfl[c], v0h, o0, 0, 0, 0);
        o1 = __builtin_amdgcn_mfma_f32_16x16x32_bf16(pfh[c], v1h, o1, 0, 0, 0);
        o1 = __builtin_amdgcn_mfma_f32_16x16x32_bf16(pfh[c], v1l, o1, 0, 0, 0);
        o1 = __builtin_amdgcn_mfma_f32_16x16x32_bf16(pfl[c], v1h, o1, 0, 0, 0);
      }
      #pragma unroll
      for (int jj = 0; jj < 4; ++jj) {
        int qrow2 = qt * 16 + l4 * 4 + jj;
        if (qrow2 < SEQL) {
          size_t o = ((size_t)b * SEQL + qrow2) * DMODEL + h * 32 + l15;
          float v0 = o0[jj] * inv[jj], v1 = o1[jj] * inv[jj];
          u16 h0 = f2b(v0), h1 = f2b(v1);
          aoh[o] = h0;
          aol[o] = f2b(v0 - b2f(h0));
          aoh[o + 16] = h1;
          aol[o + 16] = f2b(v1 - b2f(h1));
        }
      }
    }
  }
}

// ---------------- fused LN2 + router + hierarchical compaction ----------------
// 394 blocks x 64 tokens. Per wave: LN -> x2h (bf16) + fp32 logits -> top-2.
// LDS-local per-expert lists; ONE global atomic per (block, expert).
__global__ __launch_bounds__(256) void k_ln2_router(
    const float* __restrict__ tok,
    const float* __restrict__ g, const float* __restrict__ bb,
    const float* __restrict__ rw, const float* __restrict__ rb,
    u16* __restrict__ x2h,
    int* __restrict__ cnt, int* __restrict__ list) {
  __shared__ int lc[NEXP];
  __shared__ int base[NEXP];
  __shared__ int ll[NEXP][NTB];
  const int tid = threadIdx.x, lane = tid & 63, w = tid >> 6;
  if (tid < NEXP) lc[tid] = 0;
  __syncthreads();
  const int t0 = blockIdx.x * NTB;
  for (int i = w; i < NTB; i += 4) {
    int t = t0 + i;
    const float* row = tok + (size_t)t * DMODEL;
    float vv[4];
    *(float4*)vv = *(const float4*)&row[lane * 4];
    float s1 = vv[0] + vv[1] + vv[2] + vv[3];
    float s2 = vv[0]*vv[0] + vv[1]*vv[1] + vv[2]*vv[2] + vv[3]*vv[3];
    s1 = warp_sum(s1);
    s2 = warp_sum(s2);
    float mu = s1 * (1.f / DMODEL);
    float var = s2 * (1.f / DMODEL) - mu * mu;
    float rs = rsqrtf(var + 1e-5f);
    float xd[4]; u16 hh[4];
    #pragma unroll
    for (int j = 0; j < 4; ++j) {
      xd[j] = (vv[j] - mu) * rs * g[lane * 4 + j] + bb[lane * 4 + j];
      hh[j] = f2b(xd[j]);
    }
    *(uint2*)&x2h[(size_t)t * DMODEL + lane * 4] = *(const uint2*)hh;
    float p[NEXP];
    #pragma unroll
    for (int e2 = 0; e2 < NEXP; ++e2) {
      float s = 0.f;
      #pragma unroll
      for (int j = 0; j < 4; ++j) s = fmaf(xd[j], rw[e2 * DMODEL + lane * 4 + j], s);
      p[e2] = warp_sum(s) + rb[e2];
    }
    if (lane < NEXP) {
      int e2 = lane;
      int rank = 0;
      #pragma unroll
      for (int j = 0; j < NEXP; ++j)
        if (j != e2 && (p[j] > p[e2] || (p[j] == p[e2] && j < e2))) ++rank;
      if (rank < 2) {
        int idx = atomicAdd(&lc[e2], 1);
        ll[e2][idx] = t;
      }
    }
  }
  __syncthreads();
  if (tid < NEXP) base[tid] = atomicAdd(&cnt[tid], lc[tid]);
  __syncthreads();
  // copy: wave w handles expert w, lane i handles entry i (NTB == 64)
  if (lane < lc[w]) list[w * TTOK + base[w] + lane] = ll[w][lane];
}

__global__ void k_cls(const float* __restrict__ cls, float* __restrict__ tok) {
  tok[(size_t)blockIdx.x * SEQL * DMODEL + threadIdx.x] = cls[threadIdx.x];
}

__global__ __launch_bounds__(256) void k_head(const float* __restrict__ tok,
                                              const float* __restrict__ hw,
                                              const float* __restrict__ hb,
                                              float* __restrict__ out) {
  int b = blockIdx.x;
  int w = threadIdx.x >> 6, lane = threadIdx.x & 63;
  const float* row = tok + (size_t)b * SEQL * DMODEL;  // token 0
  for (int c = w; c < NCLS; c += 4) {
    float s = 0.f;
    for (int d = lane; d < DMODEL; d += 64) s = fmaf(row[d], hw[c * DMODEL + d], s);
    s = warp_sum(s);
    if (lane == 0) out[b * NCLS + c] = s + hb[c];
  }
}

extern "C" void kernel_launch(void* const* d_in, const int* in_sizes, int n_in,
                              void* d_out, int out_size, void* d_ws, size_t ws_size,
                              hipStream_t stream) {
  const float* x      = (const float*)d_in[0];
  const float* conv_w = (const float*)d_in[1];
  const float* conv_b = (const float*)d_in[2];
  const float* cls    = (const float*)d_in[3];
  const float* ln1g   = (const float*)d_in[4];
  const float* ln1b   = (const float*)d_in[5];
  const float* qkv_w  = (const float*)d_in[6];
  const float* qkv_b  = (const float*)d_in[7];
  const float* out_w  = (const float*)d_in[8];
  const float* out_b  = (const float*)d_in[9];
  const float* ln2g   = (const float*)d_in[10];
  const float* ln2b   = (const float*)d_in[11];
  const float* rw     = (const float*)d_in[12];
  const float* rb     = (const float*)d_in[13];
  const float* e_w1   = (const float*)d_in[14];
  const float* e_b1   = (const float*)d_in[15];
  const float* e_w2   = (const float*)d_in[16];
  const float* e_b2   = (const float*)d_in[17];
  const float* head_w = (const float*)d_in[18];
  const float* head_b = (const float*)d_in[19];
  float* out = (float*)d_out;

  char* ws = (char*)d_ws;
  size_t off = 0;
  auto alloc = [&](size_t bytes) {
    void* p = ws + off;
    off += (bytes + 255) & ~(size_t)255;
    return p;
  };
  float* tok  = (float*)alloc((size_t)TTOK * DMODEL * 4);
  u16*   x2h  = (u16*)alloc((size_t)TTOK * DMODEL * 2);
  u16*   x2l  = (u16*)alloc((size_t)TTOK * DMODEL * 2);
  u16*   qkvh = (u16*)alloc((size_t)TTOK * 768 * 2);
  u16*   qkvl = (u16*)alloc((size_t)TTOK * 768 * 2);
  u16*   aoh  = (u16*)alloc((size_t)TTOK * DMODEL * 2);
  u16*   aol  = (u16*)alloc((size_t)TTOK * DMODEL * 2);
  u16*   cwh  = (u16*)alloc((size_t)DMODEL * CONVK * 2);
  u16*   cwl  = (u16*)alloc((size_t)DMODEL * CONVK * 2);
  u16*   qwh  = (u16*)alloc((size_t)768 * DMODEL * 2);
  u16*   qwl  = (u16*)alloc((size_t)768 * DMODEL * 2);
  u16*   owh  = (u16*)alloc((size_t)DMODEL * DMODEL * 2);
  u16*   owl  = (u16*)alloc((size_t)DMODEL * DMODEL * 2);
  u16*   w1T  = (u16*)alloc((size_t)NEXP * FFD * DMODEL * 2);
  u16*   w2T  = (u16*)alloc((size_t)NEXP * DMODEL * FFD * 2);
  int*   cnt  = (int*)alloc(256);
  int*   list = (int*)alloc((size_t)NEXP * TTOK * 4);
  // aliases (lifetimes disjoint, stream-ordered):
  u16* Acvh = qkvh;                 // im2col hi: dead before qkv GEMM writes qkvh
  u16* Acvl = qkvl;
  u16* hid  = qkvh;                 // MoE hidden: qkv dead after attn

  hipMemsetAsync(cnt, 0, NEXP * sizeof(int), stream);

  // weight splits / transposes
  k_cast2<<<192, 256, 0, stream>>>(conv_w, cwh, cwl);
  k_cast2<<<192, 256, 0, stream>>>(qkv_w, qwh, qwl);
  k_cast2<<<64, 256, 0, stream>>>(out_w, owh, owl);
  k_castT<<<dim3(FFD / 32, DMODEL / 32, NEXP), 256, 0, stream>>>(e_w1, w1T, DMODEL, FFD);
  k_castT<<<dim3(DMODEL / 32, FFD / 32, NEXP), 256, 0, stream>>>(e_w2, w2T, FFD, DMODEL);

  // patch embed (split GEMM, fp32 out into tok with CMAP)
  k_im2col<<<(CM * CONVK / 8) / 256, 256, 0, stream>>>(x, Acvh, Acvl);
  k_mm<1,0,0,0,0,0,1,0><<<dim3(CM / 128, 2), 256, 0, stream>>>(
      Acvh, Acvl, cwh, cwl, conv_b, tok, nullptr, nullptr, DMODEL,
      CM, CONVK, nullptr, nullptr);
  k_cls<<<NBATCH, DMODEL, 0, stream>>>(cls, tok);

  // attention block (split GEMMs + MFMA attention)
  k_ln<<<TTOK, 256, 0, stream>>>(tok, x2h, x2l, ln1g, ln1b);
  k_mm<1,0,1,0,0,0,0,0><<<dim3(TTOK / 128, 6), 256, 0, stream>>>(
      x2h, x2l, qwh, qwl, qkv_b, nullptr, qkvh, qkvl, 768,
      TTOK, DMODEL, nullptr, nullptr);
  k_attn<<<NBATCH * NHEADS, 256, 0, stream>>>(qkvh, qkvl, aoh, aol);
  k_mm<1,0,0,1,0,0,0,0><<<dim3(TTOK / 128, 2), 256, 0, stream>>>(
      aoh, aol, owh, owl, out_b, tok, nullptr, nullptr, DMODEL,
      TTOK, DMODEL, nullptr, nullptr);

  // MoE block: fused LN2 + router (writes x2h for gather), then expert GEMMs
  k_ln2_router<<<TTOK / NTB, 256, 0, stream>>>(tok, ln2g, ln2b, rw, rb,
                                               x2h, cnt, list);
  for (int e = 0; e < NEXP; ++e) {
    k_mm<0,1,1,0,1,0,0,1><<<dim3(TTOK / 128, FFD / 128), 256, 0, stream>>>(
        x2h, nullptr, w1T + (size_t)e * FFD * DMODEL, nullptr,
        e_b1 + (size_t)e * FFD, nullptr, hid, nullptr, FFD,
        0, DMODEL, cnt + e, list + (size_t)e * TTOK);
    k_mm<0,0,0,1,0,1,0,1><<<dim3(TTOK / 128, DMODEL / 128), 256, 0, stream>>>(
        hid, nullptr, w2T + (size_t)e * DMODEL * FFD, nullptr,
        e_b2 + (size_t)e * DMODEL, tok, nullptr, nullptr, DMODEL,
        0, FFD, cnt + e, list + (size_t)e * TTOK);
  }

  // head
  k_head<<<NBATCH, 256, 0, stream>>>(tok, head_w, head_b, out);
}

// Round 6
// 651.962 us; speedup vs baseline: 5.9428x; 1.1605x over previous
//
#include <hip/hip_runtime.h>
#include <hip/hip_bf16.h>
#include <math.h>

#define TTOK   25216      // 128*197
#define SEQL   197
#define NBATCH 128
#define DMODEL 256
#define NHEADS 8
#define FFD    1024
#define NEXP   4
#define NCLS   38
#define CONVK  768
#define NPATCH 196
#define CM     25088      // conv GEMM rows = 128*196
#define NTB    64         // tokens per router block (394*64 = 25216 exactly)

typedef unsigned short u16;
typedef unsigned int u32;
using s16x8 = __attribute__((ext_vector_type(8))) short;
using f32x4 = __attribute__((ext_vector_type(4))) float;
using u32x4 = __attribute__((ext_vector_type(4))) unsigned int;

__device__ __forceinline__ float b2f(u16 v) {
  union { unsigned u; float f; } x; x.u = (unsigned)v << 16; return x.f;
}
__device__ __forceinline__ u16 f2b(float f) {
  __hip_bfloat16 h = __float2bfloat16(f);
  return *reinterpret_cast<u16*>(&h);
}
__device__ __forceinline__ u32 cvtpk(float a, float b) {
  u32 r;
  asm("v_cvt_pk_bf16_f32 %0, %1, %2" : "=v"(r) : "v"(a), "v"(b));
  return r;
}
__device__ __forceinline__ float bitsf(u32 u) {
  union { unsigned u; float f; } x; x.u = u; return x.f;
}
__device__ __forceinline__ void gload16(const void* g, void* l) {
  __builtin_amdgcn_global_load_lds(
      (const __attribute__((address_space(1))) void*)g,
      (__attribute__((address_space(3))) void*)l, 16, 0, 0);
}
__device__ __forceinline__ float warp_sum(float v) {
  #pragma unroll
  for (int o = 32; o; o >>= 1) v += __shfl_xor(v, o);
  return v;
}

// ---------------- fp32 -> bf16 hi/lo split cast (n % 1024 == 0) --------------
__global__ __launch_bounds__(256) void k_cast2(const float* __restrict__ in,
                                               u16* __restrict__ hi,
                                               u16* __restrict__ lo) {
  int i = (blockIdx.x * 256 + threadIdx.x) * 4;
  float4 v = *(const float4*)&in[i];
  float vv[4] = {v.x, v.y, v.z, v.w};
  u16 h[4], l[4];
  #pragma unroll
  for (int j = 0; j < 4; ++j) {
    h[j] = f2b(vv[j]);
    l[j] = f2b(vv[j] - b2f(h[j]));
  }
  *(uint2*)&hi[i] = *(const uint2*)h;
  *(uint2*)&lo[i] = *(const uint2*)l;
}

// ---------------- transpose+cast: in[R][C] fp32 -> out[C][R] bf16 (single) ---
__global__ __launch_bounds__(256) void k_castT(const float* __restrict__ in,
                                               u16* __restrict__ out, int R, int C) {
  in  += (size_t)blockIdx.z * R * C;
  out += (size_t)blockIdx.z * R * C;
  __shared__ float t[32][33];
  int c0 = blockIdx.x * 32, r0 = blockIdx.y * 32;
  int xx = threadIdx.x & 31, yy = threadIdx.x >> 5;
  for (int i = yy; i < 32; i += 8)
    t[i][xx] = in[(size_t)(r0 + i) * C + c0 + xx];
  __syncthreads();
  for (int i = yy; i < 32; i += 8)
    out[(size_t)(c0 + i) * R + r0 + xx] = f2b(t[xx][i]);
}

// ---------------- im2col + split cast: x fp32 -> Acv hi/lo [25088][768] ------
__global__ __launch_bounds__(256) void k_im2col(const float* __restrict__ x,
                                                u16* __restrict__ Ah,
                                                u16* __restrict__ Al) {
  long idx = ((long)blockIdx.x * 256 + threadIdx.x) * 8;
  int m = (int)(idx / CONVK), k = (int)(idx % CONVK);
  int b = m / NPATCH, p = m - b * NPATCH;
  int py = p / 14, px = p - py * 14;
  int c = k >> 8, r = k & 255;
  int ry = r >> 4, rx = r & 15;                       // rx in {0, 8}
  const float* src = &x[(((long)(b * 3 + c) * 224) + py * 16 + ry) * 224 +
                        px * 16 + rx];
  u16 h[8], l[8];
  #pragma unroll
  for (int j = 0; j < 8; ++j) {
    float v = src[j];
    h[j] = f2b(v);
    l[j] = f2b(v - b2f(h[j]));
  }
  *(uint4*)&Ah[idx] = *(const uint4*)h;
  *(uint4*)&Al[idx] = *(const uint4*)l;
}

// ---------------- bf16(x2) MFMA GEMM -----------------------------------------
// C[m][n] = op( sum_k A[m][k]*W[n][k] + bias[n] )
// SPLIT: A=Ah+Al, W=Wh+Wl, acc = AhWh + AhWl + AlWh  (fp32-class accuracy)
template<int SPLIT, int GELU, int OUTBF, int ADDC, int GATHER, int SCATTER, int CMAP, int DYNM>
__global__ __launch_bounds__(256) void k_mm(
    const u16* __restrict__ Ah, const u16* __restrict__ Al,
    const u16* __restrict__ Wh, const u16* __restrict__ Wl,
    const float* __restrict__ bias,
    float* __restrict__ Cf, u16* __restrict__ Cb, u16* __restrict__ Cb2, int ldc,
    int M, int K, const int* __restrict__ cntp, const int* __restrict__ list) {
  const int rows = DYNM ? *cntp : M;
  const int m0 = blockIdx.x * 128;
  if (m0 >= rows) return;
  const int n0 = blockIdx.y * 128;
  __shared__ u16 As[(SPLIT ? 2 : 1) * 128 * 64];
  __shared__ u16 Bs[(SPLIT ? 2 : 1) * 128 * 64];
  const int tid = threadIdx.x;
  const int lane = tid & 63;
  const int wv = tid >> 6;
  const int wr = wv >> 1, wc = wv & 1;
  f32x4 acc[4][4] = {};

  long aoff[4], woff[4]; int rofs[4];
  #pragma unroll
  for (int i = 0; i < 4; ++i) {
    int off = i * 4096 + tid * 16;
    int row = off >> 7;
    int c16 = (off >> 4) & 7;
    int kk = (c16 ^ (row & 7)) << 3;
    int ar = m0 + row;
    if (DYNM) ar = ar < rows ? ar : rows - 1;
    aoff[i] = GATHER ? (long)list[ar] * K + kk : (long)ar * K + kk;
    woff[i] = (long)(n0 + row) * K + kk;
    rofs[i] = off;
  }
  for (int kc = 0; kc < K; kc += 64) {
    #pragma unroll
    for (int i = 0; i < 4; ++i) {
      gload16(Ah + aoff[i] + kc, (char*)As + rofs[i]);
      gload16(Wh + woff[i] + kc, (char*)Bs + rofs[i]);
      if (SPLIT) {
        gload16(Al + aoff[i] + kc, (char*)As + 16384 + rofs[i]);
        gload16(Wl + woff[i] + kc, (char*)Bs + 16384 + rofs[i]);
      }
    }
    __syncthreads();
    #pragma unroll
    for (int kf = 0; kf < 2; ++kf) {
      s16x8 ah[4], bh[4], al[4], bl[4];
      #pragma unroll
      for (int i = 0; i < 4; ++i) {
        int rowa = wr * 64 + i * 16 + (lane & 15);
        int kb = (kf * 64 + ((lane >> 4) << 4)) ^ ((rowa & 7) << 4);
        ah[i] = *(const s16x8*)((const char*)As + rowa * 128 + kb);
        if (SPLIT) al[i] = *(const s16x8*)((const char*)As + 16384 + rowa * 128 + kb);
        int rowb = wc * 64 + i * 16 + (lane & 15);
        int kbn = (kf * 64 + ((lane >> 4) << 4)) ^ ((rowb & 7) << 4);
        bh[i] = *(const s16x8*)((const char*)Bs + rowb * 128 + kbn);
        if (SPLIT) bl[i] = *(const s16x8*)((const char*)Bs + 16384 + rowb * 128 + kbn);
      }
      #pragma unroll
      for (int i = 0; i < 4; ++i)
        #pragma unroll
        for (int j = 0; j < 4; ++j)
          acc[i][j] = __builtin_amdgcn_mfma_f32_16x16x32_bf16(ah[i], bh[j],
                                                              acc[i][j], 0, 0, 0);
      if (SPLIT) {
        #pragma unroll
        for (int i = 0; i < 4; ++i)
          #pragma unroll
          for (int j = 0; j < 4; ++j)
            acc[i][j] = __builtin_amdgcn_mfma_f32_16x16x32_bf16(ah[i], bl[j],
                                                                acc[i][j], 0, 0, 0);
        #pragma unroll
        for (int i = 0; i < 4; ++i)
          #pragma unroll
          for (int j = 0; j < 4; ++j)
            acc[i][j] = __builtin_amdgcn_mfma_f32_16x16x32_bf16(al[i], bh[j],
                                                                acc[i][j], 0, 0, 0);
      }
    }
    __syncthreads();
  }
  const int mb = m0 + wr * 64 + ((lane >> 4) << 2);
  const int nb = n0 + wc * 64 + (lane & 15);
  #pragma unroll
  for (int i = 0; i < 4; ++i) {
    #pragma unroll
    for (int jf = 0; jf < 4; ++jf) {
      #pragma unroll
      for (int j = 0; j < 4; ++j) {
        int m = mb + i * 16 + j;
        int n = nb + jf * 16;
        if (DYNM && m >= rows) continue;
        float v = acc[i][jf][j] + bias[n];
        if (GELU) v = 0.5f * v * (1.0f + erff(v * 0.70710678118654752f));
        long cr;
        if (SCATTER)     cr = list[m];
        else if (CMAP) { int bq = m / NPATCH; cr = (long)bq * SEQL + (m - bq * NPATCH) + 1; }
        else             cr = m;
        if (OUTBF) {
          u16 h = f2b(v);
          Cb[cr * ldc + n] = h;
          if (Cb2) Cb2[cr * ldc + n] = f2b(v - b2f(h));
        } else if (ADDC) {
          Cf[cr * ldc + n] += v;
        } else {
          Cf[cr * ldc + n] = v;
        }
      }
    }
  }
}

// ---------------- LayerNorm over D=256: bf16 hi (+optional lo) out -----------
__global__ __launch_bounds__(256) void k_ln(const float* __restrict__ in,
                                            u16* __restrict__ outh,
                                            u16* __restrict__ outl,
                                            const float* __restrict__ g,
                                            const float* __restrict__ bb) {
  const int row = blockIdx.x;
  const int tid = threadIdx.x;
  float v = in[(size_t)row * DMODEL + tid];
  float s1 = warp_sum(v), s2 = warp_sum(v * v);
  __shared__ float a1[4], a2[4];
  int w = tid >> 6, lane = tid & 63;
  if (lane == 0) { a1[w] = s1; a2[w] = s2; }
  __syncthreads();
  s1 = a1[0] + a1[1] + a1[2] + a1[3];
  s2 = a2[0] + a2[1] + a2[2] + a2[3];
  float mu = s1 * (1.f / DMODEL);
  float var = s2 * (1.f / DMODEL) - mu * mu;
  float rs = rsqrtf(var + 1e-5f);
  float r = (v - mu) * rs * g[tid] + bb[tid];
  u16 h = f2b(r);
  outh[(size_t)row * DMODEL + tid] = h;
  if (outl) outl[(size_t)row * DMODEL + tid] = f2b(r - b2f(h));
}

// ---------------- MFMA fused attention v2: swapped QK^T + permuted PV --------
// block = (b,h); 4 independent waves (no barriers after V staging).
// QK^T computed as mfma(K,Q) -> each lane holds P[q=lane&15][keys j*16+l4*4+jj].
// Softmax fully in-register (per-lane + shfl_xor 16/32 across l4 groups).
// PV contraction uses a bit-rotated key permutation so the lane-local P quads
// ARE the MFMA A-fragment octets: pos(s) = 32*(s>>5)+((s>>2)&3)*8+((s>>4)&1)*4+(s&3).
// V staged (hi/lo) into LDS by permuted column; zero-init covers key padding.
#define LDP 232
__global__ __launch_bounds__(256) void k_attn(const u16* __restrict__ qh,
                                              const u16* __restrict__ ql,
                                              u16* __restrict__ aoh,
                                              u16* __restrict__ aol) {
  const int bh = blockIdx.x;
  const int b = bh >> 3, h = bh & 7;
  __shared__ __align__(16) u16 Vt[64 * LDP];   // rows 0..31 = V hi (d), 32..63 = V lo
  const int tid = threadIdx.x, lane = tid & 63, w = tid >> 6;

  for (int i = tid; i < 64 * LDP / 2; i += 256) ((unsigned*)Vt)[i] = 0;
  __syncthreads();

  const u16* bqh = qh + (size_t)b * SEQL * 768;
  const u16* bql = ql + (size_t)b * SEQL * 768;
  #pragma unroll
  for (int it = 0; it < 4; ++it) {
    int s = (tid >> 2) + it * 64, c = tid & 3;
    if (s < SEQL) {
      int pos = ((s >> 5) << 5) + (((s >> 2) & 3) << 3) + (((s >> 4) & 1) << 2) + (s & 3);
      s16x8 vh = *(const s16x8*)(bqh + (size_t)s * 768 + 512 + h * 32 + c * 8);
      s16x8 vl = *(const s16x8*)(bql + (size_t)s * 768 + 512 + h * 32 + c * 8);
      #pragma unroll
      for (int i = 0; i < 8; ++i) {
        Vt[(c * 8 + i) * LDP + pos] = (u16)vh[i];
        Vt[(32 + c * 8 + i) * LDP + pos] = (u16)vl[i];
      }
    }
  }
  __syncthreads();

  const int l15 = lane & 15, l4 = lane >> 4;
  for (int qt = w; qt < 13; qt += 4) {
    int qrow = qt * 16 + l15;
    int qcl = qrow < SEQL ? qrow : SEQL - 1;
    s16x8 qfh = *(const s16x8*)(bqh + (size_t)qcl * 768 + h * 32 + l4 * 8);
    s16x8 qfl = *(const s16x8*)(bql + (size_t)qcl * 768 + h * 32 + l4 * 8);
    f32x4 sc[13];
    #pragma unroll
    for (int j = 0; j < 13; ++j) {
      int key = j * 16 + l15;
      int kcl = key < SEQL ? key : SEQL - 1;
      s16x8 kfh = *(const s16x8*)(bqh + (size_t)kcl * 768 + 256 + h * 32 + l4 * 8);
      s16x8 kfl = *(const s16x8*)(bql + (size_t)kcl * 768 + 256 + h * 32 + l4 * 8);
      f32x4 c = {};
      c = __builtin_amdgcn_mfma_f32_16x16x32_bf16(kfh, qfh, c, 0, 0, 0);
      c = __builtin_amdgcn_mfma_f32_16x16x32_bf16(kfh, qfl, c, 0, 0, 0);
      c = __builtin_amdgcn_mfma_f32_16x16x32_bf16(kfl, qfh, c, 0, 0, 0);
      sc[j] = c;
    }
    // softmax: lane holds P[q=l15][key = j*16 + l4*4 + jj]
    float mx = -1e30f;
    #pragma unroll
    for (int j = 0; j < 13; ++j)
      #pragma unroll
      for (int jj = 0; jj < 4; ++jj) {
        int key = j * 16 + l4 * 4 + jj;
        float s = sc[j][jj] * 0.17677669529663687f + (key < SEQL ? 0.f : -1e30f);
        sc[j][jj] = s;
        mx = fmaxf(mx, s);
      }
    mx = fmaxf(mx, __shfl_xor(mx, 16));
    mx = fmaxf(mx, __shfl_xor(mx, 32));
    float sm = 0.f;
    #pragma unroll
    for (int j = 0; j < 13; ++j)
      #pragma unroll
      for (int jj = 0; jj < 4; ++jj) {
        float e = __expf(sc[j][jj] - mx);
        sc[j][jj] = e;
        sm += e;
      }
    sm += __shfl_xor(sm, 16);
    sm += __shfl_xor(sm, 32);
    float inv = 1.f / sm;
    // normalize + split-pack P into per-lane octet words (j=13 = zero pad)
    u32 ph0[14], ph1[14], pl0[14], pl1[14];
    #pragma unroll
    for (int j = 0; j < 13; ++j) {
      float p0 = sc[j][0] * inv, p1 = sc[j][1] * inv;
      float p2 = sc[j][2] * inv, p3 = sc[j][3] * inv;
      u32 h01 = cvtpk(p0, p1), h23 = cvtpk(p2, p3);
      ph0[j] = h01; ph1[j] = h23;
      pl0[j] = cvtpk(p0 - bitsf(h01 << 16), p1 - bitsf(h01 & 0xffff0000u));
      pl1[j] = cvtpk(p2 - bitsf(h23 << 16), p3 - bitsf(h23 & 0xffff0000u));
    }
    ph0[13] = ph1[13] = pl0[13] = pl1[13] = 0;
    // PV: A-octets are lane-local; B from permuted Vt
    f32x4 o0 = {}, o1 = {};
    const char* vbase = (const char*)Vt;
    #pragma unroll
    for (int ks = 0; ks < 7; ++ks) {
      u32x4 wh = {ph0[2 * ks], ph1[2 * ks], ph0[2 * ks + 1], ph1[2 * ks + 1]};
      u32x4 wl = {pl0[2 * ks], pl1[2 * ks], pl0[2 * ks + 1], pl1[2 * ks + 1]};
      s16x8 pah = *(const s16x8*)&wh;
      s16x8 pal = *(const s16x8*)&wl;
      int co = ks * 64 + l4 * 16;
      s16x8 v0h = *(const s16x8*)(vbase + l15 * (LDP * 2) + co);
      s16x8 v1h = *(const s16x8*)(vbase + (16 + l15) * (LDP * 2) + co);
      s16x8 v0l = *(const s16x8*)(vbase + (32 + l15) * (LDP * 2) + co);
      s16x8 v1l = *(const s16x8*)(vbase + (48 + l15) * (LDP * 2) + co);
      o0 = __builtin_amdgcn_mfma_f32_16x16x32_bf16(pah, v0h, o0, 0, 0, 0);
      o0 = __builtin_amdgcn_mfma_f32_16x16x32_bf16(pah, v0l, o0, 0, 0, 0);
      o0 = __builtin_amdgcn_mfma_f32_16x16x32_bf16(pal, v0h, o0, 0, 0, 0);
      o1 = __builtin_amdgcn_mfma_f32_16x16x32_bf16(pah, v1h, o1, 0, 0, 0);
      o1 = __builtin_amdgcn_mfma_f32_16x16x32_bf16(pah, v1l, o1, 0, 0, 0);
      o1 = __builtin_amdgcn_mfma_f32_16x16x32_bf16(pal, v1h, o1, 0, 0, 0);
    }
    // epilogue: D row = l4*4+jj (q within tile), col = l15 (d)
    #pragma unroll
    for (int jj = 0; jj < 4; ++jj) {
      int qrow2 = qt * 16 + l4 * 4 + jj;
      if (qrow2 < SEQL) {
        size_t o = ((size_t)b * SEQL + qrow2) * DMODEL + h * 32 + l15;
        float v0 = o0[jj], v1 = o1[jj];
        u16 h0 = f2b(v0), h1 = f2b(v1);
        aoh[o] = h0;
        aol[o] = f2b(v0 - b2f(h0));
        aoh[o + 16] = h1;
        aol[o + 16] = f2b(v1 - b2f(h1));
      }
    }
  }
}

// ---------------- fused LN2 + router + hierarchical compaction ----------------
__global__ __launch_bounds__(256) void k_ln2_router(
    const float* __restrict__ tok,
    const float* __restrict__ g, const float* __restrict__ bb,
    const float* __restrict__ rw, const float* __restrict__ rb,
    u16* __restrict__ x2h,
    int* __restrict__ cnt, int* __restrict__ list) {
  __shared__ int lc[NEXP];
  __shared__ int base[NEXP];
  __shared__ int ll[NEXP][NTB];
  const int tid = threadIdx.x, lane = tid & 63, w = tid >> 6;
  if (tid < NEXP) lc[tid] = 0;
  __syncthreads();
  const int t0 = blockIdx.x * NTB;
  for (int i = w; i < NTB; i += 4) {
    int t = t0 + i;
    const float* row = tok + (size_t)t * DMODEL;
    float vv[4];
    *(float4*)vv = *(const float4*)&row[lane * 4];
    float s1 = vv[0] + vv[1] + vv[2] + vv[3];
    float s2 = vv[0]*vv[0] + vv[1]*vv[1] + vv[2]*vv[2] + vv[3]*vv[3];
    s1 = warp_sum(s1);
    s2 = warp_sum(s2);
    float mu = s1 * (1.f / DMODEL);
    float var = s2 * (1.f / DMODEL) - mu * mu;
    float rs = rsqrtf(var + 1e-5f);
    float xd[4]; u16 hh[4];
    #pragma unroll
    for (int j = 0; j < 4; ++j) {
      xd[j] = (vv[j] - mu) * rs * g[lane * 4 + j] + bb[lane * 4 + j];
      hh[j] = f2b(xd[j]);
    }
    *(uint2*)&x2h[(size_t)t * DMODEL + lane * 4] = *(const uint2*)hh;
    float p[NEXP];
    #pragma unroll
    for (int e2 = 0; e2 < NEXP; ++e2) {
      float s = 0.f;
      #pragma unroll
      for (int j = 0; j < 4; ++j) s = fmaf(xd[j], rw[e2 * DMODEL + lane * 4 + j], s);
      p[e2] = warp_sum(s) + rb[e2];
    }
    if (lane < NEXP) {
      int e2 = lane;
      int rank = 0;
      #pragma unroll
      for (int j = 0; j < NEXP; ++j)
        if (j != e2 && (p[j] > p[e2] || (p[j] == p[e2] && j < e2))) ++rank;
      if (rank < 2) {
        int idx = atomicAdd(&lc[e2], 1);
        ll[e2][idx] = t;
      }
    }
  }
  __syncthreads();
  if (tid < NEXP) base[tid] = atomicAdd(&cnt[tid], lc[tid]);
  __syncthreads();
  if (lane < lc[w]) list[w * TTOK + base[w] + lane] = ll[w][lane];
}

__global__ void k_cls(const float* __restrict__ cls, float* __restrict__ tok) {
  tok[(size_t)blockIdx.x * SEQL * DMODEL + threadIdx.x] = cls[threadIdx.x];
}

__global__ __launch_bounds__(256) void k_head(const float* __restrict__ tok,
                                              const float* __restrict__ hw,
                                              const float* __restrict__ hb,
                                              float* __restrict__ out) {
  int b = blockIdx.x;
  int w = threadIdx.x >> 6, lane = threadIdx.x & 63;
  const float* row = tok + (size_t)b * SEQL * DMODEL;  // token 0
  for (int c = w; c < NCLS; c += 4) {
    float s = 0.f;
    for (int d = lane; d < DMODEL; d += 64) s = fmaf(row[d], hw[c * DMODEL + d], s);
    s = warp_sum(s);
    if (lane == 0) out[b * NCLS + c] = s + hb[c];
  }
}

extern "C" void kernel_launch(void* const* d_in, const int* in_sizes, int n_in,
                              void* d_out, int out_size, void* d_ws, size_t ws_size,
                              hipStream_t stream) {
  const float* x      = (const float*)d_in[0];
  const float* conv_w = (const float*)d_in[1];
  const float* conv_b = (const float*)d_in[2];
  const float* cls    = (const float*)d_in[3];
  const float* ln1g   = (const float*)d_in[4];
  const float* ln1b   = (const float*)d_in[5];
  const float* qkv_w  = (const float*)d_in[6];
  const float* qkv_b  = (const float*)d_in[7];
  const float* out_w  = (const float*)d_in[8];
  const float* out_b  = (const float*)d_in[9];
  const float* ln2g   = (const float*)d_in[10];
  const float* ln2b   = (const float*)d_in[11];
  const float* rw     = (const float*)d_in[12];
  const float* rb     = (const float*)d_in[13];
  const float* e_w1   = (const float*)d_in[14];
  const float* e_b1   = (const float*)d_in[15];
  const float* e_w2   = (const float*)d_in[16];
  const float* e_b2   = (const float*)d_in[17];
  const float* head_w = (const float*)d_in[18];
  const float* head_b = (const float*)d_in[19];
  float* out = (float*)d_out;

  char* ws = (char*)d_ws;
  size_t off = 0;
  auto alloc = [&](size_t bytes) {
    void* p = ws + off;
    off += (bytes + 255) & ~(size_t)255;
    return p;
  };
  float* tok  = (float*)alloc((size_t)TTOK * DMODEL * 4);
  u16*   x2h  = (u16*)alloc((size_t)TTOK * DMODEL * 2);
  u16*   x2l  = (u16*)alloc((size_t)TTOK * DMODEL * 2);
  u16*   qkvh = (u16*)alloc((size_t)TTOK * 768 * 2);
  u16*   qkvl = (u16*)alloc((size_t)TTOK * 768 * 2);
  u16*   aoh  = (u16*)alloc((size_t)TTOK * DMODEL * 2);
  u16*   aol  = (u16*)alloc((size_t)TTOK * DMODEL * 2);
  u16*   cwh  = (u16*)alloc((size_t)DMODEL * CONVK * 2);
  u16*   cwl  = (u16*)alloc((size_t)DMODEL * CONVK * 2);
  u16*   qwh  = (u16*)alloc((size_t)768 * DMODEL * 2);
  u16*   qwl  = (u16*)alloc((size_t)768 * DMODEL * 2);
  u16*   owh  = (u16*)alloc((size_t)DMODEL * DMODEL * 2);
  u16*   owl  = (u16*)alloc((size_t)DMODEL * DMODEL * 2);
  u16*   w1T  = (u16*)alloc((size_t)NEXP * FFD * DMODEL * 2);
  u16*   w2T  = (u16*)alloc((size_t)NEXP * DMODEL * FFD * 2);
  int*   cnt  = (int*)alloc(256);
  int*   list = (int*)alloc((size_t)NEXP * TTOK * 4);
  // aliases (lifetimes disjoint, stream-ordered):
  u16* Acvh = qkvh;                 // im2col hi: dead before qkv GEMM writes qkvh
  u16* Acvl = qkvl;
  u16* hid  = qkvh;                 // MoE hidden: qkv dead after attn

  hipMemsetAsync(cnt, 0, NEXP * sizeof(int), stream);

  // weight splits / transposes
  k_cast2<<<192, 256, 0, stream>>>(conv_w, cwh, cwl);
  k_cast2<<<192, 256, 0, stream>>>(qkv_w, qwh, qwl);
  k_cast2<<<64, 256, 0, stream>>>(out_w, owh, owl);
  k_castT<<<dim3(FFD / 32, DMODEL / 32, NEXP), 256, 0, stream>>>(e_w1, w1T, DMODEL, FFD);
  k_castT<<<dim3(DMODEL / 32, FFD / 32, NEXP), 256, 0, stream>>>(e_w2, w2T, FFD, DMODEL);

  // patch embed (split GEMM, fp32 out into tok with CMAP)
  k_im2col<<<(CM * CONVK / 8) / 256, 256, 0, stream>>>(x, Acvh, Acvl);
  k_mm<1,0,0,0,0,0,1,0><<<dim3(CM / 128, 2), 256, 0, stream>>>(
      Acvh, Acvl, cwh, cwl, conv_b, tok, nullptr, nullptr, DMODEL,
      CM, CONVK, nullptr, nullptr);
  k_cls<<<NBATCH, DMODEL, 0, stream>>>(cls, tok);

  // attention block (split GEMMs + MFMA attention)
  k_ln<<<TTOK, 256, 0, stream>>>(tok, x2h, x2l, ln1g, ln1b);
  k_mm<1,0,1,0,0,0,0,0><<<dim3(TTOK / 128, 6), 256, 0, stream>>>(
      x2h, x2l, qwh, qwl, qkv_b, nullptr, qkvh, qkvl, 768,
      TTOK, DMODEL, nullptr, nullptr);
  k_attn<<<NBATCH * NHEADS, 256, 0, stream>>>(qkvh, qkvl, aoh, aol);
  k_mm<1,0,0,1,0,0,0,0><<<dim3(TTOK / 128, 2), 256, 0, stream>>>(
      aoh, aol, owh, owl, out_b, tok, nullptr, nullptr, DMODEL,
      TTOK, DMODEL, nullptr, nullptr);

  // MoE block: fused LN2 + router (writes x2h for gather), then expert GEMMs
  k_ln2_router<<<TTOK / NTB, 256, 0, stream>>>(tok, ln2g, ln2b, rw, rb,
                                               x2h, cnt, list);
  for (int e = 0; e < NEXP; ++e) {
    k_mm<0,1,1,0,1,0,0,1><<<dim3(TTOK / 128, FFD / 128), 256, 0, stream>>>(
        x2h, nullptr, w1T + (size_t)e * FFD * DMODEL, nullptr,
        e_b1 + (size_t)e * FFD, nullptr, hid, nullptr, FFD,
        0, DMODEL, cnt + e, list + (size_t)e * TTOK);
    k_mm<0,0,0,1,0,1,0,1><<<dim3(TTOK / 128, DMODEL / 128), 256, 0, stream>>>(
        hid, nullptr, w2T + (size_t)e * DMODEL * FFD, nullptr,
        e_b2 + (size_t)e * DMODEL, tok, nullptr, nullptr, DMODEL,
        0, FFD, cnt + e, list + (size_t)e * TTOK);
  }

  // head
  k_head<<<NBATCH, 256, 0, stream>>>(tok, head_w, head_b, out);
}

// Round 7
// 459.890 us; speedup vs baseline: 8.4247x; 1.4176x over previous
//
#include <hip/hip_runtime.h>
#include <hip/hip_bf16.h>
#include <math.h>

#define TTOK   25216      // 128*197
#define SEQL   197
#define NBATCH 128
#define DMODEL 256
#define NHEADS 8
#define FFD    1024
#define NEXP   4
#define NCLS   38
#define CONVK  768
#define NPATCH 196
#define CM     25088      // conv GEMM rows = 128*196

typedef unsigned short u16;
typedef unsigned int u32;
using s16x8 = __attribute__((ext_vector_type(8))) short;
using f32x4 = __attribute__((ext_vector_type(4))) float;

__device__ __forceinline__ float b2f(u16 v) {
  union { unsigned u; float f; } x; x.u = (unsigned)v << 16; return x.f;
}
__device__ __forceinline__ u16 f2b(float f) {
  __hip_bfloat16 h = __float2bfloat16(f);
  return *reinterpret_cast<u16*>(&h);
}
__device__ __forceinline__ void gload16(const void* g, void* l) {
  __builtin_amdgcn_global_load_lds(
      (const __attribute__((address_space(1))) void*)g,
      (__attribute__((address_space(3))) void*)l, 16, 0, 0);
}
__device__ __forceinline__ float warp_sum(float v) {
  #pragma unroll
  for (int o = 32; o; o >>= 1) v += __shfl_xor(v, o);
  return v;
}
__device__ __forceinline__ float warp_max(float v) {
  #pragma unroll
  for (int o = 32; o; o >>= 1) v = fmaxf(v, __shfl_xor(v, o));
  return v;
}

// ---------------- fp32 -> bf16 hi/lo split cast (n % 1024 == 0) --------------
__global__ __launch_bounds__(256) void k_cast2(const float* __restrict__ in,
                                               u16* __restrict__ hi,
                                               u16* __restrict__ lo) {
  int i = (blockIdx.x * 256 + threadIdx.x) * 4;
  float4 v = *(const float4*)&in[i];
  float vv[4] = {v.x, v.y, v.z, v.w};
  u16 h[4], l[4];
  #pragma unroll
  for (int j = 0; j < 4; ++j) {
    h[j] = f2b(vv[j]);
    l[j] = f2b(vv[j] - b2f(h[j]));
  }
  *(uint2*)&hi[i] = *(const uint2*)h;
  *(uint2*)&lo[i] = *(const uint2*)l;
}

// ---------------- im2col + split cast: x fp32 -> Acv hi/lo [25088][768] ------
__global__ __launch_bounds__(256) void k_im2col(const float* __restrict__ x,
                                                u16* __restrict__ Ah,
                                                u16* __restrict__ Al) {
  long idx = ((long)blockIdx.x * 256 + threadIdx.x) * 8;
  int m = (int)(idx / CONVK), k = (int)(idx % CONVK);
  int b = m / NPATCH, p = m - b * NPATCH;
  int py = p / 14, px = p - py * 14;
  int c = k >> 8, r = k & 255;
  int ry = r >> 4, rx = r & 15;                       // rx in {0, 8}
  const float* src = &x[(((long)(b * 3 + c) * 224) + py * 16 + ry) * 224 +
                        px * 16 + rx];
  u16 h[8], l[8];
  #pragma unroll
  for (int j = 0; j < 8; ++j) {
    float v = src[j];
    h[j] = f2b(v);
    l[j] = f2b(v - b2f(h[j]));
  }
  *(uint4*)&Ah[idx] = *(const uint4*)h;
  *(uint4*)&Al[idx] = *(const uint4*)l;
}

// ---------------- bf16(x2) MFMA GEMM -----------------------------------------
// C[m][n] = op( sum_k A[m][k]*W[n][k] + bias[n] )
// SPLIT: A=Ah+Al, W=Wh+Wl, acc = AhWh + AhWl + AlWh  (fp32-class accuracy)
template<int SPLIT, int OUTBF, int CMAP>
__global__ __launch_bounds__(256) void k_mm(
    const u16* __restrict__ Ah, const u16* __restrict__ Al,
    const u16* __restrict__ Wh, const u16* __restrict__ Wl,
    const float* __restrict__ bias,
    float* __restrict__ Cf, u16* __restrict__ Cb, u16* __restrict__ Cb2, int ldc,
    int M, int K) {
  const int m0 = blockIdx.x * 128;
  const int n0 = blockIdx.y * 128;
  __shared__ u16 As[(SPLIT ? 2 : 1) * 128 * 64];
  __shared__ u16 Bs[(SPLIT ? 2 : 1) * 128 * 64];
  const int tid = threadIdx.x;
  const int lane = tid & 63;
  const int wv = tid >> 6;
  const int wr = wv >> 1, wc = wv & 1;
  f32x4 acc[4][4] = {};

  long aoff[4], woff[4]; int rofs[4];
  #pragma unroll
  for (int i = 0; i < 4; ++i) {
    int off = i * 4096 + tid * 16;
    int row = off >> 7;
    int c16 = (off >> 4) & 7;
    int kk = (c16 ^ (row & 7)) << 3;
    aoff[i] = (long)(m0 + row) * K + kk;
    woff[i] = (long)(n0 + row) * K + kk;
    rofs[i] = off;
  }
  for (int kc = 0; kc < K; kc += 64) {
    #pragma unroll
    for (int i = 0; i < 4; ++i) {
      gload16(Ah + aoff[i] + kc, (char*)As + rofs[i]);
      gload16(Wh + woff[i] + kc, (char*)Bs + rofs[i]);
      if (SPLIT) {
        gload16(Al + aoff[i] + kc, (char*)As + 16384 + rofs[i]);
        gload16(Wl + woff[i] + kc, (char*)Bs + 16384 + rofs[i]);
      }
    }
    __syncthreads();
    #pragma unroll
    for (int kf = 0; kf < 2; ++kf) {
      s16x8 ah[4], bh[4], al[4], bl[4];
      #pragma unroll
      for (int i = 0; i < 4; ++i) {
        int rowa = wr * 64 + i * 16 + (lane & 15);
        int kb = (kf * 64 + ((lane >> 4) << 4)) ^ ((rowa & 7) << 4);
        ah[i] = *(const s16x8*)((const char*)As + rowa * 128 + kb);
        if (SPLIT) al[i] = *(const s16x8*)((const char*)As + 16384 + rowa * 128 + kb);
        int rowb = wc * 64 + i * 16 + (lane & 15);
        int kbn = (kf * 64 + ((lane >> 4) << 4)) ^ ((rowb & 7) << 4);
        bh[i] = *(const s16x8*)((const char*)Bs + rowb * 128 + kbn);
        if (SPLIT) bl[i] = *(const s16x8*)((const char*)Bs + 16384 + rowb * 128 + kbn);
      }
      #pragma unroll
      for (int i = 0; i < 4; ++i)
        #pragma unroll
        for (int j = 0; j < 4; ++j)
          acc[i][j] = __builtin_amdgcn_mfma_f32_16x16x32_bf16(ah[i], bh[j],
                                                              acc[i][j], 0, 0, 0);
      if (SPLIT) {
        #pragma unroll
        for (int i = 0; i < 4; ++i)
          #pragma unroll
          for (int j = 0; j < 4; ++j)
            acc[i][j] = __builtin_amdgcn_mfma_f32_16x16x32_bf16(ah[i], bl[j],
                                                                acc[i][j], 0, 0, 0);
        #pragma unroll
        for (int i = 0; i < 4; ++i)
          #pragma unroll
          for (int j = 0; j < 4; ++j)
            acc[i][j] = __builtin_amdgcn_mfma_f32_16x16x32_bf16(al[i], bh[j],
                                                                acc[i][j], 0, 0, 0);
      }
    }
    __syncthreads();
  }
  const int mb = m0 + wr * 64 + ((lane >> 4) << 2);
  const int nb = n0 + wc * 64 + (lane & 15);
  #pragma unroll
  for (int i = 0; i < 4; ++i) {
    #pragma unroll
    for (int jf = 0; jf < 4; ++jf) {
      #pragma unroll
      for (int j = 0; j < 4; ++j) {
        int m = mb + i * 16 + j;
        int n = nb + jf * 16;
        float v = acc[i][jf][j] + bias[n];
        long cr;
        if (CMAP) { int bq = m / NPATCH; cr = (long)bq * SEQL + (m - bq * NPATCH) + 1; }
        else        cr = m;
        if (OUTBF) {
          u16 h = f2b(v);
          Cb[cr * ldc + n] = h;
          Cb2[cr * ldc + n] = f2b(v - b2f(h));
        } else {
          Cf[cr * ldc + n] = v;
        }
      }
    }
  }
}

// ---------------- LayerNorm (wave per row): fp32 in -> bf16 hi/lo out --------
__global__ __launch_bounds__(256) void k_ln4(const float* __restrict__ in,
                                             u16* __restrict__ outh,
                                             u16* __restrict__ outl,
                                             const float* __restrict__ g,
                                             const float* __restrict__ bb) {
  const int row = blockIdx.x * 4 + (threadIdx.x >> 6);
  const int lane = threadIdx.x & 63;
  float vv[4];
  *(float4*)vv = *(const float4*)&in[(size_t)row * DMODEL + lane * 4];
  float s1 = vv[0] + vv[1] + vv[2] + vv[3];
  float s2 = vv[0]*vv[0] + vv[1]*vv[1] + vv[2]*vv[2] + vv[3]*vv[3];
  s1 = warp_sum(s1);
  s2 = warp_sum(s2);
  float mu = s1 * (1.f / DMODEL);
  float var = s2 * (1.f / DMODEL) - mu * mu;
  float rs = rsqrtf(var + 1e-5f);
  u16 hh[4], ll[4];
  #pragma unroll
  for (int j = 0; j < 4; ++j) {
    float r = (vv[j] - mu) * rs * g[lane * 4 + j] + bb[lane * 4 + j];
    hh[j] = f2b(r);
    ll[j] = f2b(r - b2f(hh[j]));
  }
  *(uint2*)&outh[(size_t)row * DMODEL + lane * 4] = *(const uint2*)hh;
  *(uint2*)&outl[(size_t)row * DMODEL + lane * 4] = *(const uint2*)ll;
}

__global__ void k_cls(const float* __restrict__ cls, float* __restrict__ tok) {
  tok[(size_t)blockIdx.x * SEQL * DMODEL + threadIdx.x] = cls[threadIdx.x];
}

// ---------------- Q projection for cls rows only: [128][256] hi/lo -----------
__global__ __launch_bounds__(256) void k_qcls(const u16* __restrict__ x2h,
                                              const u16* __restrict__ x2l,
                                              const u16* __restrict__ qwh,
                                              const u16* __restrict__ qwl,
                                              const float* __restrict__ qb,
                                              u16* __restrict__ qch,
                                              u16* __restrict__ qcl) {
  const int b = blockIdx.x, n = threadIdx.x;
  __shared__ float xs[DMODEL];
  size_t r0 = (size_t)b * SEQL * DMODEL;
  xs[n] = b2f(x2h[r0 + n]) + b2f(x2l[r0 + n]);
  __syncthreads();
  float val = qb[n];
  #pragma unroll 4
  for (int i = 0; i < 32; ++i) {
    s16x8 wh = *(const s16x8*)(qwh + (size_t)n * DMODEL + i * 8);
    s16x8 wl = *(const s16x8*)(qwl + (size_t)n * DMODEL + i * 8);
    #pragma unroll
    for (int j = 0; j < 8; ++j)
      val = fmaf(b2f((u16)wh[j]) + b2f((u16)wl[j]), xs[i * 8 + j], val);
  }
  u16 h = f2b(val);
  qch[b * DMODEL + n] = h;
  qcl[b * DMODEL + n] = f2b(val - b2f(h));
}

// ---------------- single-query attention (cls only), fp32 math ---------------
// grid 256 x 256thr: wave = one (b,h). K/V read as hi+lo fp32 from qkv buffer.
__global__ __launch_bounds__(256) void k_attn_cls(const u16* __restrict__ qch,
                                                  const u16* __restrict__ qcl,
                                                  const u16* __restrict__ kvh,
                                                  const u16* __restrict__ kvl,
                                                  float* __restrict__ ao) {
  const int w = threadIdx.x >> 6, lane = threadIdx.x & 63;
  const int unit = blockIdx.x * 4 + w;
  const int b = unit >> 3, h = unit & 7;
  __shared__ float Ss[4][200];
  float q[32];
  #pragma unroll
  for (int i = 0; i < 4; ++i) {
    s16x8 vh = *(const s16x8*)(qch + b * DMODEL + h * 32 + i * 8);
    s16x8 vl = *(const s16x8*)(qcl + b * DMODEL + h * 32 + i * 8);
    #pragma unroll
    for (int j = 0; j < 8; ++j) q[i * 8 + j] = b2f((u16)vh[j]) + b2f((u16)vl[j]);
  }
  float sc[4];
  float mx = -1e30f;
  #pragma unroll
  for (int r = 0; r < 4; ++r) {
    int k = lane + 64 * r;
    float s = -1e30f;
    if (k < SEQL) {
      size_t base = ((size_t)(b * SEQL + k)) * 768 + 256 + h * 32;
      s = 0.f;
      #pragma unroll
      for (int i = 0; i < 4; ++i) {
        s16x8 vh = *(const s16x8*)(kvh + base + i * 8);
        s16x8 vl = *(const s16x8*)(kvl + base + i * 8);
        #pragma unroll
        for (int j = 0; j < 8; ++j)
          s = fmaf(b2f((u16)vh[j]) + b2f((u16)vl[j]), q[i * 8 + j], s);
      }
      s *= 0.17677669529663687f;  // 1/sqrt(32)
    }
    sc[r] = s;
    mx = fmaxf(mx, s);
  }
  mx = warp_max(mx);
  float sm = 0.f;
  #pragma unroll
  for (int r = 0; r < 4; ++r) {
    int k = lane + 64 * r;
    float e = (k < SEQL) ? __expf(sc[r] - mx) : 0.f;
    sc[r] = e;
    sm += e;
  }
  sm = warp_sum(sm);
  float inv = 1.f / sm;
  #pragma unroll
  for (int r = 0; r < 4; ++r) {
    int k = lane + 64 * r;
    if (k < SEQL) Ss[w][k] = sc[r] * inv;
  }
  // PV: lanes 0..31 handle d; halves split keys (same-wave LDS, no barrier)
  int d = lane & 31, half = lane >> 5;
  float acc = 0.f;
  for (int i = 0; i < 99; ++i) {
    int k = half * 99 + i;
    if (k < SEQL) {
      size_t o = ((size_t)(b * SEQL + k)) * 768 + 512 + h * 32 + d;
      acc = fmaf(Ss[w][k], b2f(kvh[o]) + b2f(kvl[o]), acc);
    }
  }
  acc += __shfl_xor(acc, 32);
  if (lane < 32) ao[(b * NHEADS + h) * 32 + d] = acc;
}

// ---------------- out-proj for cls rows: tokc = tok_cls + ao@owT + ob --------
__global__ __launch_bounds__(256) void k_oproj_cls(const float* __restrict__ ao,
                                                   const float* __restrict__ ow,
                                                   const float* __restrict__ ob,
                                                   const float* __restrict__ tok,
                                                   float* __restrict__ tokc) {
  const int b = blockIdx.x, n = threadIdx.x;
  __shared__ float xs[DMODEL];
  xs[n] = ao[b * DMODEL + n];
  __syncthreads();
  float val = ob[n];
  #pragma unroll 4
  for (int i = 0; i < 64; ++i) {
    float4 wv = *(const float4*)(ow + (size_t)n * DMODEL + i * 4);
    val = fmaf(wv.x, xs[i * 4 + 0], val);
    val = fmaf(wv.y, xs[i * 4 + 1], val);
    val = fmaf(wv.z, xs[i * 4 + 2], val);
    val = fmaf(wv.w, xs[i * 4 + 3], val);
  }
  tokc[b * DMODEL + n] = tok[(size_t)b * SEQL * DMODEL + n] + val;
}

// ---------------- LN2 + router for cls rows: x2cf fp32 + mask ----------------
__global__ __launch_bounds__(256) void k_route_cls(const float* __restrict__ tokc,
                                                   const float* __restrict__ g,
                                                   const float* __restrict__ bb,
                                                   const float* __restrict__ rw,
                                                   const float* __restrict__ rb,
                                                   float* __restrict__ x2cf,
                                                   float* __restrict__ maskf) {
  const int t = blockIdx.x * 4 + (threadIdx.x >> 6);
  const int lane = threadIdx.x & 63;
  float vv[4];
  *(float4*)vv = *(const float4*)&tokc[t * DMODEL + lane * 4];
  float s1 = vv[0] + vv[1] + vv[2] + vv[3];
  float s2 = vv[0]*vv[0] + vv[1]*vv[1] + vv[2]*vv[2] + vv[3]*vv[3];
  s1 = warp_sum(s1);
  s2 = warp_sum(s2);
  float mu = s1 * (1.f / DMODEL);
  float var = s2 * (1.f / DMODEL) - mu * mu;
  float rs = rsqrtf(var + 1e-5f);
  float xd[4];
  #pragma unroll
  for (int j = 0; j < 4; ++j)
    xd[j] = (vv[j] - mu) * rs * g[lane * 4 + j] + bb[lane * 4 + j];
  *(float4*)&x2cf[t * DMODEL + lane * 4] = *(const float4*)xd;
  float p[NEXP];
  #pragma unroll
  for (int e = 0; e < NEXP; ++e) {
    float s = 0.f;
    #pragma unroll
    for (int j = 0; j < 4; ++j) s = fmaf(xd[j], rw[e * DMODEL + lane * 4 + j], s);
    p[e] = warp_sum(s) + rb[e];
  }
  if (lane < NEXP) {
    int e = lane;
    int rank = 0;
    #pragma unroll
    for (int j = 0; j < NEXP; ++j)
      if (j != e && (p[j] > p[e] || (p[j] == p[e] && j < e))) ++rank;
    maskf[t * NEXP + e] = (rank < 2) ? 1.f : 0.f;
  }
}

// ---------------- MoE GEMM1 (dense, 128 cls tokens): hid = gelu(x2@w1+b1) ----
// grid (8 ffchunk, 4 expert, 2 tpart); thread: ff = ffc*128 + tid&127, 32 t's.
__global__ __launch_bounds__(256) void k_moe1(const float* __restrict__ x2cf,
                                              const float* __restrict__ w1,
                                              const float* __restrict__ b1,
                                              float* __restrict__ hid) {
  const int ffc = blockIdx.x, e = blockIdx.y, tpart = blockIdx.z;
  const int ffl = threadIdx.x & 127, tsub = threadIdx.x >> 7;
  const int ffg = ffc * 128 + ffl;
  const int t0 = tpart * 64 + tsub * 32;
  const float* w1e = w1 + (size_t)e * DMODEL * FFD;
  float acc[32] = {};
  for (int k = 0; k < DMODEL; ++k) {
    float wv = w1e[(size_t)k * FFD + ffg];
    const float* xk = x2cf + k;
    #pragma unroll
    for (int tt = 0; tt < 32; ++tt)
      acc[tt] = fmaf(xk[(t0 + tt) * DMODEL], wv, acc[tt]);
  }
  float bv = b1[e * FFD + ffg];
  #pragma unroll
  for (int tt = 0; tt < 32; ++tt) {
    float v = acc[tt] + bv;
    hid[((size_t)e * NBATCH + t0 + tt) * FFD + ffg] =
        0.5f * v * (1.0f + erff(v * 0.70710678118654752f));
  }
}

// ---------------- MoE GEMM2 + masked sum (deterministic, e-loop inside) ------
// grid (8 dchunk, 8 tgroup); thread: dout = dc*32 + tid&31, 2 tokens.
__global__ __launch_bounds__(256) void k_moe2(const float* __restrict__ hid,
                                              const float* __restrict__ w2,
                                              const float* __restrict__ b2,
                                              const float* __restrict__ maskf,
                                              float* __restrict__ tokc) {
  const int dc = blockIdx.x, tg = blockIdx.y;
  const int dl = threadIdx.x & 31, tsub = threadIdx.x >> 5;
  const int dout = dc * 32 + dl;
  const int t0 = tg * 16 + tsub * 2;
  float sum0 = 0.f, sum1 = 0.f;
  for (int e = 0; e < NEXP; ++e) {
    float m0 = maskf[(t0 + 0) * NEXP + e];
    float m1 = maskf[(t0 + 1) * NEXP + e];
    if (m0 == 0.f && m1 == 0.f) continue;
    const float* w2e = w2 + (size_t)e * FFD * DMODEL;
    const float* h0 = hid + ((size_t)e * NBATCH + t0 + 0) * FFD;
    const float* h1 = hid + ((size_t)e * NBATCH + t0 + 1) * FFD;
    float a0 = 0.f, a1 = 0.f;
    for (int k = 0; k < FFD; ++k) {
      float wv = w2e[(size_t)k * DMODEL + dout];
      a0 = fmaf(h0[k], wv, a0);
      a1 = fmaf(h1[k], wv, a1);
    }
    float bv = b2[e * DMODEL + dout];
    sum0 += m0 * (a0 + bv);
    sum1 += m1 * (a1 + bv);
  }
  tokc[(t0 + 0) * DMODEL + dout] += sum0;
  tokc[(t0 + 1) * DMODEL + dout] += sum1;
}

// ---------------- classifier head on compact tokc ----------------------------
__global__ __launch_bounds__(256) void k_head(const float* __restrict__ tokc,
                                              const float* __restrict__ hw,
                                              const float* __restrict__ hb,
                                              float* __restrict__ out) {
  int b = blockIdx.x;
  int w = threadIdx.x >> 6, lane = threadIdx.x & 63;
  const float* row = tokc + (size_t)b * DMODEL;
  for (int c = w; c < NCLS; c += 4) {
    float s = 0.f;
    for (int d = lane; d < DMODEL; d += 64) s = fmaf(row[d], hw[c * DMODEL + d], s);
    s = warp_sum(s);
    if (lane == 0) out[b * NCLS + c] = s + hb[c];
  }
}

extern "C" void kernel_launch(void* const* d_in, const int* in_sizes, int n_in,
                              void* d_out, int out_size, void* d_ws, size_t ws_size,
                              hipStream_t stream) {
  const float* x      = (const float*)d_in[0];
  const float* conv_w = (const float*)d_in[1];
  const float* conv_b = (const float*)d_in[2];
  const float* cls    = (const float*)d_in[3];
  const float* ln1g   = (const float*)d_in[4];
  const float* ln1b   = (const float*)d_in[5];
  const float* qkv_w  = (const float*)d_in[6];
  const float* qkv_b  = (const float*)d_in[7];
  const float* out_w  = (const float*)d_in[8];
  const float* out_b  = (const float*)d_in[9];
  const float* ln2g   = (const float*)d_in[10];
  const float* ln2b   = (const float*)d_in[11];
  const float* rw     = (const float*)d_in[12];
  const float* rb     = (const float*)d_in[13];
  const float* e_w1   = (const float*)d_in[14];
  const float* e_b1   = (const float*)d_in[15];
  const float* e_w2   = (const float*)d_in[16];
  const float* e_b2   = (const float*)d_in[17];
  const float* head_w = (const float*)d_in[18];
  const float* head_b = (const float*)d_in[19];
  float* out = (float*)d_out;

  char* ws = (char*)d_ws;
  size_t off = 0;
  auto alloc = [&](size_t bytes) {
    void* p = ws + off;
    off += (bytes + 255) & ~(size_t)255;
    return p;
  };
  float* tok   = (float*)alloc((size_t)TTOK * DMODEL * 4);    // 25.8 MB
  u16*   x2h   = (u16*)alloc((size_t)TTOK * DMODEL * 2);      // 12.9
  u16*   x2l   = (u16*)alloc((size_t)TTOK * DMODEL * 2);      // 12.9
  u16*   qkvh  = (u16*)alloc((size_t)TTOK * 768 * 2);         // 38.7 (cols 256.. used)
  u16*   qkvl  = (u16*)alloc((size_t)TTOK * 768 * 2);         // 38.7
  u16*   cwh   = (u16*)alloc((size_t)DMODEL * CONVK * 2);
  u16*   cwl   = (u16*)alloc((size_t)DMODEL * CONVK * 2);
  u16*   qwh   = (u16*)alloc((size_t)768 * DMODEL * 2);
  u16*   qwl   = (u16*)alloc((size_t)768 * DMODEL * 2);
  u16*   qch   = (u16*)alloc((size_t)NBATCH * DMODEL * 2);
  u16*   qcl   = (u16*)alloc((size_t)NBATCH * DMODEL * 2);
  float* aocf  = (float*)alloc((size_t)NBATCH * DMODEL * 4);
  float* tokc  = (float*)alloc((size_t)NBATCH * DMODEL * 4);
  float* x2cf  = (float*)alloc((size_t)NBATCH * DMODEL * 4);
  float* maskf = (float*)alloc((size_t)NBATCH * NEXP * 4);
  float* hid   = (float*)alloc((size_t)NEXP * NBATCH * FFD * 4);  // 2 MB
  // aliases (lifetimes disjoint, stream-ordered):
  u16* Acvh = qkvh;   // im2col hi: consumed by conv GEMM before qkv GEMM writes
  u16* Acvl = qkvl;

  // weight splits
  k_cast2<<<192, 256, 0, stream>>>(conv_w, cwh, cwl);
  k_cast2<<<192, 256, 0, stream>>>(qkv_w, qwh, qwl);

  // patch embed (split GEMM, fp32 out into tok with CMAP) + cls fill
  k_im2col<<<(CM * CONVK / 8) / 256, 256, 0, stream>>>(x, Acvh, Acvl);
  k_mm<1,0,1><<<dim3(CM / 128, 2), 256, 0, stream>>>(
      Acvh, Acvl, cwh, cwl, conv_b, tok, nullptr, nullptr, DMODEL, CM, CONVK);
  k_cls<<<NBATCH, DMODEL, 0, stream>>>(cls, tok);

  // LN1 (all tokens) -> x2 hi/lo
  k_ln4<<<TTOK / 4, 256, 0, stream>>>(tok, x2h, x2l, ln1g, ln1b);

  // K,V projection for ALL tokens (N=512: rows 256..767 of qkv_w)
  k_mm<1,1,0><<<dim3(TTOK / 128, 4), 256, 0, stream>>>(
      x2h, x2l, qwh + 256 * DMODEL, qwl + 256 * DMODEL, qkv_b + 256,
      nullptr, qkvh + 256, qkvl + 256, 768, TTOK, DMODEL);

  // Q projection for cls rows only
  k_qcls<<<NBATCH, 256, 0, stream>>>(x2h, x2l, qwh, qwl, qkv_b, qch, qcl);

  // single-query attention for cls
  k_attn_cls<<<NBATCH * NHEADS / 4, 256, 0, stream>>>(qch, qcl, qkvh, qkvl, aocf);

  // out-proj + residual -> compact tokc
  k_oproj_cls<<<NBATCH, 256, 0, stream>>>(aocf, out_w, out_b, tok, tokc);

  // LN2 + router (cls only)
  k_route_cls<<<NBATCH / 4, 256, 0, stream>>>(tokc, ln2g, ln2b, rw, rb, x2cf, maskf);

  // MoE (dense over 4 experts x 128 tokens, fp32)
  k_moe1<<<dim3(8, NEXP, 2), 256, 0, stream>>>(x2cf, e_w1, e_b1, hid);
  k_moe2<<<dim3(8, 8), 256, 0, stream>>>(hid, e_w2, e_b2, maskf, tokc);

  // head
  k_head<<<NBATCH, 256, 0, stream>>>(tokc, head_w, head_b, out);
}

// Round 8
// 236.369 us; speedup vs baseline: 16.3915x; 1.9456x over previous
//
#include <hip/hip_runtime.h>
#include <hip/hip_bf16.h>
#include <math.h>

#define TTOK   25216      // 128*197
#define SEQL   197
#define NBATCH 128
#define DMODEL 256
#define NHEADS 8
#define FFD    1024
#define NEXP   4
#define NCLS   38
#define CONVK  768
#define NPATCH 196
#define CM     25088      // conv GEMM rows = 128*196

typedef unsigned short u16;
typedef unsigned int u32;
using s16x8 = __attribute__((ext_vector_type(8))) short;
using f32x4 = __attribute__((ext_vector_type(4))) float;

__device__ __forceinline__ float b2f(u16 v) {
  union { unsigned u; float f; } x; x.u = (unsigned)v << 16; return x.f;
}
__device__ __forceinline__ u16 f2b(float f) {
  __hip_bfloat16 h = __float2bfloat16(f);
  return *reinterpret_cast<u16*>(&h);
}
__device__ __forceinline__ void gload16(const void* g, void* l) {
  __builtin_amdgcn_global_load_lds(
      (const __attribute__((address_space(1))) void*)g,
      (__attribute__((address_space(3))) void*)l, 16, 0, 0);
}
__device__ __forceinline__ float warp_sum(float v) {
  #pragma unroll
  for (int o = 32; o; o >>= 1) v += __shfl_xor(v, o);
  return v;
}
__device__ __forceinline__ float warp_max(float v) {
  #pragma unroll
  for (int o = 32; o; o >>= 1) v = fmaxf(v, __shfl_xor(v, o));
  return v;
}

// ---------------- fp32 -> bf16 hi/lo split cast (n % 1024 == 0) --------------
__global__ __launch_bounds__(256) void k_cast2(const float* __restrict__ in,
                                               u16* __restrict__ hi,
                                               u16* __restrict__ lo) {
  int i = (blockIdx.x * 256 + threadIdx.x) * 4;
  float4 v = *(const float4*)&in[i];
  float vv[4] = {v.x, v.y, v.z, v.w};
  u16 h[4], l[4];
  #pragma unroll
  for (int j = 0; j < 4; ++j) {
    h[j] = f2b(vv[j]);
    l[j] = f2b(vv[j] - b2f(h[j]));
  }
  *(uint2*)&hi[i] = *(const uint2*)h;
  *(uint2*)&lo[i] = *(const uint2*)l;
}

// ---------------- im2col + split cast: x fp32 -> Acv hi/lo [25088][768] ------
__global__ __launch_bounds__(256) void k_im2col(const float* __restrict__ x,
                                                u16* __restrict__ Ah,
                                                u16* __restrict__ Al) {
  long idx = ((long)blockIdx.x * 256 + threadIdx.x) * 8;
  int m = (int)(idx / CONVK), k = (int)(idx % CONVK);
  int b = m / NPATCH, p = m - b * NPATCH;
  int py = p / 14, px = p - py * 14;
  int c = k >> 8, r = k & 255;
  int ry = r >> 4, rx = r & 15;                       // rx in {0, 8}
  const float* src = &x[(((long)(b * 3 + c) * 224) + py * 16 + ry) * 224 +
                        px * 16 + rx];
  u16 h[8], l[8];
  #pragma unroll
  for (int j = 0; j < 8; ++j) {
    float v = src[j];
    h[j] = f2b(v);
    l[j] = f2b(v - b2f(h[j]));
  }
  *(uint4*)&Ah[idx] = *(const uint4*)h;
  *(uint4*)&Al[idx] = *(const uint4*)l;
}

// ---------------- bf16(x2) MFMA GEMM -----------------------------------------
// C[m][n] = op( sum_k A[m][k]*W[n][k] + bias[n] )
// SPLIT: A=Ah+Al, W=Wh+Wl, acc = AhWh + AhWl + AlWh  (fp32-class accuracy)
template<int SPLIT, int OUTBF, int CMAP>
__global__ __launch_bounds__(256) void k_mm(
    const u16* __restrict__ Ah, const u16* __restrict__ Al,
    const u16* __restrict__ Wh, const u16* __restrict__ Wl,
    const float* __restrict__ bias,
    float* __restrict__ Cf, u16* __restrict__ Cb, u16* __restrict__ Cb2, int ldc,
    int M, int K) {
  const int m0 = blockIdx.x * 128;
  const int n0 = blockIdx.y * 128;
  __shared__ u16 As[(SPLIT ? 2 : 1) * 128 * 64];
  __shared__ u16 Bs[(SPLIT ? 2 : 1) * 128 * 64];
  const int tid = threadIdx.x;
  const int lane = tid & 63;
  const int wv = tid >> 6;
  const int wr = wv >> 1, wc = wv & 1;
  f32x4 acc[4][4] = {};

  long aoff[4], woff[4]; int rofs[4];
  #pragma unroll
  for (int i = 0; i < 4; ++i) {
    int off = i * 4096 + tid * 16;
    int row = off >> 7;
    int c16 = (off >> 4) & 7;
    int kk = (c16 ^ (row & 7)) << 3;
    aoff[i] = (long)(m0 + row) * K + kk;
    woff[i] = (long)(n0 + row) * K + kk;
    rofs[i] = off;
  }
  for (int kc = 0; kc < K; kc += 64) {
    #pragma unroll
    for (int i = 0; i < 4; ++i) {
      gload16(Ah + aoff[i] + kc, (char*)As + rofs[i]);
      gload16(Wh + woff[i] + kc, (char*)Bs + rofs[i]);
      if (SPLIT) {
        gload16(Al + aoff[i] + kc, (char*)As + 16384 + rofs[i]);
        gload16(Wl + woff[i] + kc, (char*)Bs + 16384 + rofs[i]);
      }
    }
    __syncthreads();
    #pragma unroll
    for (int kf = 0; kf < 2; ++kf) {
      s16x8 ah[4], bh[4], al[4], bl[4];
      #pragma unroll
      for (int i = 0; i < 4; ++i) {
        int rowa = wr * 64 + i * 16 + (lane & 15);
        int kb = (kf * 64 + ((lane >> 4) << 4)) ^ ((rowa & 7) << 4);
        ah[i] = *(const s16x8*)((const char*)As + rowa * 128 + kb);
        if (SPLIT) al[i] = *(const s16x8*)((const char*)As + 16384 + rowa * 128 + kb);
        int rowb = wc * 64 + i * 16 + (lane & 15);
        int kbn = (kf * 64 + ((lane >> 4) << 4)) ^ ((rowb & 7) << 4);
        bh[i] = *(const s16x8*)((const char*)Bs + rowb * 128 + kbn);
        if (SPLIT) bl[i] = *(const s16x8*)((const char*)Bs + 16384 + rowb * 128 + kbn);
      }
      #pragma unroll
      for (int i = 0; i < 4; ++i)
        #pragma unroll
        for (int j = 0; j < 4; ++j)
          acc[i][j] = __builtin_amdgcn_mfma_f32_16x16x32_bf16(ah[i], bh[j],
                                                              acc[i][j], 0, 0, 0);
      if (SPLIT) {
        #pragma unroll
        for (int i = 0; i < 4; ++i)
          #pragma unroll
          for (int j = 0; j < 4; ++j)
            acc[i][j] = __builtin_amdgcn_mfma_f32_16x16x32_bf16(ah[i], bl[j],
                                                                acc[i][j], 0, 0, 0);
        #pragma unroll
        for (int i = 0; i < 4; ++i)
          #pragma unroll
          for (int j = 0; j < 4; ++j)
            acc[i][j] = __builtin_amdgcn_mfma_f32_16x16x32_bf16(al[i], bh[j],
                                                                acc[i][j], 0, 0, 0);
      }
    }
    __syncthreads();
  }
  const int mb = m0 + wr * 64 + ((lane >> 4) << 2);
  const int nb = n0 + wc * 64 + (lane & 15);
  #pragma unroll
  for (int i = 0; i < 4; ++i) {
    #pragma unroll
    for (int jf = 0; jf < 4; ++jf) {
      #pragma unroll
      for (int j = 0; j < 4; ++j) {
        int m = mb + i * 16 + j;
        int n = nb + jf * 16;
        float v = acc[i][jf][j] + bias[n];
        long cr;
        if (CMAP) { int bq = m / NPATCH; cr = (long)bq * SEQL + (m - bq * NPATCH) + 1; }
        else        cr = m;
        if (OUTBF) {
          u16 h = f2b(v);
          Cb[cr * ldc + n] = h;
          Cb2[cr * ldc + n] = f2b(v - b2f(h));
        } else {
          Cf[cr * ldc + n] = v;
        }
      }
    }
  }
}

// ---------------- LayerNorm (wave per row): fp32 in -> bf16 hi/lo out --------
__global__ __launch_bounds__(256) void k_ln4(const float* __restrict__ in,
                                             u16* __restrict__ outh,
                                             u16* __restrict__ outl,
                                             const float* __restrict__ g,
                                             const float* __restrict__ bb) {
  const int row = blockIdx.x * 4 + (threadIdx.x >> 6);
  const int lane = threadIdx.x & 63;
  float vv[4];
  *(float4*)vv = *(const float4*)&in[(size_t)row * DMODEL + lane * 4];
  float s1 = vv[0] + vv[1] + vv[2] + vv[3];
  float s2 = vv[0]*vv[0] + vv[1]*vv[1] + vv[2]*vv[2] + vv[3]*vv[3];
  s1 = warp_sum(s1);
  s2 = warp_sum(s2);
  float mu = s1 * (1.f / DMODEL);
  float var = s2 * (1.f / DMODEL) - mu * mu;
  float rs = rsqrtf(var + 1e-5f);
  u16 hh[4], ll[4];
  #pragma unroll
  for (int j = 0; j < 4; ++j) {
    float r = (vv[j] - mu) * rs * g[lane * 4 + j] + bb[lane * 4 + j];
    hh[j] = f2b(r);
    ll[j] = f2b(r - b2f(hh[j]));
  }
  *(uint2*)&outh[(size_t)row * DMODEL + lane * 4] = *(const uint2*)hh;
  *(uint2*)&outl[(size_t)row * DMODEL + lane * 4] = *(const uint2*)ll;
}

__global__ void k_cls(const float* __restrict__ cls, float* __restrict__ tok) {
  tok[(size_t)blockIdx.x * SEQL * DMODEL + threadIdx.x] = cls[threadIdx.x];
}

// ---------------- Q projection for cls rows only: [128][256] hi/lo -----------
__global__ __launch_bounds__(256) void k_qcls(const u16* __restrict__ x2h,
                                              const u16* __restrict__ x2l,
                                              const u16* __restrict__ qwh,
                                              const u16* __restrict__ qwl,
                                              const float* __restrict__ qb,
                                              u16* __restrict__ qch,
                                              u16* __restrict__ qcl) {
  const int b = blockIdx.x, n = threadIdx.x;
  __shared__ float xs[DMODEL];
  size_t r0 = (size_t)b * SEQL * DMODEL;
  xs[n] = b2f(x2h[r0 + n]) + b2f(x2l[r0 + n]);
  __syncthreads();
  float val = qb[n];
  #pragma unroll 4
  for (int i = 0; i < 32; ++i) {
    s16x8 wh = *(const s16x8*)(qwh + (size_t)n * DMODEL + i * 8);
    s16x8 wl = *(const s16x8*)(qwl + (size_t)n * DMODEL + i * 8);
    #pragma unroll
    for (int j = 0; j < 8; ++j)
      val = fmaf(b2f((u16)wh[j]) + b2f((u16)wl[j]), xs[i * 8 + j], val);
  }
  u16 h = f2b(val);
  qch[b * DMODEL + n] = h;
  qcl[b * DMODEL + n] = f2b(val - b2f(h));
}

// ---------------- single-query attention (cls only), fp32 math ---------------
__global__ __launch_bounds__(256) void k_attn_cls(const u16* __restrict__ qch,
                                                  const u16* __restrict__ qcl,
                                                  const u16* __restrict__ kvh,
                                                  const u16* __restrict__ kvl,
                                                  float* __restrict__ ao) {
  const int w = threadIdx.x >> 6, lane = threadIdx.x & 63;
  const int unit = blockIdx.x * 4 + w;
  const int b = unit >> 3, h = unit & 7;
  __shared__ float Ss[4][200];
  float q[32];
  #pragma unroll
  for (int i = 0; i < 4; ++i) {
    s16x8 vh = *(const s16x8*)(qch + b * DMODEL + h * 32 + i * 8);
    s16x8 vl = *(const s16x8*)(qcl + b * DMODEL + h * 32 + i * 8);
    #pragma unroll
    for (int j = 0; j < 8; ++j) q[i * 8 + j] = b2f((u16)vh[j]) + b2f((u16)vl[j]);
  }
  float sc[4];
  float mx = -1e30f;
  #pragma unroll
  for (int r = 0; r < 4; ++r) {
    int k = lane + 64 * r;
    float s = -1e30f;
    if (k < SEQL) {
      size_t base = ((size_t)(b * SEQL + k)) * 768 + 256 + h * 32;
      s = 0.f;
      #pragma unroll
      for (int i = 0; i < 4; ++i) {
        s16x8 vh = *(const s16x8*)(kvh + base + i * 8);
        s16x8 vl = *(const s16x8*)(kvl + base + i * 8);
        #pragma unroll
        for (int j = 0; j < 8; ++j)
          s = fmaf(b2f((u16)vh[j]) + b2f((u16)vl[j]), q[i * 8 + j], s);
      }
      s *= 0.17677669529663687f;  // 1/sqrt(32)
    }
    sc[r] = s;
    mx = fmaxf(mx, s);
  }
  mx = warp_max(mx);
  float sm = 0.f;
  #pragma unroll
  for (int r = 0; r < 4; ++r) {
    int k = lane + 64 * r;
    float e = (k < SEQL) ? __expf(sc[r] - mx) : 0.f;
    sc[r] = e;
    sm += e;
  }
  sm = warp_sum(sm);
  float inv = 1.f / sm;
  #pragma unroll
  for (int r = 0; r < 4; ++r) {
    int k = lane + 64 * r;
    if (k < SEQL) Ss[w][k] = sc[r] * inv;
  }
  int d = lane & 31, half = lane >> 5;
  float acc = 0.f;
  for (int i = 0; i < 99; ++i) {
    int k = half * 99 + i;
    if (k < SEQL) {
      size_t o = ((size_t)(b * SEQL + k)) * 768 + 512 + h * 32 + d;
      acc = fmaf(Ss[w][k], b2f(kvh[o]) + b2f(kvl[o]), acc);
    }
  }
  acc += __shfl_xor(acc, 32);
  if (lane < 32) ao[(b * NHEADS + h) * 32 + d] = acc;
}

// ---------------- out-proj for cls rows: tokc = tok_cls + ao@owT + ob --------
__global__ __launch_bounds__(256) void k_oproj_cls(const float* __restrict__ ao,
                                                   const float* __restrict__ ow,
                                                   const float* __restrict__ ob,
                                                   const float* __restrict__ tok,
                                                   float* __restrict__ tokc) {
  const int b = blockIdx.x, n = threadIdx.x;
  __shared__ float xs[DMODEL];
  xs[n] = ao[b * DMODEL + n];
  __syncthreads();
  float val = ob[n];
  #pragma unroll 4
  for (int i = 0; i < 64; ++i) {
    float4 wv = *(const float4*)(ow + (size_t)n * DMODEL + i * 4);
    val = fmaf(wv.x, xs[i * 4 + 0], val);
    val = fmaf(wv.y, xs[i * 4 + 1], val);
    val = fmaf(wv.z, xs[i * 4 + 2], val);
    val = fmaf(wv.w, xs[i * 4 + 3], val);
  }
  tokc[b * DMODEL + n] = tok[(size_t)b * SEQL * DMODEL + n] + val;
}

// ---------------- LN2 + router for cls rows: x2cf fp32 + mask ----------------
__global__ __launch_bounds__(256) void k_route_cls(const float* __restrict__ tokc,
                                                   const float* __restrict__ g,
                                                   const float* __restrict__ bb,
                                                   const float* __restrict__ rw,
                                                   const float* __restrict__ rb,
                                                   float* __restrict__ x2cf,
                                                   float* __restrict__ maskf) {
  const int t = blockIdx.x * 4 + (threadIdx.x >> 6);
  const int lane = threadIdx.x & 63;
  float vv[4];
  *(float4*)vv = *(const float4*)&tokc[t * DMODEL + lane * 4];
  float s1 = vv[0] + vv[1] + vv[2] + vv[3];
  float s2 = vv[0]*vv[0] + vv[1]*vv[1] + vv[2]*vv[2] + vv[3]*vv[3];
  s1 = warp_sum(s1);
  s2 = warp_sum(s2);
  float mu = s1 * (1.f / DMODEL);
  float var = s2 * (1.f / DMODEL) - mu * mu;
  float rs = rsqrtf(var + 1e-5f);
  float xd[4];
  #pragma unroll
  for (int j = 0; j < 4; ++j)
    xd[j] = (vv[j] - mu) * rs * g[lane * 4 + j] + bb[lane * 4 + j];
  *(float4*)&x2cf[t * DMODEL + lane * 4] = *(const float4*)xd;
  float p[NEXP];
  #pragma unroll
  for (int e = 0; e < NEXP; ++e) {
    float s = 0.f;
    #pragma unroll
    for (int j = 0; j < 4; ++j) s = fmaf(xd[j], rw[e * DMODEL + lane * 4 + j], s);
    p[e] = warp_sum(s) + rb[e];
  }
  if (lane < NEXP) {
    int e = lane;
    int rank = 0;
    #pragma unroll
    for (int j = 0; j < NEXP; ++j)
      if (j != e && (p[j] > p[e] || (p[j] == p[e] && j < e))) ++rank;
    maskf[t * NEXP + e] = (rank < 2) ? 1.f : 0.f;
  }
}

// ---------------- MoE GEMM1 (parallel): one block per (expert, token) --------
// early-exit on mask; x2 row in LDS; thread owns 4 ff cols (indep chains).
__global__ __launch_bounds__(256) void k_moe1(const float* __restrict__ x2cf,
                                              const float* __restrict__ w1,
                                              const float* __restrict__ b1,
                                              const float* __restrict__ maskf,
                                              float* __restrict__ hid) {
  const int e = blockIdx.x, t = blockIdx.y;
  if (maskf[t * NEXP + e] == 0.f) return;
  __shared__ float xs[DMODEL];
  const int tid = threadIdx.x;
  xs[tid] = x2cf[t * DMODEL + tid];
  __syncthreads();
  const float* w1e = w1 + (size_t)e * DMODEL * FFD + tid;
  float a0 = 0.f, a1 = 0.f, a2 = 0.f, a3 = 0.f;
  #pragma unroll 4
  for (int k = 0; k < DMODEL; ++k) {
    float xv = xs[k];
    const float* wr_ = w1e + (size_t)k * FFD;
    a0 = fmaf(xv, wr_[0], a0);
    a1 = fmaf(xv, wr_[256], a1);
    a2 = fmaf(xv, wr_[512], a2);
    a3 = fmaf(xv, wr_[768], a3);
  }
  float accs[4] = {a0, a1, a2, a3};
  float* hrow = hid + ((size_t)e * NBATCH + t) * FFD;
  #pragma unroll
  for (int j = 0; j < 4; ++j) {
    float v = accs[j] + b1[e * FFD + tid + j * 256];
    hrow[tid + j * 256] = 0.5f * v * (1.0f + erff(v * 0.70710678118654752f));
  }
}

// ---------------- MoE GEMM2 (parallel): block per (token, dchunk) ------------
// exactly-2 active experts; hid rows in LDS; k split across 2 thread halves.
__global__ __launch_bounds__(256) void k_moe2(const float* __restrict__ hid,
                                              const float* __restrict__ w2,
                                              const float* __restrict__ b2,
                                              const float* __restrict__ maskf,
                                              float* __restrict__ tokc) {
  const int t = blockIdx.x, dc = blockIdx.y;
  const int tid = threadIdx.x;
  const int dl = tid & 127, kh = tid >> 7;
  const int dout = dc * 128 + dl;
  int e0 = 0;
  while (e0 < 3 && maskf[t * NEXP + e0] == 0.f) ++e0;
  int e1 = e0 + 1;
  while (e1 < 3 && maskf[t * NEXP + e1] == 0.f) ++e1;
  __shared__ float hs0[FFD], hs1[FFD];
  const float* h0 = hid + ((size_t)e0 * NBATCH + t) * FFD;
  const float* h1 = hid + ((size_t)e1 * NBATCH + t) * FFD;
  for (int i = tid * 4; i < FFD; i += 1024) {
    *(float4*)&hs0[i] = *(const float4*)&h0[i];
    *(float4*)&hs1[i] = *(const float4*)&h1[i];
  }
  __syncthreads();
  const float* w20 = w2 + (size_t)e0 * FFD * DMODEL + dout;
  const float* w21 = w2 + (size_t)e1 * FFD * DMODEL + dout;
  float a0 = 0.f, a1 = 0.f;
  const int k0 = kh * 512;
  #pragma unroll 8
  for (int k = k0; k < k0 + 512; ++k) {
    a0 = fmaf(hs0[k], w20[(size_t)k * DMODEL], a0);
    a1 = fmaf(hs1[k], w21[(size_t)k * DMODEL], a1);
  }
  __shared__ float red[256];
  red[tid] = a0 + a1;
  __syncthreads();
  if (kh == 0) {
    float full = red[dl] + red[128 + dl] +
                 b2[e0 * DMODEL + dout] + b2[e1 * DMODEL + dout];
    tokc[t * DMODEL + dout] += full;
  }
}

// ---------------- classifier head on compact tokc ----------------------------
__global__ __launch_bounds__(256) void k_head(const float* __restrict__ tokc,
                                              const float* __restrict__ hw,
                                              const float* __restrict__ hb,
                                              float* __restrict__ out) {
  int b = blockIdx.x;
  int w = threadIdx.x >> 6, lane = threadIdx.x & 63;
  const float* row = tokc + (size_t)b * DMODEL;
  for (int c = w; c < NCLS; c += 4) {
    float s = 0.f;
    for (int d = lane; d < DMODEL; d += 64) s = fmaf(row[d], hw[c * DMODEL + d], s);
    s = warp_sum(s);
    if (lane == 0) out[b * NCLS + c] = s + hb[c];
  }
}

extern "C" void kernel_launch(void* const* d_in, const int* in_sizes, int n_in,
                              void* d_out, int out_size, void* d_ws, size_t ws_size,
                              hipStream_t stream) {
  const float* x      = (const float*)d_in[0];
  const float* conv_w = (const float*)d_in[1];
  const float* conv_b = (const float*)d_in[2];
  const float* cls    = (const float*)d_in[3];
  const float* ln1g   = (const float*)d_in[4];
  const float* ln1b   = (const float*)d_in[5];
  const float* qkv_w  = (const float*)d_in[6];
  const float* qkv_b  = (const float*)d_in[7];
  const float* out_w  = (const float*)d_in[8];
  const float* out_b  = (const float*)d_in[9];
  const float* ln2g   = (const float*)d_in[10];
  const float* ln2b   = (const float*)d_in[11];
  const float* rw     = (const float*)d_in[12];
  const float* rb     = (const float*)d_in[13];
  const float* e_w1   = (const float*)d_in[14];
  const float* e_b1   = (const float*)d_in[15];
  const float* e_w2   = (const float*)d_in[16];
  const float* e_b2   = (const float*)d_in[17];
  const float* head_w = (const float*)d_in[18];
  const float* head_b = (const float*)d_in[19];
  float* out = (float*)d_out;

  char* ws = (char*)d_ws;
  size_t off = 0;
  auto alloc = [&](size_t bytes) {
    void* p = ws + off;
    off += (bytes + 255) & ~(size_t)255;
    return p;
  };
  float* tok   = (float*)alloc((size_t)TTOK * DMODEL * 4);    // 25.8 MB
  u16*   x2h   = (u16*)alloc((size_t)TTOK * DMODEL * 2);      // 12.9
  u16*   x2l   = (u16*)alloc((size_t)TTOK * DMODEL * 2);      // 12.9
  u16*   qkvh  = (u16*)alloc((size_t)TTOK * 768 * 2);         // 38.7 (cols 256.. used)
  u16*   qkvl  = (u16*)alloc((size_t)TTOK * 768 * 2);         // 38.7
  u16*   cwh   = (u16*)alloc((size_t)DMODEL * CONVK * 2);
  u16*   cwl   = (u16*)alloc((size_t)DMODEL * CONVK * 2);
  u16*   qwh   = (u16*)alloc((size_t)768 * DMODEL * 2);
  u16*   qwl   = (u16*)alloc((size_t)768 * DMODEL * 2);
  u16*   qch   = (u16*)alloc((size_t)NBATCH * DMODEL * 2);
  u16*   qcl   = (u16*)alloc((size_t)NBATCH * DMODEL * 2);
  float* aocf  = (float*)alloc((size_t)NBATCH * DMODEL * 4);
  float* tokc  = (float*)alloc((size_t)NBATCH * DMODEL * 4);
  float* x2cf  = (float*)alloc((size_t)NBATCH * DMODEL * 4);
  float* maskf = (float*)alloc((size_t)NBATCH * NEXP * 4);
  float* hid   = (float*)alloc((size_t)NEXP * NBATCH * FFD * 4);  // 2 MB
  // aliases (lifetimes disjoint, stream-ordered):
  u16* Acvh = qkvh;   // im2col hi: consumed by conv GEMM before qkv GEMM writes
  u16* Acvl = qkvl;

  // weight splits
  k_cast2<<<192, 256, 0, stream>>>(conv_w, cwh, cwl);
  k_cast2<<<192, 256, 0, stream>>>(qkv_w, qwh, qwl);

  // patch embed (split GEMM, fp32 out into tok with CMAP) + cls fill
  k_im2col<<<(CM * CONVK / 8) / 256, 256, 0, stream>>>(x, Acvh, Acvl);
  k_mm<1,0,1><<<dim3(CM / 128, 2), 256, 0, stream>>>(
      Acvh, Acvl, cwh, cwl, conv_b, tok, nullptr, nullptr, DMODEL, CM, CONVK);
  k_cls<<<NBATCH, DMODEL, 0, stream>>>(cls, tok);

  // LN1 (all tokens) -> x2 hi/lo
  k_ln4<<<TTOK / 4, 256, 0, stream>>>(tok, x2h, x2l, ln1g, ln1b);

  // K,V projection for ALL tokens (N=512: rows 256..767 of qkv_w)
  k_mm<1,1,0><<<dim3(TTOK / 128, 4), 256, 0, stream>>>(
      x2h, x2l, qwh + 256 * DMODEL, qwl + 256 * DMODEL, qkv_b + 256,
      nullptr, qkvh + 256, qkvl + 256, 768, TTOK, DMODEL);

  // Q projection for cls rows only
  k_qcls<<<NBATCH, 256, 0, stream>>>(x2h, x2l, qwh, qwl, qkv_b, qch, qcl);

  // single-query attention for cls
  k_attn_cls<<<NBATCH * NHEADS / 4, 256, 0, stream>>>(qch, qcl, qkvh, qkvl, aocf);

  // out-proj + residual -> compact tokc
  k_oproj_cls<<<NBATCH, 256, 0, stream>>>(aocf, out_w, out_b, tok, tokc);

  // LN2 + router (cls only)
  k_route_cls<<<NBATCH / 4, 256, 0, stream>>>(tokc, ln2g, ln2b, rw, rb, x2cf, maskf);

  // MoE (parallelized, fp32, deterministic)
  k_moe1<<<dim3(NEXP, NBATCH), 256, 0, stream>>>(x2cf, e_w1, e_b1, maskf, hid);
  k_moe2<<<dim3(NBATCH, 2), 256, 0, stream>>>(hid, e_w2, e_b2, maskf, tokc);

  // head
  k_head<<<NBATCH, 256, 0, stream>>>(tokc, head_w, head_b, out);
}

// Round 9
// 212.262 us; speedup vs baseline: 18.2532x; 1.1136x over previous
//
#include <hip/hip_runtime.h>
#include <hip/hip_bf16.h>
#include <math.h>

#define TTOK   25216      // 128*197
#define SEQL   197
#define NBATCH 128
#define DMODEL 256
#define NHEADS 8
#define FFD    1024
#define NEXP   4
#define NCLS   38
#define CONVK  768
#define NPATCH 196
#define CM     25088      // conv GEMM rows = 128*196

typedef unsigned short u16;
typedef unsigned int u32;
using s16x8 = __attribute__((ext_vector_type(8))) short;
using f32x4 = __attribute__((ext_vector_type(4))) float;

__device__ __forceinline__ float b2f(u16 v) {
  union { unsigned u; float f; } x; x.u = (unsigned)v << 16; return x.f;
}
__device__ __forceinline__ u16 f2b(float f) {
  __hip_bfloat16 h = __float2bfloat16(f);
  return *reinterpret_cast<u16*>(&h);
}
__device__ __forceinline__ void gload16(const void* g, void* l) {
  __builtin_amdgcn_global_load_lds(
      (const __attribute__((address_space(1))) void*)g,
      (__attribute__((address_space(3))) void*)l, 16, 0, 0);
}
__device__ __forceinline__ float warp_sum(float v) {
  #pragma unroll
  for (int o = 32; o; o >>= 1) v += __shfl_xor(v, o);
  return v;
}
__device__ __forceinline__ float warp_max(float v) {
  #pragma unroll
  for (int o = 32; o; o >>= 1) v = fmaxf(v, __shfl_xor(v, o));
  return v;
}
// BK=32 bank-spread swizzle: chunk' = chunk ^ fsw(row), 2-way (free) on b128 reads
__device__ __forceinline__ int fsw(int row) { return (row ^ (row >> 2)) & 3; }

// ---------------- fp32 -> bf16 hi/lo split cast (n % 1024 == 0) --------------
__global__ __launch_bounds__(256) void k_cast2(const float* __restrict__ in,
                                               u16* __restrict__ hi,
                                               u16* __restrict__ lo) {
  int i = (blockIdx.x * 256 + threadIdx.x) * 4;
  float4 v = *(const float4*)&in[i];
  float vv[4] = {v.x, v.y, v.z, v.w};
  u16 h[4], l[4];
  #pragma unroll
  for (int j = 0; j < 4; ++j) {
    h[j] = f2b(vv[j]);
    l[j] = f2b(vv[j] - b2f(h[j]));
  }
  *(uint2*)&hi[i] = *(const uint2*)h;
  *(uint2*)&lo[i] = *(const uint2*)l;
}

// ---------------- fused im2col + split-MFMA conv GEMM ------------------------
// tile 128x128, BK=32; A reg-staged from x (fp32->hi/lo, swizzled ds_write);
// W via global_load_lds with pre-swizzled source. acc = AhWh + AhWl + AlWh.
__global__ __launch_bounds__(256) void k_conv(const float* __restrict__ x,
                                              const u16* __restrict__ cwh,
                                              const u16* __restrict__ cwl,
                                              const float* __restrict__ cb,
                                              float* __restrict__ tok) {
  const int m0 = blockIdx.x * 128;
  const int n0 = blockIdx.y * 128;
  __shared__ __align__(16) u16 lds[4 * 128 * 32];
  u16* Ah_s = lds;
  u16* Al_s = lds + 4096;
  u16* Wh_s = lds + 8192;
  u16* Wl_s = lds + 12288;
  const int tid = threadIdx.x;
  const int lane = tid & 63;
  const int wv = tid >> 6;
  const int wr = wv >> 1, wc = wv & 1;
  const int l15 = lane & 15, l4 = lane >> 4;
  f32x4 acc[4][4] = {};

  // A staging map: it in 0..3 -> row = it*32 + tid>>3, kk = (tid&7)*4
  const int kk_t = (tid & 7) * 4;
  long abase[4]; int aldso[4];
  #pragma unroll
  for (int it = 0; it < 4; ++it) {
    int row = it * 32 + (tid >> 3);
    int m = m0 + row;
    int b = m / NPATCH, p = m - b * NPATCH;
    int py = p / 14, px = p - py * 14;
    abase[it] = (long)(b * 3) * 50176 + (py * 16) * 224 + px * 16;
    aldso[it] = row * 64 + (((kk_t >> 3) ^ fsw(row)) << 4) + (kk_t & 7) * 2;
  }
  // W staging (gload16, pre-swizzled source): 2 rounds x 8KB
  long woff[2]; int wofs[2];
  #pragma unroll
  for (int r = 0; r < 2; ++r) {
    int off = r * 4096 + tid * 16;
    int row = off >> 6;
    int c16 = (off >> 4) & 3;
    int kk = (c16 ^ fsw(row)) << 3;
    woff[r] = (long)(n0 + row) * CONVK + kk;
    wofs[r] = off;
  }
  for (int kc = 0; kc < CONVK; kc += 32) {
    #pragma unroll
    for (int r = 0; r < 2; ++r) {
      gload16(cwh + woff[r] + kc, (char*)Wh_s + wofs[r]);
      gload16(cwl + woff[r] + kc, (char*)Wl_s + wofs[r]);
    }
    int k = kc + kk_t;
    int c = k >> 8, r8 = k & 255;
    long soff = (long)c * 50176 + (r8 >> 4) * 224 + (r8 & 15);
    #pragma unroll
    for (int it = 0; it < 4; ++it) {
      float4 v = *(const float4*)&x[abase[it] + soff];
      float vv[4] = {v.x, v.y, v.z, v.w};
      u16 h[4], l[4];
      #pragma unroll
      for (int j = 0; j < 4; ++j) {
        h[j] = f2b(vv[j]);
        l[j] = f2b(vv[j] - b2f(h[j]));
      }
      *(uint2*)((char*)Ah_s + aldso[it]) = *(const uint2*)h;
      *(uint2*)((char*)Al_s + aldso[it]) = *(const uint2*)l;
    }
    __syncthreads();
    s16x8 ah[4], al[4], bh[4], bl[4];
    #pragma unroll
    for (int i = 0; i < 4; ++i) {
      int rowa = wr * 64 + i * 16 + l15;
      int kba = (l4 ^ fsw(rowa)) << 4;
      ah[i] = *(const s16x8*)((const char*)Ah_s + rowa * 64 + kba);
      al[i] = *(const s16x8*)((const char*)Al_s + rowa * 64 + kba);
      int rowb = wc * 64 + i * 16 + l15;
      int kbb = (l4 ^ fsw(rowb)) << 4;
      bh[i] = *(const s16x8*)((const char*)Wh_s + rowb * 64 + kbb);
      bl[i] = *(const s16x8*)((const char*)Wl_s + rowb * 64 + kbb);
    }
    #pragma unroll
    for (int i = 0; i < 4; ++i)
      #pragma unroll
      for (int j = 0; j < 4; ++j)
        acc[i][j] = __builtin_amdgcn_mfma_f32_16x16x32_bf16(ah[i], bh[j],
                                                            acc[i][j], 0, 0, 0);
    #pragma unroll
    for (int i = 0; i < 4; ++i)
      #pragma unroll
      for (int j = 0; j < 4; ++j)
        acc[i][j] = __builtin_amdgcn_mfma_f32_16x16x32_bf16(ah[i], bl[j],
                                                            acc[i][j], 0, 0, 0);
    #pragma unroll
    for (int i = 0; i < 4; ++i)
      #pragma unroll
      for (int j = 0; j < 4; ++j)
        acc[i][j] = __builtin_amdgcn_mfma_f32_16x16x32_bf16(al[i], bh[j],
                                                            acc[i][j], 0, 0, 0);
    __syncthreads();
  }
  const int mb = m0 + wr * 64 + (l4 << 2);
  const int nb = n0 + wc * 64 + l15;
  #pragma unroll
  for (int i = 0; i < 4; ++i) {
    #pragma unroll
    for (int jf = 0; jf < 4; ++jf) {
      #pragma unroll
      for (int j = 0; j < 4; ++j) {
        int m = mb + i * 16 + j;
        int n = nb + jf * 16;
        int bq = m / NPATCH;
        long cr = (long)bq * SEQL + (m - bq * NPATCH) + 1;
        tok[cr * DMODEL + n] = acc[i][jf][j] + cb[n];
      }
    }
  }
}

// ---------------- split-MFMA GEMM (qkv K/V): fp32 out ------------------------
// A = x2 hi/lo [M][256]; W = qkv_w rows 256..767 hi/lo; C fp32 [M][512].
__global__ __launch_bounds__(256) void k_qkv(const u16* __restrict__ Ah,
                                             const u16* __restrict__ Al,
                                             const u16* __restrict__ Wh,
                                             const u16* __restrict__ Wl,
                                             const float* __restrict__ bias,
                                             float* __restrict__ Cf) {
  const int m0 = blockIdx.x * 128;
  const int n0 = blockIdx.y * 128;
  const int K = DMODEL, ldc = 512;
  __shared__ __align__(16) u16 lds[4 * 128 * 32];
  u16* Ah_s = lds;
  u16* Al_s = lds + 4096;
  u16* Wh_s = lds + 8192;
  u16* Wl_s = lds + 12288;
  const int tid = threadIdx.x;
  const int lane = tid & 63;
  const int wv = tid >> 6;
  const int wr = wv >> 1, wc = wv & 1;
  const int l15 = lane & 15, l4 = lane >> 4;
  f32x4 acc[4][4] = {};

  long aoff[2], woff[2]; int ofs[2];
  #pragma unroll
  for (int r = 0; r < 2; ++r) {
    int off = r * 4096 + tid * 16;
    int row = off >> 6;
    int c16 = (off >> 4) & 3;
    int kk = (c16 ^ fsw(row)) << 3;
    aoff[r] = (long)(m0 + row) * K + kk;
    woff[r] = (long)(n0 + row) * K + kk;
    ofs[r] = off;
  }
  for (int kc = 0; kc < K; kc += 32) {
    #pragma unroll
    for (int r = 0; r < 2; ++r) {
      gload16(Ah + aoff[r] + kc, (char*)Ah_s + ofs[r]);
      gload16(Al + aoff[r] + kc, (char*)Al_s + ofs[r]);
      gload16(Wh + woff[r] + kc, (char*)Wh_s + ofs[r]);
      gload16(Wl + woff[r] + kc, (char*)Wl_s + ofs[r]);
    }
    __syncthreads();
    s16x8 ah[4], al[4], bh[4], bl[4];
    #pragma unroll
    for (int i = 0; i < 4; ++i) {
      int rowa = wr * 64 + i * 16 + l15;
      int kba = (l4 ^ fsw(rowa)) << 4;
      ah[i] = *(const s16x8*)((const char*)Ah_s + rowa * 64 + kba);
      al[i] = *(const s16x8*)((const char*)Al_s + rowa * 64 + kba);
      int rowb = wc * 64 + i * 16 + l15;
      int kbb = (l4 ^ fsw(rowb)) << 4;
      bh[i] = *(const s16x8*)((const char*)Wh_s + rowb * 64 + kbb);
      bl[i] = *(const s16x8*)((const char*)Wl_s + rowb * 64 + kbb);
    }
    #pragma unroll
    for (int i = 0; i < 4; ++i)
      #pragma unroll
      for (int j = 0; j < 4; ++j)
        acc[i][j] = __builtin_amdgcn_mfma_f32_16x16x32_bf16(ah[i], bh[j],
                                                            acc[i][j], 0, 0, 0);
    #pragma unroll
    for (int i = 0; i < 4; ++i)
      #pragma unroll
      for (int j = 0; j < 4; ++j)
        acc[i][j] = __builtin_amdgcn_mfma_f32_16x16x32_bf16(ah[i], bl[j],
                                                            acc[i][j], 0, 0, 0);
    #pragma unroll
    for (int i = 0; i < 4; ++i)
      #pragma unroll
      for (int j = 0; j < 4; ++j)
        acc[i][j] = __builtin_amdgcn_mfma_f32_16x16x32_bf16(al[i], bh[j],
                                                            acc[i][j], 0, 0, 0);
    __syncthreads();
  }
  const int mb = m0 + wr * 64 + (l4 << 2);
  const int nb = n0 + wc * 64 + l15;
  #pragma unroll
  for (int i = 0; i < 4; ++i) {
    #pragma unroll
    for (int jf = 0; jf < 4; ++jf) {
      #pragma unroll
      for (int j = 0; j < 4; ++j) {
        int m = mb + i * 16 + j;
        int n = nb + jf * 16;
        Cf[(long)m * ldc + n] = acc[i][jf][j] + bias[n];
      }
    }
  }
}

// ---------------- LayerNorm (wave per row): fp32 in -> bf16 hi/lo out --------
__global__ __launch_bounds__(256) void k_ln4(const float* __restrict__ in,
                                             u16* __restrict__ outh,
                                             u16* __restrict__ outl,
                                             const float* __restrict__ g,
                                             const float* __restrict__ bb) {
  const int row = blockIdx.x * 4 + (threadIdx.x >> 6);
  const int lane = threadIdx.x & 63;
  float vv[4];
  *(float4*)vv = *(const float4*)&in[(size_t)row * DMODEL + lane * 4];
  float s1 = vv[0] + vv[1] + vv[2] + vv[3];
  float s2 = vv[0]*vv[0] + vv[1]*vv[1] + vv[2]*vv[2] + vv[3]*vv[3];
  s1 = warp_sum(s1);
  s2 = warp_sum(s2);
  float mu = s1 * (1.f / DMODEL);
  float var = s2 * (1.f / DMODEL) - mu * mu;
  float rs = rsqrtf(var + 1e-5f);
  u16 hh[4], ll[4];
  #pragma unroll
  for (int j = 0; j < 4; ++j) {
    float r = (vv[j] - mu) * rs * g[lane * 4 + j] + bb[lane * 4 + j];
    hh[j] = f2b(r);
    ll[j] = f2b(r - b2f(hh[j]));
  }
  *(uint2*)&outh[(size_t)row * DMODEL + lane * 4] = *(const uint2*)hh;
  *(uint2*)&outl[(size_t)row * DMODEL + lane * 4] = *(const uint2*)ll;
}

__global__ void k_cls(const float* __restrict__ cls, float* __restrict__ tok) {
  tok[(size_t)blockIdx.x * SEQL * DMODEL + threadIdx.x] = cls[threadIdx.x];
}

// ---------------- Q projection for cls rows only: [128][256] hi/lo -----------
__global__ __launch_bounds__(256) void k_qcls(const u16* __restrict__ x2h,
                                              const u16* __restrict__ x2l,
                                              const u16* __restrict__ qwh,
                                              const u16* __restrict__ qwl,
                                              const float* __restrict__ qb,
                                              u16* __restrict__ qch,
                                              u16* __restrict__ qcl) {
  const int b = blockIdx.x, n = threadIdx.x;
  __shared__ float xs[DMODEL];
  size_t r0 = (size_t)b * SEQL * DMODEL;
  xs[n] = b2f(x2h[r0 + n]) + b2f(x2l[r0 + n]);
  __syncthreads();
  float val = qb[n];
  #pragma unroll 4
  for (int i = 0; i < 32; ++i) {
    s16x8 wh = *(const s16x8*)(qwh + (size_t)n * DMODEL + i * 8);
    s16x8 wl = *(const s16x8*)(qwl + (size_t)n * DMODEL + i * 8);
    #pragma unroll
    for (int j = 0; j < 8; ++j)
      val = fmaf(b2f((u16)wh[j]) + b2f((u16)wl[j]), xs[i * 8 + j], val);
  }
  u16 h = f2b(val);
  qch[b * DMODEL + n] = h;
  qcl[b * DMODEL + n] = f2b(val - b2f(h));
}

// ---------------- single-query attention (cls only), fp32 K/V ----------------
__global__ __launch_bounds__(256) void k_attn_cls(const u16* __restrict__ qch,
                                                  const u16* __restrict__ qcl,
                                                  const float* __restrict__ kvf,
                                                  float* __restrict__ ao) {
  const int w = threadIdx.x >> 6, lane = threadIdx.x & 63;
  const int unit = blockIdx.x * 4 + w;
  const int b = unit >> 3, h = unit & 7;
  __shared__ float Ss[4][200];
  float q[32];
  #pragma unroll
  for (int i = 0; i < 4; ++i) {
    s16x8 vh = *(const s16x8*)(qch + b * DMODEL + h * 32 + i * 8);
    s16x8 vl = *(const s16x8*)(qcl + b * DMODEL + h * 32 + i * 8);
    #pragma unroll
    for (int j = 0; j < 8; ++j) q[i * 8 + j] = b2f((u16)vh[j]) + b2f((u16)vl[j]);
  }
  float sc[4];
  float mx = -1e30f;
  #pragma unroll
  for (int r = 0; r < 4; ++r) {
    int k = lane + 64 * r;
    float s = -1e30f;
    if (k < SEQL) {
      const float* kr = kvf + ((size_t)(b * SEQL + k)) * 512 + h * 32;
      s = 0.f;
      #pragma unroll
      for (int i = 0; i < 8; ++i) {
        float4 kv4 = *(const float4*)(kr + i * 4);
        s = fmaf(kv4.x, q[i * 4 + 0], s);
        s = fmaf(kv4.y, q[i * 4 + 1], s);
        s = fmaf(kv4.z, q[i * 4 + 2], s);
        s = fmaf(kv4.w, q[i * 4 + 3], s);
      }
      s *= 0.17677669529663687f;  // 1/sqrt(32)
    }
    sc[r] = s;
    mx = fmaxf(mx, s);
  }
  mx = warp_max(mx);
  float sm = 0.f;
  #pragma unroll
  for (int r = 0; r < 4; ++r) {
    int k = lane + 64 * r;
    float e = (k < SEQL) ? __expf(sc[r] - mx) : 0.f;
    sc[r] = e;
    sm += e;
  }
  sm = warp_sum(sm);
  float inv = 1.f / sm;
  #pragma unroll
  for (int r = 0; r < 4; ++r) {
    int k = lane + 64 * r;
    if (k < SEQL) Ss[w][k] = sc[r] * inv;
  }
  int d = lane & 31, half = lane >> 5;
  float acc = 0.f;
  for (int i = 0; i < 99; ++i) {
    int k = half * 99 + i;
    if (k < SEQL)
      acc = fmaf(Ss[w][k], kvf[((size_t)(b * SEQL + k)) * 512 + 256 + h * 32 + d], acc);
  }
  acc += __shfl_xor(acc, 32);
  if (lane < 32) ao[(b * NHEADS + h) * 32 + d] = acc;
}

// ---------------- fused out-proj + residual + LN2 + router (per-b block) -----
__global__ __launch_bounds__(256) void k_oproj_route(
    const float* __restrict__ ao, const float* __restrict__ ow,
    const float* __restrict__ ob, const float* __restrict__ tok,
    const float* __restrict__ g, const float* __restrict__ bb,
    const float* __restrict__ rw, const float* __restrict__ rb,
    float* __restrict__ tokc, float* __restrict__ x2cf,
    float* __restrict__ maskf) {
  const int b = blockIdx.x, n = threadIdx.x;
  const int w = n >> 6, lane = n & 63;
  __shared__ float xs[DMODEL];
  __shared__ float xd_s[DMODEL];
  __shared__ float red[8];
  __shared__ float lg[4];
  xs[n] = ao[b * DMODEL + n];
  __syncthreads();
  float val = ob[n];
  #pragma unroll 4
  for (int i = 0; i < 64; ++i) {
    float4 wv = *(const float4*)(ow + (size_t)n * DMODEL + i * 4);
    val = fmaf(wv.x, xs[i * 4 + 0], val);
    val = fmaf(wv.y, xs[i * 4 + 1], val);
    val = fmaf(wv.z, xs[i * 4 + 2], val);
    val = fmaf(wv.w, xs[i * 4 + 3], val);
  }
  float t = tok[(size_t)b * SEQL * DMODEL + n] + val;
  tokc[b * DMODEL + n] = t;
  // LN2 block reduce
  float s1 = warp_sum(t), s2 = warp_sum(t * t);
  if (lane == 0) { red[w] = s1; red[4 + w] = s2; }
  __syncthreads();
  s1 = red[0] + red[1] + red[2] + red[3];
  s2 = red[4] + red[5] + red[6] + red[7];
  float mu = s1 * (1.f / DMODEL);
  float var = s2 * (1.f / DMODEL) - mu * mu;
  float rs = rsqrtf(var + 1e-5f);
  float xd = (t - mu) * rs * g[n] + bb[n];
  x2cf[b * DMODEL + n] = xd;
  xd_s[n] = xd;
  __syncthreads();
  // logits: wave w = expert w
  float s = 0.f;
  #pragma unroll
  for (int i = 0; i < 4; ++i) s = fmaf(xd_s[lane + i * 64], rw[w * DMODEL + lane + i * 64], s);
  s = warp_sum(s) + rb[w];
  if (lane == 0) lg[w] = s;
  __syncthreads();
  if (n < NEXP) {
    int e = n;
    int rank = 0;
    #pragma unroll
    for (int j = 0; j < NEXP; ++j)
      if (j != e && (lg[j] > lg[e] || (lg[j] == lg[e] && j < e))) ++rank;
    maskf[b * NEXP + e] = (rank < 2) ? 1.f : 0.f;
  }
}

// ---------------- MoE GEMM1 (parallel): one block per (expert, token) --------
__global__ __launch_bounds__(256) void k_moe1(const float* __restrict__ x2cf,
                                              const float* __restrict__ w1,
                                              const float* __restrict__ b1,
                                              const float* __restrict__ maskf,
                                              float* __restrict__ hid) {
  const int e = blockIdx.x, t = blockIdx.y;
  if (maskf[t * NEXP + e] == 0.f) return;
  __shared__ float xs[DMODEL];
  const int tid = threadIdx.x;
  xs[tid] = x2cf[t * DMODEL + tid];
  __syncthreads();
  const float* w1e = w1 + (size_t)e * DMODEL * FFD + tid;
  float a0 = 0.f, a1 = 0.f, a2 = 0.f, a3 = 0.f;
  #pragma unroll 4
  for (int k = 0; k < DMODEL; ++k) {
    float xv = xs[k];
    const float* wr_ = w1e + (size_t)k * FFD;
    a0 = fmaf(xv, wr_[0], a0);
    a1 = fmaf(xv, wr_[256], a1);
    a2 = fmaf(xv, wr_[512], a2);
    a3 = fmaf(xv, wr_[768], a3);
  }
  float accs[4] = {a0, a1, a2, a3};
  float* hrow = hid + ((size_t)e * NBATCH + t) * FFD;
  #pragma unroll
  for (int j = 0; j < 4; ++j) {
    float v = accs[j] + b1[e * FFD + tid + j * 256];
    hrow[tid + j * 256] = 0.5f * v * (1.0f + erff(v * 0.70710678118654752f));
  }
}

// ---------------- MoE GEMM2 (parallel): block per (token, dchunk) ------------
__global__ __launch_bounds__(256) void k_moe2(const float* __restrict__ hid,
                                              const float* __restrict__ w2,
                                              const float* __restrict__ b2,
                                              const float* __restrict__ maskf,
                                              float* __restrict__ tokc) {
  const int t = blockIdx.x, dc = blockIdx.y;
  const int tid = threadIdx.x;
  const int dl = tid & 127, kh = tid >> 7;
  const int dout = dc * 128 + dl;
  int e0 = 0;
  while (e0 < 3 && maskf[t * NEXP + e0] == 0.f) ++e0;
  int e1 = e0 + 1;
  while (e1 < 3 && maskf[t * NEXP + e1] == 0.f) ++e1;
  __shared__ float hs0[FFD], hs1[FFD];
  const float* h0 = hid + ((size_t)e0 * NBATCH + t) * FFD;
  const float* h1 = hid + ((size_t)e1 * NBATCH + t) * FFD;
  for (int i = tid * 4; i < FFD; i += 1024) {
    *(float4*)&hs0[i] = *(const float4*)&h0[i];
    *(float4*)&hs1[i] = *(const float4*)&h1[i];
  }
  __syncthreads();
  const float* w20 = w2 + (size_t)e0 * FFD * DMODEL + dout;
  const float* w21 = w2 + (size_t)e1 * FFD * DMODEL + dout;
  float a0 = 0.f, a1 = 0.f;
  const int k0 = kh * 512;
  #pragma unroll 8
  for (int k = k0; k < k0 + 512; ++k) {
    a0 = fmaf(hs0[k], w20[(size_t)k * DMODEL], a0);
    a1 = fmaf(hs1[k], w21[(size_t)k * DMODEL], a1);
  }
  __shared__ float red[256];
  red[tid] = a0 + a1;
  __syncthreads();
  if (kh == 0) {
    float full = red[dl] + red[128 + dl] +
                 b2[e0 * DMODEL + dout] + b2[e1 * DMODEL + dout];
    tokc[t * DMODEL + dout] += full;
  }
}

// ---------------- classifier head on compact tokc ----------------------------
__global__ __launch_bounds__(256) void k_head(const float* __restrict__ tokc,
                                              const float* __restrict__ hw,
                                              const float* __restrict__ hb,
                                              float* __restrict__ out) {
  int b = blockIdx.x;
  int w = threadIdx.x >> 6, lane = threadIdx.x & 63;
  const float* row = tokc + (size_t)b * DMODEL;
  for (int c = w; c < NCLS; c += 4) {
    float s = 0.f;
    for (int d = lane; d < DMODEL; d += 64) s = fmaf(row[d], hw[c * DMODEL + d], s);
    s = warp_sum(s);
    if (lane == 0) out[b * NCLS + c] = s + hb[c];
  }
}

extern "C" void kernel_launch(void* const* d_in, const int* in_sizes, int n_in,
                              void* d_out, int out_size, void* d_ws, size_t ws_size,
                              hipStream_t stream) {
  const float* x      = (const float*)d_in[0];
  const float* conv_w = (const float*)d_in[1];
  const float* conv_b = (const float*)d_in[2];
  const float* cls    = (const float*)d_in[3];
  const float* ln1g   = (const float*)d_in[4];
  const float* ln1b   = (const float*)d_in[5];
  const float* qkv_w  = (const float*)d_in[6];
  const float* qkv_b  = (const float*)d_in[7];
  const float* out_w  = (const float*)d_in[8];
  const float* out_b  = (const float*)d_in[9];
  const float* ln2g   = (const float*)d_in[10];
  const float* ln2b   = (const float*)d_in[11];
  const float* rw     = (const float*)d_in[12];
  const float* rb     = (const float*)d_in[13];
  const float* e_w1   = (const float*)d_in[14];
  const float* e_b1   = (const float*)d_in[15];
  const float* e_w2   = (const float*)d_in[16];
  const float* e_b2   = (const float*)d_in[17];
  const float* head_w = (const float*)d_in[18];
  const float* head_b = (const float*)d_in[19];
  float* out = (float*)d_out;

  char* ws = (char*)d_ws;
  size_t off = 0;
  auto alloc = [&](size_t bytes) {
    void* p = ws + off;
    off += (bytes + 255) & ~(size_t)255;
    return p;
  };
  float* tok   = (float*)alloc((size_t)TTOK * DMODEL * 4);    // 25.8 MB
  u16*   x2h   = (u16*)alloc((size_t)TTOK * DMODEL * 2);      // 12.9
  u16*   x2l   = (u16*)alloc((size_t)TTOK * DMODEL * 2);      // 12.9
  float* qkvf  = (float*)alloc((size_t)TTOK * 512 * 4);       // 51.6 (K|V fp32)
  u16*   cwh   = (u16*)alloc((size_t)DMODEL * CONVK * 2);
  u16*   cwl   = (u16*)alloc((size_t)DMODEL * CONVK * 2);
  u16*   qwh   = (u16*)alloc((size_t)768 * DMODEL * 2);
  u16*   qwl   = (u16*)alloc((size_t)768 * DMODEL * 2);
  u16*   qch   = (u16*)alloc((size_t)NBATCH * DMODEL * 2);
  u16*   qcl   = (u16*)alloc((size_t)NBATCH * DMODEL * 2);
  float* aocf  = (float*)alloc((size_t)NBATCH * DMODEL * 4);
  float* tokc  = (float*)alloc((size_t)NBATCH * DMODEL * 4);
  float* x2cf  = (float*)alloc((size_t)NBATCH * DMODEL * 4);
  float* maskf = (float*)alloc((size_t)NBATCH * NEXP * 4);
  float* hid   = (float*)alloc((size_t)NEXP * NBATCH * FFD * 4);  // 2 MB

  // weight splits
  k_cast2<<<192, 256, 0, stream>>>(conv_w, cwh, cwl);
  k_cast2<<<192, 256, 0, stream>>>(qkv_w, qwh, qwl);

  // fused im2col + conv GEMM (fp32 out into tok, CMAP) + cls fill
  k_conv<<<dim3(CM / 128, 2), 256, 0, stream>>>(x, cwh, cwl, conv_b, tok);
  k_cls<<<NBATCH, DMODEL, 0, stream>>>(cls, tok);

  // LN1 (all tokens) -> x2 hi/lo
  k_ln4<<<TTOK / 4, 256, 0, stream>>>(tok, x2h, x2l, ln1g, ln1b);

  // K,V projection for ALL tokens -> fp32 [TTOK][512]
  k_qkv<<<dim3(TTOK / 128, 4), 256, 0, stream>>>(
      x2h, x2l, qwh + 256 * DMODEL, qwl + 256 * DMODEL, qkv_b + 256, qkvf);

  // Q projection for cls rows only
  k_qcls<<<NBATCH, 256, 0, stream>>>(x2h, x2l, qwh, qwl, qkv_b, qch, qcl);

  // single-query attention for cls
  k_attn_cls<<<NBATCH * NHEADS / 4, 256, 0, stream>>>(qch, qcl, qkvf, aocf);

  // out-proj + residual + LN2 + router (fused, per-b)
  k_oproj_route<<<NBATCH, 256, 0, stream>>>(aocf, out_w, out_b, tok,
                                            ln2g, ln2b, rw, rb,
                                            tokc, x2cf, maskf);

  // MoE (parallelized, fp32, deterministic)
  k_moe1<<<dim3(NEXP, NBATCH), 256, 0, stream>>>(x2cf, e_w1, e_b1, maskf, hid);
  k_moe2<<<dim3(NBATCH, 2), 256, 0, stream>>>(hid, e_w2, e_b2, maskf, tokc);

  // head
  k_head<<<NBATCH, 256, 0, stream>>>(tokc, head_w, head_b, out);
}